// Round 1
// baseline (744.248 us; speedup 1.0000x reference)
//
#include <hip/hip_runtime.h>

#define H 128
#define SHIFT 9             // nodes per coarse bucket = 512
#define BN 512
#define MAXNB 256           // max coarse buckets (N <= 131072)
#define CHUNK 4096          // edges per scatter block
#define CAP 16384           // slack capacity per bucket (exp 8192, sigma ~90)
#define CSTRIDE (H * 16 + 4)   // 2052 floats: per-cc transposed W block, conflict-free
#define FCHUNK 8            // features per L2-resident slice chunk (32 B)
#define NCHUNK (H / FCHUNK) // 16 chunks; slice = N*8*4 = 3.2 MB < 4 MB XCD L2

// ============ graph build: slack-bucket counting sort (no global histogram pass) ============
// Packing: src < 2^17, local node < 512 -> record = (local<<17)|src fits u32.
// Bucket b owns pairbuf/csr region [b*CAP, (b+1)*CAP); gcur[b] (memset 0) allocates within.

__global__ __launch_bounds__(256) void scatter_pairs_k(const int* __restrict__ src,
                                                       const int* __restrict__ dst,
                                                       int* __restrict__ gcur,
                                                       unsigned* __restrict__ pairbuf,
                                                       int E, int NBv) {
    __shared__ unsigned stage[CHUNK];
    __shared__ unsigned char stb[CHUNK];
    __shared__ int hist[MAXNB], basel[MAXNB], cur[MAXNB], gbase[MAXNB];
    __shared__ int total;
    int tid = threadIdx.x;
    int base = blockIdx.x * CHUNK;

    int mysrc[16], mydst[16];
    #pragma unroll
    for (int i = 0; i < 16; ++i) {
        int e = base + i * 256 + tid;
        if (e < E) { mysrc[i] = src[e]; mydst[i] = dst[e]; } else mydst[i] = -1;
    }
    hist[tid] = 0;
    __syncthreads();
    #pragma unroll
    for (int i = 0; i < 16; ++i)
        if (mydst[i] >= 0) atomicAdd(&hist[mydst[i] >> SHIFT], 1);
    __syncthreads();
    if (tid == 0) {
        int run = 0;
        for (int b = 0; b < NBv; ++b) { basel[b] = run; run += hist[b]; }
        total = run;
    }
    __syncthreads();
    if (tid < NBv) {
        cur[tid] = basel[tid];
        if (hist[tid] > 0) gbase[tid] = tid * CAP + atomicAdd(&gcur[tid], hist[tid]);
    }
    __syncthreads();
    #pragma unroll
    for (int i = 0; i < 16; ++i)
        if (mydst[i] >= 0) {
            int b = mydst[i] >> SHIFT;
            int slot = atomicAdd(&cur[b], 1);
            stage[slot] = ((unsigned)(mydst[i] & (BN - 1)) << 17) | (unsigned)mysrc[i];
            stb[slot] = (unsigned char)b;
        }
    __syncthreads();
    for (int s = tid; s < total; s += 256) {
        int b = stb[s];
        pairbuf[gbase[b] + (s - basel[b])] = stage[s];   // contiguous runs -> full-line writes
    }
}

// one block per bucket: LDS hist + scan -> offs/eend/dinv/s, then in-bucket scatter (L2-local)
__global__ __launch_bounds__(512) void build_csr_k(const unsigned* __restrict__ pairbuf,
                                                   const int* __restrict__ gcur,
                                                   const float* __restrict__ x,
                                                   int* __restrict__ offs, int* __restrict__ eend,
                                                   float* __restrict__ dinv, float* __restrict__ s,
                                                   int* __restrict__ csr, int N) {
    __shared__ int hist[BN];
    __shared__ int cur[BN];
    __shared__ int ps[BN];
    int b = blockIdx.x, tid = threadIdx.x;
    int node0 = b << SHIFT;
    int e0 = b * CAP, e1 = e0 + gcur[b];
    hist[tid] = 0;
    __syncthreads();
    for (int p = e0 + tid; p < e1; p += 512)
        atomicAdd(&hist[pairbuf[p] >> 17], 1);
    __syncthreads();
    int v0 = hist[tid];
    ps[tid] = v0;
    __syncthreads();
    for (int off = 1; off < BN; off <<= 1) {
        int t = (tid >= off) ? ps[tid - off] : 0;
        __syncthreads();
        ps[tid] += t;
        __syncthreads();
    }
    int g0 = e0 + ps[tid] - v0;
    int n0 = node0 + tid;
    if (n0 < N) {
        float d = rsqrtf((float)(v0 + 1));
        offs[n0] = g0;
        eend[n0] = g0 + v0;
        dinv[n0] = d;
        s[n0] = x[n0] * d;      // fused s_k
    }
    cur[tid] = g0;
    __syncthreads();
    for (int p = e0 + tid; p < e1; p += 512) {
        unsigned v = pairbuf[p];
        int pos = atomicAdd(&cur[v >> 17], 1);
        csr[pos] = (int)(v & 0x1FFFFu);
    }
}

// ---------------- layer 1: t_i = dinv_i*(s_i + sum s_src); emits (t, dinv) pairs ----------------

__global__ void agg1_k(const float* __restrict__ s, const int* __restrict__ offs,
                       const int* __restrict__ eend, const int* __restrict__ csr,
                       const float* __restrict__ dinv, float2* __restrict__ td, int n) {
    int i = blockIdx.x * blockDim.x + threadIdx.x;
    if (i >= n) return;
    float sum = s[i];
    int e0 = offs[i], e1 = eend[i];
    float a0 = 0.f, a1 = 0.f, a2 = 0.f, a3 = 0.f;
    int p = e0;
    for (; p + 4 <= e1; p += 4) {
        a0 += s[csr[p]]; a1 += s[csr[p + 1]]; a2 += s[csr[p + 2]]; a3 += s[csr[p + 3]];
    }
    for (; p < e1; ++p) sum += s[csr[p]];
    sum += (a0 + a1) + (a2 + a3);
    float d = dinv[i];
    td[i] = make_float2(sum * d, d);
}

// ------- layer-2 fused aggregation over SCALARS (aggregate-then-GEMM algebra) -------
// U2_i = dinv_i * sum_{j in N(i)+self} dinv_j * relu(t_j*w1 + b1)

__global__ __launch_bounds__(256) void l2_agg_k(const float2* __restrict__ td,
                                                const int* __restrict__ offs,
                                                const int* __restrict__ eend,
                                                const int* __restrict__ csr,
                                                const float* __restrict__ w1,
                                                const float* __restrict__ b1,
                                                float* __restrict__ U, int n) {
    int node = blockIdx.x * 4 + (threadIdx.x >> 6);
    int lane = threadIdx.x & 63;
    if (node >= n) return;
    float wa = w1[lane],      wb = w1[lane + 64];
    float ba = b1[lane],      bb = b1[lane + 64];
    float2 self = td[node];
    float sa = fmaxf(fmaf(self.x, wa, ba), 0.f) * self.y;
    float sb = fmaxf(fmaf(self.x, wb, bb), 0.f) * self.y;
    int e0 = offs[node], e1 = eend[node];
    int p = e0;
    for (; p + 8 <= e1; p += 8) {
        float2 v[8];
        #pragma unroll
        for (int u = 0; u < 8; ++u) v[u] = td[csr[p + u]];
        #pragma unroll
        for (int u = 0; u < 8; ++u) {
            sa = fmaf(fmaxf(fmaf(v[u].x, wa, ba), 0.f), v[u].y, sa);
            sb = fmaf(fmaxf(fmaf(v[u].x, wb, bb), 0.f), v[u].y, sb);
        }
    }
    for (; p < e1; ++p) {
        float2 v = td[csr[p]];
        sa = fmaf(fmaxf(fmaf(v.x, wa, ba), 0.f), v.y, sa);
        sb = fmaf(fmaxf(fmaf(v.x, wb, bb), 0.f), v.y, sb);
    }
    float d = self.y;
    U[(size_t)node * H + lane]      = sa * d;
    U[(size_t)node * H + lane + 64] = sb * d;
}

// ---- conflict-free W staging: WT[cc][k][j], stride CSTRIDE per cc ----

__device__ __forceinline__ void stage_WT(const float* __restrict__ W, float* __restrict__ WT) {
    for (int idx = threadIdx.x; idx < H * H / 4; idx += 256) {
        float4 v = ((const float4*)W)[idx];
        int k  = idx >> 5;
        int c4 = idx & 31;
        int cc = c4 >> 2;
        int j  = (c4 & 3) * 4;
        *(float4*)(WT + cc * CSTRIDE + k * 16 + j) = v;
    }
}

// ------- GEMM with post-activation row scale: Z2 = pscale[row] * relu(in@W + bias) -------
// in: row-major [n][H].  out: CHUNKED layout Zc[chunk][node][8] (chunk = feat>>3).

__global__ __launch_bounds__(256) void gemm_post_k(const float* __restrict__ in, const float* __restrict__ W,
                                                   const float* __restrict__ bias, const float* __restrict__ pscale,
                                                   float* __restrict__ out, int n) {
    __shared__ float WT[8 * CSTRIDE];
    stage_WT(W, WT);
    __syncthreads();
    const int cc = threadIdx.x & 7;
    const int rg = threadIdx.x >> 3;
    const int c0 = cc * 16;
    const int row0 = blockIdx.x * 128 + rg * 4;
    const float* wt = WT + cc * CSTRIDE;
    const size_t n8 = (size_t)n * FCHUNK;

    const float* p[4];
    #pragma unroll
    for (int r = 0; r < 4; ++r) {
        int rr = row0 + r; if (rr > n - 1) rr = n - 1;
        p[r] = in + (size_t)rr * H;
    }

    float acc[4][16];
    #pragma unroll
    for (int r = 0; r < 4; ++r)
        #pragma unroll
        for (int j = 0; j < 16; ++j) acc[r][j] = 0.f;

    for (int k4 = 0; k4 < H / 4; ++k4) {
        float4 a[4];
        #pragma unroll
        for (int r = 0; r < 4; ++r) a[r] = *(const float4*)(p[r] + k4 * 4);
        #pragma unroll
        for (int kk = 0; kk < 4; ++kk) {
            const float* wb = wt + (k4 * 4 + kk) * 16;
            float w[16];
            *(float4*)(w + 0)  = *(const float4*)(wb + 0);
            *(float4*)(w + 4)  = *(const float4*)(wb + 4);
            *(float4*)(w + 8)  = *(const float4*)(wb + 8);
            *(float4*)(w + 12) = *(const float4*)(wb + 12);
            float av[4];
            #pragma unroll
            for (int r = 0; r < 4; ++r) av[r] = ((const float*)&a[r])[kk];
            #pragma unroll
            for (int r = 0; r < 4; ++r)
                #pragma unroll
                for (int j = 0; j < 16; ++j)
                    acc[r][j] = fmaf(av[r], w[j], acc[r][j]);
        }
    }

    // epilogue: features c0+j4*4 -> chunk 2cc + (j4>>1), within-chunk offset (j4&1)*4
    #pragma unroll
    for (int r = 0; r < 4; ++r) {
        int row = row0 + r;
        if (row < n) {
            float sc = pscale[row];
            float* zc0 = out + (size_t)(2 * cc) * n8 + (size_t)row * FCHUNK;
            #pragma unroll
            for (int j4 = 0; j4 < 4; ++j4) {
                float4 o;
                o.x = fmaxf(acc[r][j4 * 4 + 0] + bias[c0 + j4 * 4 + 0], 0.f) * sc;
                o.y = fmaxf(acc[r][j4 * 4 + 1] + bias[c0 + j4 * 4 + 1], 0.f) * sc;
                o.z = fmaxf(acc[r][j4 * 4 + 2] + bias[c0 + j4 * 4 + 2], 0.f) * sc;
                o.w = fmaxf(acc[r][j4 * 4 + 3] + bias[c0 + j4 * 4 + 3], 0.f) * sc;
                *(float4*)(zc0 + (size_t)(j4 >> 1) * n8 + (j4 & 1) * 4) = o;
            }
        }
    }
}

// ------- layer-3 chunked aggregation: U3c[c][i][f] = dinv_i * (Zc[c][i][f] + sum_src Zc[c][src][f]) -------
// One chunk slice (N*8*4 = 3.2 MB) fits an XCD's 4 MB L2. Grid ordered so that under
// round-robin blockIdx%8 -> XCD placement, chunk (phase*8 + bid%8) runs ONLY on XCD bid%8:
// the slice is faulted into that L2 once; all gather demand after that is an L2 hit.
// Wave = 2 nodes x (8 edge slots x 4 float2-lanes). csr is streamed (nontemporal).

__global__ __launch_bounds__(256) void agg3c_k(const float* __restrict__ Z,
                                               const int* __restrict__ offs,
                                               const int* __restrict__ eend,
                                               const int* __restrict__ csr,
                                               const float* __restrict__ dinv,
                                               float* __restrict__ U, int n, int perphase) {
    int bid = blockIdx.x;
    int p = (bid >= perphase) ? 1 : 0;          // 2 temporal phases of 8 chunks
    int rem = bid - p * perphase;
    int chunk = (p << 3) | (rem & 7);           // bid%8 == chunk%8 -> XCD pin
    int nb = rem >> 3;
    int wave = threadIdx.x >> 6;                // 4 waves/block
    int l = threadIdx.x & 63;
    int np = l >> 5;                            // node parity (2 nodes per wave)
    int ll = l & 31;
    int fp = ll & 3;                            // float2 feature pair: feats [2fp, 2fp+1]
    int slot = ll >> 2;                         // 8 edge slots per node

    const size_t n8 = (size_t)n * FCHUNK;
    const float* Zc = Z + (size_t)chunk * n8;
    float*       Uc = U + (size_t)chunk * n8;

    int base = nb << 6;                         // 64 nodes per block
    int hi = base + 64; if (hi > n) hi = n;

    for (int i2 = base + (wave << 1); i2 < hi; i2 += 8) {
        int i = i2 + np;
        bool valid = (i < hi);
        int iv = valid ? i : (hi - 1);
        int e0 = offs[iv];
        int total = eend[iv] - e0 + 1;          // self + neighbors
        int tot_eff = valid ? total : 0;
        int tmax = tot_eff;
        { int o = __shfl_xor(tmax, 32); if (o > tmax) tmax = o; }
        float ax = 0.f, ay = 0.f;
        for (int t = slot; t < tmax; t += 8) {
            if (t < tot_eff) {
                int srcn = iv;
                if (t > 0) srcn = __builtin_nontemporal_load(&csr[e0 + t - 1]);
                const float2 v = *(const float2*)(Zc + (size_t)srcn * FCHUNK + (fp << 1));
                ax += v.x; ay += v.y;
            }
        }
        #pragma unroll
        for (int m = 4; m <= 16; m <<= 1) {     // fold the 8 slots (lane bits 2..4)
            ax += __shfl_xor(ax, m);
            ay += __shfl_xor(ay, m);
        }
        if (ll < 4 && valid) {
            float d = dinv[i];
            float2 o; o.x = ax * d; o.y = ay * d;
            *(float2*)(Uc + (size_t)i * FCHUNK + (fp << 1)) = o;
        }
    }
}

// ------- layer-3 GEMM: h3 = relu(U3@W3 + b3) -------
// in: CHUNKED layout [16][n][8] (feat k -> chunk k>>3).  out: row-major [n][H].

__global__ __launch_bounds__(256) void gemm_k(const float* __restrict__ in, const float* __restrict__ W,
                                              const float* __restrict__ bias,
                                              float* __restrict__ out, int n) {
    __shared__ float WT[8 * CSTRIDE];
    stage_WT(W, WT);
    __syncthreads();
    const int cc = threadIdx.x & 7;
    const int rg = threadIdx.x >> 3;
    const int c0 = cc * 16;
    const int row0 = blockIdx.x * 128 + rg * 4;
    const float* wt = WT + cc * CSTRIDE;
    const size_t n8 = (size_t)n * FCHUNK;

    size_t rowoff[4];
    #pragma unroll
    for (int r = 0; r < 4; ++r) {
        int rr = row0 + r; if (rr > n - 1) rr = n - 1;
        rowoff[r] = (size_t)rr * FCHUNK;
    }

    float acc[4][16];
    #pragma unroll
    for (int r = 0; r < 4; ++r)
        #pragma unroll
        for (int j = 0; j < 16; ++j) acc[r][j] = 0.f;

    for (int k4 = 0; k4 < H / 4; ++k4) {
        // feats k4*4 .. k4*4+3 live in chunk k4>>1, within-chunk offset (k4&1)*4
        const float* ab = in + (size_t)(k4 >> 1) * n8 + ((k4 & 1) << 2);
        float4 a[4];
        #pragma unroll
        for (int r = 0; r < 4; ++r) a[r] = *(const float4*)(ab + rowoff[r]);
        #pragma unroll
        for (int kk = 0; kk < 4; ++kk) {
            const float* wb = wt + (k4 * 4 + kk) * 16;
            float w[16];
            *(float4*)(w + 0)  = *(const float4*)(wb + 0);
            *(float4*)(w + 4)  = *(const float4*)(wb + 4);
            *(float4*)(w + 8)  = *(const float4*)(wb + 8);
            *(float4*)(w + 12) = *(const float4*)(wb + 12);
            float av[4];
            #pragma unroll
            for (int r = 0; r < 4; ++r) av[r] = ((const float*)&a[r])[kk];
            #pragma unroll
            for (int r = 0; r < 4; ++r)
                #pragma unroll
                for (int j = 0; j < 16; ++j)
                    acc[r][j] = fmaf(av[r], w[j], acc[r][j]);
        }
    }

    #pragma unroll
    for (int r = 0; r < 4; ++r) {
        int row = row0 + r;
        if (row < n) {
            float* orow = out + (size_t)row * H + c0;
            #pragma unroll
            for (int j4 = 0; j4 < 4; ++j4) {
                float4 o;
                o.x = fmaxf(acc[r][j4 * 4 + 0] + bias[c0 + j4 * 4 + 0], 0.f);
                o.y = fmaxf(acc[r][j4 * 4 + 1] + bias[c0 + j4 * 4 + 1], 0.f);
                o.z = fmaxf(acc[r][j4 * 4 + 2] + bias[c0 + j4 * 4 + 2], 0.f);
                o.w = fmaxf(acc[r][j4 * 4 + 3] + bias[c0 + j4 * 4 + 3], 0.f);
                *(float4*)(orow + j4 * 4) = o;
            }
        }
    }
}

// ---------------- pooling (binary search over sorted batch ids; overwrite, no atomics) --------

__global__ __launch_bounds__(128) void pool_k(const float* __restrict__ h, const int* __restrict__ batch,
                                              float* __restrict__ P, int n, int G) {
    int g = blockIdx.x, f = threadIdx.x;
    int lo = 0, hi = n;
    while (lo < hi) { int m = (lo + hi) >> 1; if (batch[m] < g) lo = m + 1; else hi = m; }
    int s0 = lo;
    hi = n;
    while (lo < hi) { int m = (lo + hi) >> 1; if (batch[m] < g + 1) lo = m + 1; else hi = m; }
    int s1 = lo;
    float a0 = 0.f, a1 = 0.f, a2 = 0.f, a3 = 0.f;
    int i = s0;
    for (; i + 4 <= s1; i += 4) {
        a0 += h[(size_t)i * H + f];
        a1 += h[(size_t)(i + 1) * H + f];
        a2 += h[(size_t)(i + 2) * H + f];
        a3 += h[(size_t)(i + 3) * H + f];
    }
    for (; i < s1; ++i) a0 += h[(size_t)i * H + f];
    float sum = (a0 + a1) + (a2 + a3);
    float c = (float)(s1 - s0); if (c < 1.f) c = 1.f;
    P[(size_t)g * H + f] = sum / c;
}

// ------- fused MLP head: relu(@Wl1+bl1) + relu(@Wl2+bl2) + dot Wl3 + bl3 -------

__global__ __launch_bounds__(256) void head_k(const float* __restrict__ P,
                                              const float* __restrict__ Wl1, const float* __restrict__ bl1,
                                              const float* __restrict__ Wl2, const float* __restrict__ bl2,
                                              const float* __restrict__ Wl3, const float* __restrict__ bl3,
                                              float* __restrict__ out, int G) {
    __shared__ float Wb[H * H];
    __shared__ float Tl[H * 133];
    __shared__ float w3l[H];
    int tid = threadIdx.x;
    int g0 = blockIdx.x * 128;

    if (tid < 128) w3l[tid] = Wl3[tid];
    for (int i = tid; i < H * H / 4; i += 256) ((float4*)Wb)[i] = ((const float4*)Wl1)[i];
    __syncthreads();

    const int cc = tid & 7, rg = tid >> 3, c0 = cc * 16;
    float acc[4][16];

    #pragma unroll
    for (int r = 0; r < 4; ++r)
        #pragma unroll
        for (int j = 0; j < 16; ++j) acc[r][j] = 0.f;
    const float4* P4 = (const float4*)P;
    for (int k4 = 0; k4 < H / 4; ++k4) {
        float4 a[4];
        #pragma unroll
        for (int r = 0; r < 4; ++r) a[r] = P4[(size_t)(g0 + rg * 4 + r) * 32 + k4];
        const float* wbase = Wb + (k4 * 4) * H + c0;
        #pragma unroll
        for (int kk = 0; kk < 4; ++kk) {
            float w[16];
            *(float4*)(w + 0)  = *(const float4*)(wbase + kk * H + 0);
            *(float4*)(w + 4)  = *(const float4*)(wbase + kk * H + 4);
            *(float4*)(w + 8)  = *(const float4*)(wbase + kk * H + 8);
            *(float4*)(w + 12) = *(const float4*)(wbase + kk * H + 12);
            float av[4];
            #pragma unroll
            for (int r = 0; r < 4; ++r) av[r] = ((const float*)&a[r])[kk];
            #pragma unroll
            for (int r = 0; r < 4; ++r)
                #pragma unroll
                for (int j = 0; j < 16; ++j)
                    acc[r][j] = fmaf(av[r], w[j], acc[r][j]);
        }
    }
    #pragma unroll
    for (int r = 0; r < 4; ++r) {
        int rl = rg * 4 + r;
        #pragma unroll
        for (int j = 0; j < 16; ++j)
            Tl[rl * 133 + c0 + j] = fmaxf(acc[r][j] + bl1[c0 + j], 0.f);
    }
    __syncthreads();
    for (int i = tid; i < H * H / 4; i += 256) ((float4*)Wb)[i] = ((const float4*)Wl2)[i];
    __syncthreads();

    #pragma unroll
    for (int r = 0; r < 4; ++r)
        #pragma unroll
        for (int j = 0; j < 16; ++j) acc[r][j] = 0.f;
    for (int k4 = 0; k4 < H / 4; ++k4) {
        float4 a[4];
        #pragma unroll
        for (int r = 0; r < 4; ++r) a[r] = *(const float4*)(Tl + (rg * 4 + r) * 133 + k4 * 4);
        const float* wbase = Wb + (k4 * 4) * H + c0;
        #pragma unroll
        for (int kk = 0; kk < 4; ++kk) {
            float w[16];
            *(float4*)(w + 0)  = *(const float4*)(wbase + kk * H + 0);
            *(float4*)(w + 4)  = *(const float4*)(wbase + kk * H + 4);
            *(float4*)(w + 8)  = *(const float4*)(wbase + kk * H + 8);
            *(float4*)(w + 12) = *(const float4*)(wbase + kk * H + 12);
            float av[4];
            #pragma unroll
            for (int r = 0; r < 4; ++r) av[r] = ((const float*)&a[r])[kk];
            #pragma unroll
            for (int r = 0; r < 4; ++r)
                #pragma unroll
                for (int j = 0; j < 16; ++j)
                    acc[r][j] = fmaf(av[r], w[j], acc[r][j]);
        }
    }
    float part[4];
    #pragma unroll
    for (int r = 0; r < 4; ++r) {
        float s = 0.f;
        #pragma unroll
        for (int j = 0; j < 16; ++j)
            s += fmaxf(acc[r][j] + bl2[c0 + j], 0.f) * w3l[c0 + j];
        part[r] = s;
    }
    #pragma unroll
    for (int off = 1; off < 8; off <<= 1)
        #pragma unroll
        for (int r = 0; r < 4; ++r) part[r] += __shfl_xor(part[r], off);
    if (cc == 0) {
        float bb = bl3[0];
        #pragma unroll
        for (int r = 0; r < 4; ++r) out[g0 + rg * 4 + r] = part[r] + bb;
    }
}

// ---------------- launch ----------------

extern "C" void kernel_launch(void* const* d_in, const int* in_sizes, int n_in,
                              void* d_out, int out_size, void* d_ws, size_t ws_size,
                              hipStream_t stream) {
    const float* x     = (const float*)d_in[0];
    const int*   ei    = (const int*)d_in[1];
    const int*   batch = (const int*)d_in[2];
    const float* W1  = (const float*)d_in[3];  const float* b1  = (const float*)d_in[4];
    const float* W2  = (const float*)d_in[5];  const float* b2  = (const float*)d_in[6];
    const float* W3  = (const float*)d_in[7];  const float* b3  = (const float*)d_in[8];
    const float* Wl1 = (const float*)d_in[9];  const float* bl1 = (const float*)d_in[10];
    const float* Wl2 = (const float*)d_in[11]; const float* bl2 = (const float*)d_in[12];
    const float* Wl3 = (const float*)d_in[13]; const float* bl3 = (const float*)d_in[14];

    const int N = in_sizes[0];
    const int E = in_sizes[1] / 2;
    const int G = out_size;
    const int* srcp = ei;
    const int* dstp = ei + E;
    const int NB = (N + BN - 1) / BN;    // 196 for N=100000

    char* w = (char*)d_ws;
    size_t off = 0;
    auto alloc = [&](size_t bytes) -> void* {
        void* p = w + off;
        off += (bytes + 255) & ~(size_t)255;
        return p;
    };
    int*    gcur   = (int*)alloc((size_t)MAXNB * 4);
    int*    offs   = (int*)alloc((size_t)N * 4);
    int*    eend   = (int*)alloc((size_t)N * 4);
    int*    csr    = (int*)alloc((size_t)NB * CAP * 4);   // bucket-padded
    float*  dinv   = (float*)alloc((size_t)N * 4);
    float*  sbuf   = (float*)alloc((size_t)N * 4);
    float2* td     = (float2*)alloc((size_t)N * 8);
    float*  A      = (float*)alloc((size_t)N * H * 4);   // U2 (row-major), then U3 (chunked)
    float*  B      = (float*)alloc((size_t)N * H * 4);   // pairbuf, then Z2 (chunked), then h3
    float*  P      = (float*)alloc((size_t)G * H * 4);   // pooled means
    unsigned* pairbuf = (unsigned*)B;   // alias (NB*CAP*4 = 12.9 MB << N*H*4)
    (void)ws_size; (void)n_in;

    // --- graph build (slack buckets: no histogram pass) ---
    hipMemsetAsync(gcur, 0, (size_t)MAXNB * 4, stream);
    scatter_pairs_k<<<(E + CHUNK - 1) / CHUNK, 256, 0, stream>>>(srcp, dstp, gcur, pairbuf, E, NB);
    build_csr_k<<<NB, 512, 0, stream>>>(pairbuf, gcur, x, offs, eend, dinv, sbuf, csr, N);

    // --- layer 1 (scalar feature) ---
    agg1_k<<<(N + 255) / 256, 256, 0, stream>>>(sbuf, offs, eend, csr, dinv, td, N);

    // --- layer 2: scalar-gather fused aggregation, then GEMM (chunked Z2 out) ---
    l2_agg_k<<<(N + 3) / 4, 256, 0, stream>>>(td, offs, eend, csr, W1, b1, A, N);
    gemm_post_k<<<(N + 127) / 128, 256, 0, stream>>>(A, W2, b2, dinv, B, N);   // B = Z2 (chunked)

    // --- layer 3: L2-resident chunked aggregation, GEMM, pool ---
    {
        int nblk64 = (N + 63) >> 6;
        int perphase = nblk64 * 8;
        agg3c_k<<<2 * perphase, 256, 0, stream>>>(B, offs, eend, csr, dinv, A, N, perphase); // A = U3 (chunked)
    }
    gemm_k<<<(N + 127) / 128, 256, 0, stream>>>(A, W3, b3, B, N);              // B = h3 (row-major)
    pool_k<<<G, 128, 0, stream>>>(B, batch, P, N, G);

    // --- fused MLP head ---
    head_k<<<(G + 127) / 128, 256, 0, stream>>>(P, Wl1, bl1, Wl2, bl2, Wl3, bl3,
                                                (float*)d_out, G);
}

// Round 2
// 614.537 us; speedup vs baseline: 1.2111x; 1.2111x over previous
//
#include <hip/hip_runtime.h>

#define H 128
#define SHIFT 9             // nodes per coarse bucket = 512
#define BN 512
#define MAXNB 256           // max coarse buckets (N <= 131072)
#define CHUNK 4096          // edges per scatter block
#define CAP 16384           // slack capacity per bucket (exp 8192, sigma ~90)
#define CSTRIDE (H * 16 + 4)   // 2052 floats: per-cc transposed W block, conflict-free
#define FCHUNK 8            // features per L2-resident slice chunk (32 B)
#define NCHUNK (H / FCHUNK) // 16 chunks; slice = N*8*4 = 3.2 MB < 4 MB XCD L2
#define NT3 128             // nodes per agg3 block (window stays inside one bucket)
#define LDSE 4096           // LDS csr window capacity (16 KB; lambda=2048, 45 sigma)

// ============ graph build: slack-bucket counting sort (no global histogram pass) ============
// Packing: src < 2^17, local node < 512 -> record = (local<<17)|src fits u32.
// Bucket b owns pairbuf/csr region [b*CAP, (b+1)*CAP); gcur[b] (memset 0) allocates within.

__global__ __launch_bounds__(256) void scatter_pairs_k(const int* __restrict__ src,
                                                       const int* __restrict__ dst,
                                                       int* __restrict__ gcur,
                                                       unsigned* __restrict__ pairbuf,
                                                       int E, int NBv) {
    __shared__ unsigned stage[CHUNK];
    __shared__ unsigned char stb[CHUNK];
    __shared__ int hist[MAXNB], basel[MAXNB], cur[MAXNB], gbase[MAXNB];
    __shared__ int total;
    int tid = threadIdx.x;
    int base = blockIdx.x * CHUNK;

    int mysrc[16], mydst[16];
    #pragma unroll
    for (int i = 0; i < 16; ++i) {
        int e = base + i * 256 + tid;
        if (e < E) { mysrc[i] = src[e]; mydst[i] = dst[e]; } else mydst[i] = -1;
    }
    hist[tid] = 0;
    __syncthreads();
    #pragma unroll
    for (int i = 0; i < 16; ++i)
        if (mydst[i] >= 0) atomicAdd(&hist[mydst[i] >> SHIFT], 1);
    __syncthreads();
    if (tid == 0) {
        int run = 0;
        for (int b = 0; b < NBv; ++b) { basel[b] = run; run += hist[b]; }
        total = run;
    }
    __syncthreads();
    if (tid < NBv) {
        cur[tid] = basel[tid];
        if (hist[tid] > 0) gbase[tid] = tid * CAP + atomicAdd(&gcur[tid], hist[tid]);
    }
    __syncthreads();
    #pragma unroll
    for (int i = 0; i < 16; ++i)
        if (mydst[i] >= 0) {
            int b = mydst[i] >> SHIFT;
            int slot = atomicAdd(&cur[b], 1);
            stage[slot] = ((unsigned)(mydst[i] & (BN - 1)) << 17) | (unsigned)mysrc[i];
            stb[slot] = (unsigned char)b;
        }
    __syncthreads();
    for (int s = tid; s < total; s += 256) {
        int b = stb[s];
        pairbuf[gbase[b] + (s - basel[b])] = stage[s];   // contiguous runs -> full-line writes
    }
}

// one block per bucket: LDS hist + scan -> offs/eend/dinv/s, then in-bucket scatter (L2-local)
__global__ __launch_bounds__(512) void build_csr_k(const unsigned* __restrict__ pairbuf,
                                                   const int* __restrict__ gcur,
                                                   const float* __restrict__ x,
                                                   int* __restrict__ offs, int* __restrict__ eend,
                                                   float* __restrict__ dinv, float* __restrict__ s,
                                                   int* __restrict__ csr, int N) {
    __shared__ int hist[BN];
    __shared__ int cur[BN];
    __shared__ int ps[BN];
    int b = blockIdx.x, tid = threadIdx.x;
    int node0 = b << SHIFT;
    int e0 = b * CAP, e1 = e0 + gcur[b];
    hist[tid] = 0;
    __syncthreads();
    for (int p = e0 + tid; p < e1; p += 512)
        atomicAdd(&hist[pairbuf[p] >> 17], 1);
    __syncthreads();
    int v0 = hist[tid];
    ps[tid] = v0;
    __syncthreads();
    for (int off = 1; off < BN; off <<= 1) {
        int t = (tid >= off) ? ps[tid - off] : 0;
        __syncthreads();
        ps[tid] += t;
        __syncthreads();
    }
    int g0 = e0 + ps[tid] - v0;
    int n0 = node0 + tid;
    if (n0 < N) {
        float d = rsqrtf((float)(v0 + 1));
        offs[n0] = g0;
        eend[n0] = g0 + v0;
        dinv[n0] = d;
        s[n0] = x[n0] * d;      // fused s_k
    }
    cur[tid] = g0;
    __syncthreads();
    for (int p = e0 + tid; p < e1; p += 512) {
        unsigned v = pairbuf[p];
        int pos = atomicAdd(&cur[v >> 17], 1);
        csr[pos] = (int)(v & 0x1FFFFu);
    }
}

// ---------------- layer 1: t_i = dinv_i*(s_i + sum s_src); emits (t, dinv) pairs ----------------

__global__ void agg1_k(const float* __restrict__ s, const int* __restrict__ offs,
                       const int* __restrict__ eend, const int* __restrict__ csr,
                       const float* __restrict__ dinv, float2* __restrict__ td, int n) {
    int i = blockIdx.x * blockDim.x + threadIdx.x;
    if (i >= n) return;
    float sum = s[i];
    int e0 = offs[i], e1 = eend[i];
    float a0 = 0.f, a1 = 0.f, a2 = 0.f, a3 = 0.f;
    int p = e0;
    for (; p + 4 <= e1; p += 4) {
        a0 += s[csr[p]]; a1 += s[csr[p + 1]]; a2 += s[csr[p + 2]]; a3 += s[csr[p + 3]];
    }
    for (; p < e1; ++p) sum += s[csr[p]];
    sum += (a0 + a1) + (a2 + a3);
    float d = dinv[i];
    td[i] = make_float2(sum * d, d);
}

// ------- layer-2 fused aggregation over SCALARS (aggregate-then-GEMM algebra) -------
// U2_i = dinv_i * sum_{j in N(i)+self} dinv_j * relu(t_j*w1 + b1)

__global__ __launch_bounds__(256) void l2_agg_k(const float2* __restrict__ td,
                                                const int* __restrict__ offs,
                                                const int* __restrict__ eend,
                                                const int* __restrict__ csr,
                                                const float* __restrict__ w1,
                                                const float* __restrict__ b1,
                                                float* __restrict__ U, int n) {
    int node = blockIdx.x * 4 + (threadIdx.x >> 6);
    int lane = threadIdx.x & 63;
    if (node >= n) return;
    float wa = w1[lane],      wb = w1[lane + 64];
    float ba = b1[lane],      bb = b1[lane + 64];
    float2 self = td[node];
    float sa = fmaxf(fmaf(self.x, wa, ba), 0.f) * self.y;
    float sb = fmaxf(fmaf(self.x, wb, bb), 0.f) * self.y;
    int e0 = offs[node], e1 = eend[node];
    int p = e0;
    for (; p + 8 <= e1; p += 8) {
        float2 v[8];
        #pragma unroll
        for (int u = 0; u < 8; ++u) v[u] = td[csr[p + u]];
        #pragma unroll
        for (int u = 0; u < 8; ++u) {
            sa = fmaf(fmaxf(fmaf(v[u].x, wa, ba), 0.f), v[u].y, sa);
            sb = fmaf(fmaxf(fmaf(v[u].x, wb, bb), 0.f), v[u].y, sb);
        }
    }
    for (; p < e1; ++p) {
        float2 v = td[csr[p]];
        sa = fmaf(fmaxf(fmaf(v.x, wa, ba), 0.f), v.y, sa);
        sb = fmaf(fmaxf(fmaf(v.x, wb, bb), 0.f), v.y, sb);
    }
    float d = self.y;
    U[(size_t)node * H + lane]      = sa * d;
    U[(size_t)node * H + lane + 64] = sb * d;
}

// ---- conflict-free W staging: WT[cc][k][j], stride CSTRIDE per cc ----

__device__ __forceinline__ void stage_WT(const float* __restrict__ W, float* __restrict__ WT) {
    for (int idx = threadIdx.x; idx < H * H / 4; idx += 256) {
        float4 v = ((const float4*)W)[idx];
        int k  = idx >> 5;
        int c4 = idx & 31;
        int cc = c4 >> 2;
        int j  = (c4 & 3) * 4;
        *(float4*)(WT + cc * CSTRIDE + k * 16 + j) = v;
    }
}

// ------- GEMM with post-activation row scale: Z2 = pscale[row] * relu(in@W + bias) -------
// in: row-major [n][H].  out: CHUNKED layout Zc[chunk][node][8] (chunk = feat>>3).

__global__ __launch_bounds__(256) void gemm_post_k(const float* __restrict__ in, const float* __restrict__ W,
                                                   const float* __restrict__ bias, const float* __restrict__ pscale,
                                                   float* __restrict__ out, int n) {
    __shared__ float WT[8 * CSTRIDE];
    stage_WT(W, WT);
    __syncthreads();
    const int cc = threadIdx.x & 7;
    const int rg = threadIdx.x >> 3;
    const int c0 = cc * 16;
    const int row0 = blockIdx.x * 128 + rg * 4;
    const float* wt = WT + cc * CSTRIDE;
    const size_t n8 = (size_t)n * FCHUNK;

    const float* p[4];
    #pragma unroll
    for (int r = 0; r < 4; ++r) {
        int rr = row0 + r; if (rr > n - 1) rr = n - 1;
        p[r] = in + (size_t)rr * H;
    }

    float acc[4][16];
    #pragma unroll
    for (int r = 0; r < 4; ++r)
        #pragma unroll
        for (int j = 0; j < 16; ++j) acc[r][j] = 0.f;

    for (int k4 = 0; k4 < H / 4; ++k4) {
        float4 a[4];
        #pragma unroll
        for (int r = 0; r < 4; ++r) a[r] = *(const float4*)(p[r] + k4 * 4);
        #pragma unroll
        for (int kk = 0; kk < 4; ++kk) {
            const float* wb = wt + (k4 * 4 + kk) * 16;
            float w[16];
            *(float4*)(w + 0)  = *(const float4*)(wb + 0);
            *(float4*)(w + 4)  = *(const float4*)(wb + 4);
            *(float4*)(w + 8)  = *(const float4*)(wb + 8);
            *(float4*)(w + 12) = *(const float4*)(wb + 12);
            float av[4];
            #pragma unroll
            for (int r = 0; r < 4; ++r) av[r] = ((const float*)&a[r])[kk];
            #pragma unroll
            for (int r = 0; r < 4; ++r)
                #pragma unroll
                for (int j = 0; j < 16; ++j)
                    acc[r][j] = fmaf(av[r], w[j], acc[r][j]);
        }
    }

    // epilogue: features c0+j4*4 -> chunk 2cc + (j4>>1), within-chunk offset (j4&1)*4
    #pragma unroll
    for (int r = 0; r < 4; ++r) {
        int row = row0 + r;
        if (row < n) {
            float sc = pscale[row];
            float* zc0 = out + (size_t)(2 * cc) * n8 + (size_t)row * FCHUNK;
            #pragma unroll
            for (int j4 = 0; j4 < 4; ++j4) {
                float4 o;
                o.x = fmaxf(acc[r][j4 * 4 + 0] + bias[c0 + j4 * 4 + 0], 0.f) * sc;
                o.y = fmaxf(acc[r][j4 * 4 + 1] + bias[c0 + j4 * 4 + 1], 0.f) * sc;
                o.z = fmaxf(acc[r][j4 * 4 + 2] + bias[c0 + j4 * 4 + 2], 0.f) * sc;
                o.w = fmaxf(acc[r][j4 * 4 + 3] + bias[c0 + j4 * 4 + 3], 0.f) * sc;
                *(float4*)(zc0 + (size_t)(j4 >> 1) * n8 + (j4 & 1) * 4) = o;
            }
        }
    }
}

// ------- layer-3 chunked aggregation: U3c[c][i][f] = dinv_i * (Zc[c][i][f] + sum_src Zc[c][src][f]) -------
// Residency (proven r1: FETCH 403->133 MB): chunk slice (3.2 MB) pinned per XCD via
// bid%8 == chunk%8 round-robin placement, 2 temporal phases of 8 chunks.
// Execution fix (r1 was latency-bound at 24% VALUBusy, 530 GB/s): csr window staged in
// LDS with coalesced nt loads (keeps L2 clean for the slice; no dependent-HBM index
// fetch), gather loop unrolled x2 with both 8B loads issued before accumulation.
// Wave = 2 nodes x 8 edge slots x 4 float2 lanes; self term added by writer lanes.

__global__ __launch_bounds__(256) void agg3c_k(const float* __restrict__ Z,
                                               const int* __restrict__ offs,
                                               const int* __restrict__ eend,
                                               const int* __restrict__ csr,
                                               const float* __restrict__ dinv,
                                               float* __restrict__ U, int n, int perphase) {
    __shared__ int lcsr[LDSE];
    int bid = blockIdx.x;
    int p = (bid >= perphase) ? 1 : 0;          // 2 temporal phases of 8 chunks
    int rem = bid - p * perphase;
    int chunk = (p << 3) | (rem & 7);           // bid%8 == chunk%8 -> XCD pin
    int nb = rem >> 3;
    int base = nb * NT3;                        // NT3=128, bucket=512 -> window in one bucket
    int hi = base + NT3; if (hi > n) hi = n;

    int w0 = offs[base];
    int W = eend[hi - 1] - w0;                  // contiguous csr window

    const size_t n8 = (size_t)n * FCHUNK;
    const float* __restrict__ Zc = Z + (size_t)chunk * n8;
    float* __restrict__ Uc = U + (size_t)chunk * n8;

    int wave = threadIdx.x >> 6;                // 4 waves/block
    int l = threadIdx.x & 63;
    int np = l >> 5;                            // node parity (2 nodes per wave)
    int ll = l & 31;
    int fp = ll & 3;                            // float2 feature pair
    int slot = ll >> 2;                         // 8 edge slots

    if (W <= LDSE) {
        for (int idx = threadIdx.x; idx < W; idx += 256)
            lcsr[idx] = __builtin_nontemporal_load(&csr[w0 + idx]);
        __syncthreads();
        for (int i2 = base + (wave << 1); i2 < hi; i2 += 8) {
            int i = i2 + np;
            bool valid = (i < hi);
            int iv = valid ? i : (hi - 1);
            int e0 = offs[iv] - w0;
            int deg = valid ? (eend[iv] - offs[iv]) : 0;
            float ax = 0.f, ay = 0.f;
            int t = slot;
            for (; t + 8 < deg; t += 16) {      // 2 independent gathers in flight
                int sA = lcsr[e0 + t];
                int sB = lcsr[e0 + t + 8];
                const float2 vA = *(const float2*)(Zc + (size_t)sA * FCHUNK + (fp << 1));
                const float2 vB = *(const float2*)(Zc + (size_t)sB * FCHUNK + (fp << 1));
                ax += vA.x; ay += vA.y;
                ax += vB.x; ay += vB.y;
            }
            if (t < deg) {
                int sA = lcsr[e0 + t];
                const float2 vA = *(const float2*)(Zc + (size_t)sA * FCHUNK + (fp << 1));
                ax += vA.x; ay += vA.y;
            }
            #pragma unroll
            for (int m = 4; m <= 16; m <<= 1) { // fold 8 slots (lane bits 2..4)
                ax += __shfl_xor(ax, m);
                ay += __shfl_xor(ay, m);
            }
            if (ll < 4 && valid) {              // writer lanes: add self, scale, store
                const float2 sv = *(const float2*)(Zc + (size_t)i * FCHUNK + (ll << 1));
                float d = dinv[i];
                float2 o; o.x = (ax + sv.x) * d; o.y = (ay + sv.y) * d;
                *(float2*)(Uc + (size_t)i * FCHUNK + (ll << 1)) = o;
            }
        }
    } else {
        // fallback: window exceeds LDS capacity (>=45 sigma event) -> global csr reads
        __syncthreads();
        for (int i2 = base + (wave << 1); i2 < hi; i2 += 8) {
            int i = i2 + np;
            bool valid = (i < hi);
            int iv = valid ? i : (hi - 1);
            int e0 = offs[iv];
            int deg = valid ? (eend[iv] - offs[iv]) : 0;
            float ax = 0.f, ay = 0.f;
            int t = slot;
            for (; t + 8 < deg; t += 16) {
                int sA = csr[e0 + t];
                int sB = csr[e0 + t + 8];
                const float2 vA = *(const float2*)(Zc + (size_t)sA * FCHUNK + (fp << 1));
                const float2 vB = *(const float2*)(Zc + (size_t)sB * FCHUNK + (fp << 1));
                ax += vA.x; ay += vA.y;
                ax += vB.x; ay += vB.y;
            }
            if (t < deg) {
                int sA = csr[e0 + t];
                const float2 vA = *(const float2*)(Zc + (size_t)sA * FCHUNK + (fp << 1));
                ax += vA.x; ay += vA.y;
            }
            #pragma unroll
            for (int m = 4; m <= 16; m <<= 1) {
                ax += __shfl_xor(ax, m);
                ay += __shfl_xor(ay, m);
            }
            if (ll < 4 && valid) {
                const float2 sv = *(const float2*)(Zc + (size_t)i * FCHUNK + (ll << 1));
                float d = dinv[i];
                float2 o; o.x = (ax + sv.x) * d; o.y = (ay + sv.y) * d;
                *(float2*)(Uc + (size_t)i * FCHUNK + (ll << 1)) = o;
            }
        }
    }
}

// ------- layer-3 GEMM: h3 = relu(U3@W3 + b3) -------
// in: CHUNKED layout [16][n][8] (feat k -> chunk k>>3).  out: row-major [n][H].

__global__ __launch_bounds__(256) void gemm_k(const float* __restrict__ in, const float* __restrict__ W,
                                              const float* __restrict__ bias,
                                              float* __restrict__ out, int n) {
    __shared__ float WT[8 * CSTRIDE];
    stage_WT(W, WT);
    __syncthreads();
    const int cc = threadIdx.x & 7;
    const int rg = threadIdx.x >> 3;
    const int c0 = cc * 16;
    const int row0 = blockIdx.x * 128 + rg * 4;
    const float* wt = WT + cc * CSTRIDE;
    const size_t n8 = (size_t)n * FCHUNK;

    size_t rowoff[4];
    #pragma unroll
    for (int r = 0; r < 4; ++r) {
        int rr = row0 + r; if (rr > n - 1) rr = n - 1;
        rowoff[r] = (size_t)rr * FCHUNK;
    }

    float acc[4][16];
    #pragma unroll
    for (int r = 0; r < 4; ++r)
        #pragma unroll
        for (int j = 0; j < 16; ++j) acc[r][j] = 0.f;

    for (int k4 = 0; k4 < H / 4; ++k4) {
        // feats k4*4 .. k4*4+3 live in chunk k4>>1, within-chunk offset (k4&1)*4
        const float* ab = in + (size_t)(k4 >> 1) * n8 + ((k4 & 1) << 2);
        float4 a[4];
        #pragma unroll
        for (int r = 0; r < 4; ++r) a[r] = *(const float4*)(ab + rowoff[r]);
        #pragma unroll
        for (int kk = 0; kk < 4; ++kk) {
            const float* wb = wt + (k4 * 4 + kk) * 16;
            float w[16];
            *(float4*)(w + 0)  = *(const float4*)(wb + 0);
            *(float4*)(w + 4)  = *(const float4*)(wb + 4);
            *(float4*)(w + 8)  = *(const float4*)(wb + 8);
            *(float4*)(w + 12) = *(const float4*)(wb + 12);
            float av[4];
            #pragma unroll
            for (int r = 0; r < 4; ++r) av[r] = ((const float*)&a[r])[kk];
            #pragma unroll
            for (int r = 0; r < 4; ++r)
                #pragma unroll
                for (int j = 0; j < 16; ++j)
                    acc[r][j] = fmaf(av[r], w[j], acc[r][j]);
        }
    }

    #pragma unroll
    for (int r = 0; r < 4; ++r) {
        int row = row0 + r;
        if (row < n) {
            float* orow = out + (size_t)row * H + c0;
            #pragma unroll
            for (int j4 = 0; j4 < 4; ++j4) {
                float4 o;
                o.x = fmaxf(acc[r][j4 * 4 + 0] + bias[c0 + j4 * 4 + 0], 0.f);
                o.y = fmaxf(acc[r][j4 * 4 + 1] + bias[c0 + j4 * 4 + 1], 0.f);
                o.z = fmaxf(acc[r][j4 * 4 + 2] + bias[c0 + j4 * 4 + 2], 0.f);
                o.w = fmaxf(acc[r][j4 * 4 + 3] + bias[c0 + j4 * 4 + 3], 0.f);
                *(float4*)(orow + j4 * 4) = o;
            }
        }
    }
}

// ---------------- pooling (binary search over sorted batch ids; overwrite, no atomics) --------

__global__ __launch_bounds__(128) void pool_k(const float* __restrict__ h, const int* __restrict__ batch,
                                              float* __restrict__ P, int n, int G) {
    int g = blockIdx.x, f = threadIdx.x;
    int lo = 0, hi = n;
    while (lo < hi) { int m = (lo + hi) >> 1; if (batch[m] < g) lo = m + 1; else hi = m; }
    int s0 = lo;
    hi = n;
    while (lo < hi) { int m = (lo + hi) >> 1; if (batch[m] < g + 1) lo = m + 1; else hi = m; }
    int s1 = lo;
    float a0 = 0.f, a1 = 0.f, a2 = 0.f, a3 = 0.f;
    int i = s0;
    for (; i + 4 <= s1; i += 4) {
        a0 += h[(size_t)i * H + f];
        a1 += h[(size_t)(i + 1) * H + f];
        a2 += h[(size_t)(i + 2) * H + f];
        a3 += h[(size_t)(i + 3) * H + f];
    }
    for (; i < s1; ++i) a0 += h[(size_t)i * H + f];
    float sum = (a0 + a1) + (a2 + a3);
    float c = (float)(s1 - s0); if (c < 1.f) c = 1.f;
    P[(size_t)g * H + f] = sum / c;
}

// ------- fused MLP head: relu(@Wl1+bl1) + relu(@Wl2+bl2) + dot Wl3 + bl3 -------

__global__ __launch_bounds__(256) void head_k(const float* __restrict__ P,
                                              const float* __restrict__ Wl1, const float* __restrict__ bl1,
                                              const float* __restrict__ Wl2, const float* __restrict__ bl2,
                                              const float* __restrict__ Wl3, const float* __restrict__ bl3,
                                              float* __restrict__ out, int G) {
    __shared__ float Wb[H * H];
    __shared__ float Tl[H * 133];
    __shared__ float w3l[H];
    int tid = threadIdx.x;
    int g0 = blockIdx.x * 128;

    if (tid < 128) w3l[tid] = Wl3[tid];
    for (int i = tid; i < H * H / 4; i += 256) ((float4*)Wb)[i] = ((const float4*)Wl1)[i];
    __syncthreads();

    const int cc = tid & 7, rg = tid >> 3, c0 = cc * 16;
    float acc[4][16];

    #pragma unroll
    for (int r = 0; r < 4; ++r)
        #pragma unroll
        for (int j = 0; j < 16; ++j) acc[r][j] = 0.f;
    const float4* P4 = (const float4*)P;
    for (int k4 = 0; k4 < H / 4; ++k4) {
        float4 a[4];
        #pragma unroll
        for (int r = 0; r < 4; ++r) a[r] = P4[(size_t)(g0 + rg * 4 + r) * 32 + k4];
        const float* wbase = Wb + (k4 * 4) * H + c0;
        #pragma unroll
        for (int kk = 0; kk < 4; ++kk) {
            float w[16];
            *(float4*)(w + 0)  = *(const float4*)(wbase + kk * H + 0);
            *(float4*)(w + 4)  = *(const float4*)(wbase + kk * H + 4);
            *(float4*)(w + 8)  = *(const float4*)(wbase + kk * H + 8);
            *(float4*)(w + 12) = *(const float4*)(wbase + kk * H + 12);
            float av[4];
            #pragma unroll
            for (int r = 0; r < 4; ++r) av[r] = ((const float*)&a[r])[kk];
            #pragma unroll
            for (int r = 0; r < 4; ++r)
                #pragma unroll
                for (int j = 0; j < 16; ++j)
                    acc[r][j] = fmaf(av[r], w[j], acc[r][j]);
        }
    }
    #pragma unroll
    for (int r = 0; r < 4; ++r) {
        int rl = rg * 4 + r;
        #pragma unroll
        for (int j = 0; j < 16; ++j)
            Tl[rl * 133 + c0 + j] = fmaxf(acc[r][j] + bl1[c0 + j], 0.f);
    }
    __syncthreads();
    for (int i = tid; i < H * H / 4; i += 256) ((float4*)Wb)[i] = ((const float4*)Wl2)[i];
    __syncthreads();

    #pragma unroll
    for (int r = 0; r < 4; ++r)
        #pragma unroll
        for (int j = 0; j < 16; ++j) acc[r][j] = 0.f;
    for (int k4 = 0; k4 < H / 4; ++k4) {
        float4 a[4];
        #pragma unroll
        for (int r = 0; r < 4; ++r) a[r] = *(const float4*)(Tl + (rg * 4 + r) * 133 + k4 * 4);
        const float* wbase = Wb + (k4 * 4) * H + c0;
        #pragma unroll
        for (int kk = 0; kk < 4; ++kk) {
            float w[16];
            *(float4*)(w + 0)  = *(const float4*)(wbase + kk * H + 0);
            *(float4*)(w + 4)  = *(const float4*)(wbase + kk * H + 4);
            *(float4*)(w + 8)  = *(const float4*)(wbase + kk * H + 8);
            *(float4*)(w + 12) = *(const float4*)(wbase + kk * H + 12);
            float av[4];
            #pragma unroll
            for (int r = 0; r < 4; ++r) av[r] = ((const float*)&a[r])[kk];
            #pragma unroll
            for (int r = 0; r < 4; ++r)
                #pragma unroll
                for (int j = 0; j < 16; ++j)
                    acc[r][j] = fmaf(av[r], w[j], acc[r][j]);
        }
    }
    float part[4];
    #pragma unroll
    for (int r = 0; r < 4; ++r) {
        float s = 0.f;
        #pragma unroll
        for (int j = 0; j < 16; ++j)
            s += fmaxf(acc[r][j] + bl2[c0 + j], 0.f) * w3l[c0 + j];
        part[r] = s;
    }
    #pragma unroll
    for (int off = 1; off < 8; off <<= 1)
        #pragma unroll
        for (int r = 0; r < 4; ++r) part[r] += __shfl_xor(part[r], off);
    if (cc == 0) {
        float bb = bl3[0];
        #pragma unroll
        for (int r = 0; r < 4; ++r) out[g0 + rg * 4 + r] = part[r] + bb;
    }
}

// ---------------- launch ----------------

extern "C" void kernel_launch(void* const* d_in, const int* in_sizes, int n_in,
                              void* d_out, int out_size, void* d_ws, size_t ws_size,
                              hipStream_t stream) {
    const float* x     = (const float*)d_in[0];
    const int*   ei    = (const int*)d_in[1];
    const int*   batch = (const int*)d_in[2];
    const float* W1  = (const float*)d_in[3];  const float* b1  = (const float*)d_in[4];
    const float* W2  = (const float*)d_in[5];  const float* b2  = (const float*)d_in[6];
    const float* W3  = (const float*)d_in[7];  const float* b3  = (const float*)d_in[8];
    const float* Wl1 = (const float*)d_in[9];  const float* bl1 = (const float*)d_in[10];
    const float* Wl2 = (const float*)d_in[11]; const float* bl2 = (const float*)d_in[12];
    const float* Wl3 = (const float*)d_in[13]; const float* bl3 = (const float*)d_in[14];

    const int N = in_sizes[0];
    const int E = in_sizes[1] / 2;
    const int G = out_size;
    const int* srcp = ei;
    const int* dstp = ei + E;
    const int NB = (N + BN - 1) / BN;    // 196 for N=100000

    char* w = (char*)d_ws;
    size_t off = 0;
    auto alloc = [&](size_t bytes) -> void* {
        void* p = w + off;
        off += (bytes + 255) & ~(size_t)255;
        return p;
    };
    int*    gcur   = (int*)alloc((size_t)MAXNB * 4);
    int*    offs   = (int*)alloc((size_t)N * 4);
    int*    eend   = (int*)alloc((size_t)N * 4);
    int*    csr    = (int*)alloc((size_t)NB * CAP * 4);   // bucket-padded
    float*  dinv   = (float*)alloc((size_t)N * 4);
    float*  sbuf   = (float*)alloc((size_t)N * 4);
    float2* td     = (float2*)alloc((size_t)N * 8);
    float*  A      = (float*)alloc((size_t)N * H * 4);   // U2 (row-major), then U3 (chunked)
    float*  B      = (float*)alloc((size_t)N * H * 4);   // pairbuf, then Z2 (chunked), then h3
    float*  P      = (float*)alloc((size_t)G * H * 4);   // pooled means
    unsigned* pairbuf = (unsigned*)B;   // alias (NB*CAP*4 = 12.9 MB << N*H*4)
    (void)ws_size; (void)n_in;

    // --- graph build (slack buckets: no histogram pass) ---
    hipMemsetAsync(gcur, 0, (size_t)MAXNB * 4, stream);
    scatter_pairs_k<<<(E + CHUNK - 1) / CHUNK, 256, 0, stream>>>(srcp, dstp, gcur, pairbuf, E, NB);
    build_csr_k<<<NB, 512, 0, stream>>>(pairbuf, gcur, x, offs, eend, dinv, sbuf, csr, N);

    // --- layer 1 (scalar feature) ---
    agg1_k<<<(N + 255) / 256, 256, 0, stream>>>(sbuf, offs, eend, csr, dinv, td, N);

    // --- layer 2: scalar-gather fused aggregation, then GEMM (chunked Z2 out) ---
    l2_agg_k<<<(N + 3) / 4, 256, 0, stream>>>(td, offs, eend, csr, W1, b1, A, N);
    gemm_post_k<<<(N + 127) / 128, 256, 0, stream>>>(A, W2, b2, dinv, B, N);   // B = Z2 (chunked)

    // --- layer 3: L2-resident chunked aggregation (LDS-staged csr), GEMM, pool ---
    {
        int nblk = (N + NT3 - 1) / NT3;
        int perphase = nblk * 8;
        agg3c_k<<<2 * perphase, 256, 0, stream>>>(B, offs, eend, csr, dinv, A, N, perphase); // A = U3 (chunked)
    }
    gemm_k<<<(N + 127) / 128, 256, 0, stream>>>(A, W3, b3, B, N);              // B = h3 (row-major)
    pool_k<<<G, 128, 0, stream>>>(B, batch, P, N, G);

    // --- fused MLP head ---
    head_k<<<(G + 127) / 128, 256, 0, stream>>>(P, Wl1, bl1, Wl2, bl2, Wl3, bl3,
                                                (float*)d_out, G);
}

// Round 3
// 457.065 us; speedup vs baseline: 1.6283x; 1.3445x over previous
//
#include <hip/hip_runtime.h>
#include <hip/hip_fp16.h>

#define H 128
#define SHIFT 9             // nodes per coarse bucket = 512
#define BN 512
#define MAXNB 256           // max coarse buckets (N <= 131072)
#define CHUNK 4096          // edges per scatter block
#define CAP 16384           // slack capacity per bucket (exp 8192, sigma ~90)
#define CSTRIDE (H * 16 + 4)   // 2052 floats: per-cc transposed W block, conflict-free

// ============ graph build: slack-bucket counting sort (no global histogram pass) ============
// Packing: src < 2^17, local node < 512 -> record = (local<<17)|src fits u32.
// Bucket b owns pairbuf/csr region [b*CAP, (b+1)*CAP); gcur[b] (memset 0) allocates within.

__global__ __launch_bounds__(256) void scatter_pairs_k(const int* __restrict__ src,
                                                       const int* __restrict__ dst,
                                                       int* __restrict__ gcur,
                                                       unsigned* __restrict__ pairbuf,
                                                       int E, int NBv) {
    __shared__ unsigned stage[CHUNK];
    __shared__ unsigned char stb[CHUNK];
    __shared__ int hist[MAXNB], basel[MAXNB], cur[MAXNB], gbase[MAXNB];
    __shared__ int total;
    int tid = threadIdx.x;
    int base = blockIdx.x * CHUNK;

    int mysrc[16], mydst[16];
    #pragma unroll
    for (int i = 0; i < 16; ++i) {
        int e = base + i * 256 + tid;
        if (e < E) { mysrc[i] = src[e]; mydst[i] = dst[e]; } else mydst[i] = -1;
    }
    hist[tid] = 0;
    __syncthreads();
    #pragma unroll
    for (int i = 0; i < 16; ++i)
        if (mydst[i] >= 0) atomicAdd(&hist[mydst[i] >> SHIFT], 1);
    __syncthreads();
    if (tid == 0) {
        int run = 0;
        for (int b = 0; b < NBv; ++b) { basel[b] = run; run += hist[b]; }
        total = run;
    }
    __syncthreads();
    if (tid < NBv) {
        cur[tid] = basel[tid];
        if (hist[tid] > 0) gbase[tid] = tid * CAP + atomicAdd(&gcur[tid], hist[tid]);
    }
    __syncthreads();
    #pragma unroll
    for (int i = 0; i < 16; ++i)
        if (mydst[i] >= 0) {
            int b = mydst[i] >> SHIFT;
            int slot = atomicAdd(&cur[b], 1);
            stage[slot] = ((unsigned)(mydst[i] & (BN - 1)) << 17) | (unsigned)mysrc[i];
            stb[slot] = (unsigned char)b;
        }
    __syncthreads();
    for (int s = tid; s < total; s += 256) {
        int b = stb[s];
        pairbuf[gbase[b] + (s - basel[b])] = stage[s];   // contiguous runs -> full-line writes
    }
}

// one block per bucket: LDS hist + scan -> offs/eend/dinv/s, then in-bucket scatter (L2-local)
__global__ __launch_bounds__(512) void build_csr_k(const unsigned* __restrict__ pairbuf,
                                                   const int* __restrict__ gcur,
                                                   const float* __restrict__ x,
                                                   int* __restrict__ offs, int* __restrict__ eend,
                                                   float* __restrict__ dinv, float* __restrict__ s,
                                                   int* __restrict__ csr, int N) {
    __shared__ int hist[BN];
    __shared__ int cur[BN];
    __shared__ int ps[BN];
    int b = blockIdx.x, tid = threadIdx.x;
    int node0 = b << SHIFT;
    int e0 = b * CAP, e1 = e0 + gcur[b];
    hist[tid] = 0;
    __syncthreads();
    for (int p = e0 + tid; p < e1; p += 512)
        atomicAdd(&hist[pairbuf[p] >> 17], 1);
    __syncthreads();
    int v0 = hist[tid];
    ps[tid] = v0;
    __syncthreads();
    for (int off = 1; off < BN; off <<= 1) {
        int t = (tid >= off) ? ps[tid - off] : 0;
        __syncthreads();
        ps[tid] += t;
        __syncthreads();
    }
    int g0 = e0 + ps[tid] - v0;
    int n0 = node0 + tid;
    if (n0 < N) {
        float d = rsqrtf((float)(v0 + 1));
        offs[n0] = g0;
        eend[n0] = g0 + v0;
        dinv[n0] = d;
        s[n0] = x[n0] * d;      // fused s_k
    }
    cur[tid] = g0;
    __syncthreads();
    for (int p = e0 + tid; p < e1; p += 512) {
        unsigned v = pairbuf[p];
        int pos = atomicAdd(&cur[v >> 17], 1);
        csr[pos] = (int)(v & 0x1FFFFu);
    }
}

// ---------------- layer 1: t_i = dinv_i*(s_i + sum s_src); emits (t, dinv) pairs ----------------

__global__ void agg1_k(const float* __restrict__ s, const int* __restrict__ offs,
                       const int* __restrict__ eend, const int* __restrict__ csr,
                       const float* __restrict__ dinv, float2* __restrict__ td, int n) {
    int i = blockIdx.x * blockDim.x + threadIdx.x;
    if (i >= n) return;
    float sum = s[i];
    int e0 = offs[i], e1 = eend[i];
    float a0 = 0.f, a1 = 0.f, a2 = 0.f, a3 = 0.f;
    int p = e0;
    for (; p + 4 <= e1; p += 4) {
        a0 += s[csr[p]]; a1 += s[csr[p + 1]]; a2 += s[csr[p + 2]]; a3 += s[csr[p + 3]];
    }
    for (; p < e1; ++p) sum += s[csr[p]];
    sum += (a0 + a1) + (a2 + a3);
    float d = dinv[i];
    td[i] = make_float2(sum * d, d);
}

// ------- layer-2 fused aggregation over SCALARS (aggregate-then-GEMM algebra) -------
// U2_i = dinv_i * sum_{j in N(i)+self} dinv_j * relu(t_j*w1 + b1)

__global__ __launch_bounds__(256) void l2_agg_k(const float2* __restrict__ td,
                                                const int* __restrict__ offs,
                                                const int* __restrict__ eend,
                                                const int* __restrict__ csr,
                                                const float* __restrict__ w1,
                                                const float* __restrict__ b1,
                                                float* __restrict__ U, int n) {
    int node = blockIdx.x * 4 + (threadIdx.x >> 6);
    int lane = threadIdx.x & 63;
    if (node >= n) return;
    float wa = w1[lane],      wb = w1[lane + 64];
    float ba = b1[lane],      bb = b1[lane + 64];
    float2 self = td[node];
    float sa = fmaxf(fmaf(self.x, wa, ba), 0.f) * self.y;
    float sb = fmaxf(fmaf(self.x, wb, bb), 0.f) * self.y;
    int e0 = offs[node], e1 = eend[node];
    int p = e0;
    for (; p + 8 <= e1; p += 8) {
        float2 v[8];
        #pragma unroll
        for (int u = 0; u < 8; ++u) v[u] = td[csr[p + u]];
        #pragma unroll
        for (int u = 0; u < 8; ++u) {
            sa = fmaf(fmaxf(fmaf(v[u].x, wa, ba), 0.f), v[u].y, sa);
            sb = fmaf(fmaxf(fmaf(v[u].x, wb, bb), 0.f), v[u].y, sb);
        }
    }
    for (; p < e1; ++p) {
        float2 v = td[csr[p]];
        sa = fmaf(fmaxf(fmaf(v.x, wa, ba), 0.f), v.y, sa);
        sb = fmaf(fmaxf(fmaf(v.x, wb, bb), 0.f), v.y, sb);
    }
    float d = self.y;
    U[(size_t)node * H + lane]      = sa * d;
    U[(size_t)node * H + lane + 64] = sb * d;
}

// ---- conflict-free W staging: WT[cc][k][j], stride CSTRIDE per cc ----

__device__ __forceinline__ void stage_WT(const float* __restrict__ W, float* __restrict__ WT) {
    for (int idx = threadIdx.x; idx < H * H / 4; idx += 256) {
        float4 v = ((const float4*)W)[idx];
        int k  = idx >> 5;
        int c4 = idx & 31;
        int cc = c4 >> 2;
        int j  = (c4 & 3) * 4;
        *(float4*)(WT + cc * CSTRIDE + k * 16 + j) = v;
    }
}

// ------- GEMM with post-activation row scale: Z2h = fp16( pscale[row] * relu(in@W + bias) ) -------
// in: row-major fp32 [n][H].  out: row-major fp16 [n][H] (256 B rows -> half the gather
// line-requests and half the L2-fill bytes for agg3h).

__global__ __launch_bounds__(256) void gemm_post_k(const float* __restrict__ in, const float* __restrict__ W,
                                                   const float* __restrict__ bias, const float* __restrict__ pscale,
                                                   __half* __restrict__ out, int n) {
    __shared__ float WT[8 * CSTRIDE];
    stage_WT(W, WT);
    __syncthreads();
    const int cc = threadIdx.x & 7;
    const int rg = threadIdx.x >> 3;
    const int c0 = cc * 16;
    const int row0 = blockIdx.x * 128 + rg * 4;
    const float* wt = WT + cc * CSTRIDE;

    const float* p[4];
    #pragma unroll
    for (int r = 0; r < 4; ++r) {
        int rr = row0 + r; if (rr > n - 1) rr = n - 1;
        p[r] = in + (size_t)rr * H;
    }

    float acc[4][16];
    #pragma unroll
    for (int r = 0; r < 4; ++r)
        #pragma unroll
        for (int j = 0; j < 16; ++j) acc[r][j] = 0.f;

    for (int k4 = 0; k4 < H / 4; ++k4) {
        float4 a[4];
        #pragma unroll
        for (int r = 0; r < 4; ++r) a[r] = *(const float4*)(p[r] + k4 * 4);
        #pragma unroll
        for (int kk = 0; kk < 4; ++kk) {
            const float* wb = wt + (k4 * 4 + kk) * 16;
            float w[16];
            *(float4*)(w + 0)  = *(const float4*)(wb + 0);
            *(float4*)(w + 4)  = *(const float4*)(wb + 4);
            *(float4*)(w + 8)  = *(const float4*)(wb + 8);
            *(float4*)(w + 12) = *(const float4*)(wb + 12);
            float av[4];
            #pragma unroll
            for (int r = 0; r < 4; ++r) av[r] = ((const float*)&a[r])[kk];
            #pragma unroll
            for (int r = 0; r < 4; ++r)
                #pragma unroll
                for (int j = 0; j < 16; ++j)
                    acc[r][j] = fmaf(av[r], w[j], acc[r][j]);
        }
    }

    #pragma unroll
    for (int r = 0; r < 4; ++r) {
        int row = row0 + r;
        if (row < n) {
            float sc = pscale[row];
            __half2 hb[8];
            #pragma unroll
            for (int j4 = 0; j4 < 4; ++j4) {
                float ox = fmaxf(acc[r][j4 * 4 + 0] + bias[c0 + j4 * 4 + 0], 0.f) * sc;
                float oy = fmaxf(acc[r][j4 * 4 + 1] + bias[c0 + j4 * 4 + 1], 0.f) * sc;
                float oz = fmaxf(acc[r][j4 * 4 + 2] + bias[c0 + j4 * 4 + 2], 0.f) * sc;
                float ow = fmaxf(acc[r][j4 * 4 + 3] + bias[c0 + j4 * 4 + 3], 0.f) * sc;
                hb[j4 * 2 + 0] = __floats2half2_rn(ox, oy);
                hb[j4 * 2 + 1] = __floats2half2_rn(oz, ow);
            }
            __half* orow = out + (size_t)row * H + c0;
            *(uint4*)(orow + 0) = *(uint4*)&hb[0];
            *(uint4*)(orow + 8) = *(uint4*)&hb[4];
        }
    }
}

// ------- whole-wave gather of one node's neighbor-row sum (fp16 rows, fp32 accumulate) -------
// Row = 128 halves = 256 B; lane l of 32 reads 8 B (halves 4l..4l+3) -> 2 line-requests/row,
// 2 rows per wave instruction. 8 independent loads in flight per slot group.

__device__ __forceinline__ void acc_h(float4& a, uint2 r) {
    __half2 h0 = *(__half2*)&r.x;
    __half2 h1 = *(__half2*)&r.y;
    float2 f0 = __half22float2(h0);
    float2 f1 = __half22float2(h1);
    a.x += f0.x; a.y += f0.y; a.z += f1.x; a.w += f1.y;
}

__device__ __forceinline__ float4 gather_row_sum_h(const uint2* __restrict__ hrow,
                                                   const int* __restrict__ csr,
                                                   int node, int e0, int e1, int half, int l) {
    float4 acc[8];
    #pragma unroll
    for (int u = 0; u < 8; ++u) acc[u] = make_float4(0.f, 0.f, 0.f, 0.f);
    if (half == 0) {                                  // self loop
        uint2 rs = hrow[(size_t)node * 32 + l];
        acc_h(acc[0], rs);
    }
    int q = e0;
    for (; q + 15 < e1; q += 16) {
        int idx[8];
        #pragma unroll
        for (int u = 0; u < 8; ++u) idx[u] = csr[q + 2 * u + half];
        uint2 raw[8];
        #pragma unroll
        for (int u = 0; u < 8; ++u) raw[u] = hrow[(size_t)idx[u] * 32 + l];
        #pragma unroll
        for (int u = 0; u < 8; ++u) acc_h(acc[u], raw[u]);
    }
    for (; q + 7 < e1; q += 8) {
        int idx[4];
        #pragma unroll
        for (int u = 0; u < 4; ++u) idx[u] = csr[q + 2 * u + half];
        uint2 raw[4];
        #pragma unroll
        for (int u = 0; u < 4; ++u) raw[u] = hrow[(size_t)idx[u] * 32 + l];
        #pragma unroll
        for (int u = 0; u < 4; ++u) acc_h(acc[u], raw[u]);
    }
    for (; q < e1; q += 2) {
        int off = q + half;
        if (off < e1) {
            uint2 raw = hrow[(size_t)csr[off] * 32 + l];
            acc_h(acc[0], raw);
        }
    }
    float4 sum;
    sum.x = ((acc[0].x + acc[1].x) + (acc[2].x + acc[3].x)) + ((acc[4].x + acc[5].x) + (acc[6].x + acc[7].x));
    sum.y = ((acc[0].y + acc[1].y) + (acc[2].y + acc[3].y)) + ((acc[4].y + acc[5].y) + (acc[6].y + acc[7].y));
    sum.z = ((acc[0].z + acc[1].z) + (acc[2].z + acc[3].z)) + ((acc[4].z + acc[5].z) + (acc[6].z + acc[7].z));
    sum.w = ((acc[0].w + acc[1].w) + (acc[2].w + acc[3].w)) + ((acc[4].w + acc[5].w) + (acc[6].w + acc[7].w));
    sum.x += __shfl_xor(sum.x, 32);
    sum.y += __shfl_xor(sum.y, 32);
    sum.z += __shfl_xor(sum.z, 32);
    sum.w += __shfl_xor(sum.w, 32);
    return sum;
}

// ------- layer-3 aggregation of fp16 Z2 rows: U3_i = dinv_i * (Z2_i + sum Z2_src) [fp32 out] -------

__global__ __launch_bounds__(256) void agg3h_k(const uint2* __restrict__ Zh, const int* __restrict__ offs,
                                               const int* __restrict__ eend, const int* __restrict__ csr,
                                               const float* __restrict__ dinv,
                                               float* __restrict__ U, int n) {
    int node = blockIdx.x * 4 + (threadIdx.x >> 6);
    int lane = threadIdx.x & 63;
    int half = lane >> 5;
    int l = lane & 31;
    if (node >= n) return;
    float4 sum = gather_row_sum_h(Zh, csr, node, offs[node], eend[node], half, l);
    if (half == 0) {
        float d = dinv[node];
        float4 o;
        o.x = sum.x * d; o.y = sum.y * d; o.z = sum.z * d; o.w = sum.w * d;
        ((float4*)U)[(size_t)node * 32 + l] = o;
    }
}

// ------- layer-3 GEMM: h3 = relu(U3@W3 + b3) [fp32 row-major in/out] -------

__global__ __launch_bounds__(256) void gemm_k(const float* __restrict__ in, const float* __restrict__ W,
                                              const float* __restrict__ bias,
                                              float* __restrict__ out, int n) {
    __shared__ float WT[8 * CSTRIDE];
    stage_WT(W, WT);
    __syncthreads();
    const int cc = threadIdx.x & 7;
    const int rg = threadIdx.x >> 3;
    const int c0 = cc * 16;
    const int row0 = blockIdx.x * 128 + rg * 4;
    const float* wt = WT + cc * CSTRIDE;

    const float* p[4];
    #pragma unroll
    for (int r = 0; r < 4; ++r) {
        int rr = row0 + r; if (rr > n - 1) rr = n - 1;
        p[r] = in + (size_t)rr * H;
    }

    float acc[4][16];
    #pragma unroll
    for (int r = 0; r < 4; ++r)
        #pragma unroll
        for (int j = 0; j < 16; ++j) acc[r][j] = 0.f;

    for (int k4 = 0; k4 < H / 4; ++k4) {
        float4 a[4];
        #pragma unroll
        for (int r = 0; r < 4; ++r) a[r] = *(const float4*)(p[r] + k4 * 4);
        #pragma unroll
        for (int kk = 0; kk < 4; ++kk) {
            const float* wb = wt + (k4 * 4 + kk) * 16;
            float w[16];
            *(float4*)(w + 0)  = *(const float4*)(wb + 0);
            *(float4*)(w + 4)  = *(const float4*)(wb + 4);
            *(float4*)(w + 8)  = *(const float4*)(wb + 8);
            *(float4*)(w + 12) = *(const float4*)(wb + 12);
            float av[4];
            #pragma unroll
            for (int r = 0; r < 4; ++r) av[r] = ((const float*)&a[r])[kk];
            #pragma unroll
            for (int r = 0; r < 4; ++r)
                #pragma unroll
                for (int j = 0; j < 16; ++j)
                    acc[r][j] = fmaf(av[r], w[j], acc[r][j]);
        }
    }

    #pragma unroll
    for (int r = 0; r < 4; ++r) {
        int row = row0 + r;
        if (row < n) {
            float* orow = out + (size_t)row * H + c0;
            #pragma unroll
            for (int j4 = 0; j4 < 4; ++j4) {
                float4 o;
                o.x = fmaxf(acc[r][j4 * 4 + 0] + bias[c0 + j4 * 4 + 0], 0.f);
                o.y = fmaxf(acc[r][j4 * 4 + 1] + bias[c0 + j4 * 4 + 1], 0.f);
                o.z = fmaxf(acc[r][j4 * 4 + 2] + bias[c0 + j4 * 4 + 2], 0.f);
                o.w = fmaxf(acc[r][j4 * 4 + 3] + bias[c0 + j4 * 4 + 3], 0.f);
                *(float4*)(orow + j4 * 4) = o;
            }
        }
    }
}

// ---------------- pooling (binary search over sorted batch ids; overwrite, no atomics) --------

__global__ __launch_bounds__(128) void pool_k(const float* __restrict__ h, const int* __restrict__ batch,
                                              float* __restrict__ P, int n, int G) {
    int g = blockIdx.x, f = threadIdx.x;
    int lo = 0, hi = n;
    while (lo < hi) { int m = (lo + hi) >> 1; if (batch[m] < g) lo = m + 1; else hi = m; }
    int s0 = lo;
    hi = n;
    while (lo < hi) { int m = (lo + hi) >> 1; if (batch[m] < g + 1) lo = m + 1; else hi = m; }
    int s1 = lo;
    float a0 = 0.f, a1 = 0.f, a2 = 0.f, a3 = 0.f;
    int i = s0;
    for (; i + 4 <= s1; i += 4) {
        a0 += h[(size_t)i * H + f];
        a1 += h[(size_t)(i + 1) * H + f];
        a2 += h[(size_t)(i + 2) * H + f];
        a3 += h[(size_t)(i + 3) * H + f];
    }
    for (; i < s1; ++i) a0 += h[(size_t)i * H + f];
    float sum = (a0 + a1) + (a2 + a3);
    float c = (float)(s1 - s0); if (c < 1.f) c = 1.f;
    P[(size_t)g * H + f] = sum / c;
}

// ------- fused MLP head: relu(@Wl1+bl1) + relu(@Wl2+bl2) + dot Wl3 + bl3 -------

__global__ __launch_bounds__(256) void head_k(const float* __restrict__ P,
                                              const float* __restrict__ Wl1, const float* __restrict__ bl1,
                                              const float* __restrict__ Wl2, const float* __restrict__ bl2,
                                              const float* __restrict__ Wl3, const float* __restrict__ bl3,
                                              float* __restrict__ out, int G) {
    __shared__ float Wb[H * H];
    __shared__ float Tl[H * 133];
    __shared__ float w3l[H];
    int tid = threadIdx.x;
    int g0 = blockIdx.x * 128;

    if (tid < 128) w3l[tid] = Wl3[tid];
    for (int i = tid; i < H * H / 4; i += 256) ((float4*)Wb)[i] = ((const float4*)Wl1)[i];
    __syncthreads();

    const int cc = tid & 7, rg = tid >> 3, c0 = cc * 16;
    float acc[4][16];

    #pragma unroll
    for (int r = 0; r < 4; ++r)
        #pragma unroll
        for (int j = 0; j < 16; ++j) acc[r][j] = 0.f;
    const float4* P4 = (const float4*)P;
    for (int k4 = 0; k4 < H / 4; ++k4) {
        float4 a[4];
        #pragma unroll
        for (int r = 0; r < 4; ++r) a[r] = P4[(size_t)(g0 + rg * 4 + r) * 32 + k4];
        const float* wbase = Wb + (k4 * 4) * H + c0;
        #pragma unroll
        for (int kk = 0; kk < 4; ++kk) {
            float w[16];
            *(float4*)(w + 0)  = *(const float4*)(wbase + kk * H + 0);
            *(float4*)(w + 4)  = *(const float4*)(wbase + kk * H + 4);
            *(float4*)(w + 8)  = *(const float4*)(wbase + kk * H + 8);
            *(float4*)(w + 12) = *(const float4*)(wbase + kk * H + 12);
            float av[4];
            #pragma unroll
            for (int r = 0; r < 4; ++r) av[r] = ((const float*)&a[r])[kk];
            #pragma unroll
            for (int r = 0; r < 4; ++r)
                #pragma unroll
                for (int j = 0; j < 16; ++j)
                    acc[r][j] = fmaf(av[r], w[j], acc[r][j]);
        }
    }
    #pragma unroll
    for (int r = 0; r < 4; ++r) {
        int rl = rg * 4 + r;
        #pragma unroll
        for (int j = 0; j < 16; ++j)
            Tl[rl * 133 + c0 + j] = fmaxf(acc[r][j] + bl1[c0 + j], 0.f);
    }
    __syncthreads();
    for (int i = tid; i < H * H / 4; i += 256) ((float4*)Wb)[i] = ((const float4*)Wl2)[i];
    __syncthreads();

    #pragma unroll
    for (int r = 0; r < 4; ++r)
        #pragma unroll
        for (int j = 0; j < 16; ++j) acc[r][j] = 0.f;
    for (int k4 = 0; k4 < H / 4; ++k4) {
        float4 a[4];
        #pragma unroll
        for (int r = 0; r < 4; ++r) a[r] = *(const float4*)(Tl + (rg * 4 + r) * 133 + k4 * 4);
        const float* wbase = Wb + (k4 * 4) * H + c0;
        #pragma unroll
        for (int kk = 0; kk < 4; ++kk) {
            float w[16];
            *(float4*)(w + 0)  = *(const float4*)(wbase + kk * H + 0);
            *(float4*)(w + 4)  = *(const float4*)(wbase + kk * H + 4);
            *(float4*)(w + 8)  = *(const float4*)(wbase + kk * H + 8);
            *(float4*)(w + 12) = *(const float4*)(wbase + kk * H + 12);
            float av[4];
            #pragma unroll
            for (int r = 0; r < 4; ++r) av[r] = ((const float*)&a[r])[kk];
            #pragma unroll
            for (int r = 0; r < 4; ++r)
                #pragma unroll
                for (int j = 0; j < 16; ++j)
                    acc[r][j] = fmaf(av[r], w[j], acc[r][j]);
        }
    }
    float part[4];
    #pragma unroll
    for (int r = 0; r < 4; ++r) {
        float s = 0.f;
        #pragma unroll
        for (int j = 0; j < 16; ++j)
            s += fmaxf(acc[r][j] + bl2[c0 + j], 0.f) * w3l[c0 + j];
        part[r] = s;
    }
    #pragma unroll
    for (int off = 1; off < 8; off <<= 1)
        #pragma unroll
        for (int r = 0; r < 4; ++r) part[r] += __shfl_xor(part[r], off);
    if (cc == 0) {
        float bb = bl3[0];
        #pragma unroll
        for (int r = 0; r < 4; ++r) out[g0 + rg * 4 + r] = part[r] + bb;
    }
}

// ---------------- launch ----------------

extern "C" void kernel_launch(void* const* d_in, const int* in_sizes, int n_in,
                              void* d_out, int out_size, void* d_ws, size_t ws_size,
                              hipStream_t stream) {
    const float* x     = (const float*)d_in[0];
    const int*   ei    = (const int*)d_in[1];
    const int*   batch = (const int*)d_in[2];
    const float* W1  = (const float*)d_in[3];  const float* b1  = (const float*)d_in[4];
    const float* W2  = (const float*)d_in[5];  const float* b2  = (const float*)d_in[6];
    const float* W3  = (const float*)d_in[7];  const float* b3  = (const float*)d_in[8];
    const float* Wl1 = (const float*)d_in[9];  const float* bl1 = (const float*)d_in[10];
    const float* Wl2 = (const float*)d_in[11]; const float* bl2 = (const float*)d_in[12];
    const float* Wl3 = (const float*)d_in[13]; const float* bl3 = (const float*)d_in[14];

    const int N = in_sizes[0];
    const int E = in_sizes[1] / 2;
    const int G = out_size;
    const int* srcp = ei;
    const int* dstp = ei + E;
    const int NB = (N + BN - 1) / BN;    // 196 for N=100000

    char* w = (char*)d_ws;
    size_t off = 0;
    auto alloc = [&](size_t bytes) -> void* {
        void* p = w + off;
        off += (bytes + 255) & ~(size_t)255;
        return p;
    };
    int*    gcur   = (int*)alloc((size_t)MAXNB * 4);
    int*    offs   = (int*)alloc((size_t)N * 4);
    int*    eend   = (int*)alloc((size_t)N * 4);
    int*    csr    = (int*)alloc((size_t)NB * CAP * 4);   // bucket-padded
    float*  dinv   = (float*)alloc((size_t)N * 4);
    float*  sbuf   = (float*)alloc((size_t)N * 4);
    float2* td     = (float2*)alloc((size_t)N * 8);
    float*  A      = (float*)alloc((size_t)N * H * 4);   // U2 (fp32), then U3 (fp32)
    float*  B      = (float*)alloc((size_t)N * H * 4);   // pairbuf, then Z2h (fp16), then h3 (fp32)
    float*  P      = (float*)alloc((size_t)G * H * 4);   // pooled means
    unsigned* pairbuf = (unsigned*)B;   // alias (NB*CAP*4 = 12.9 MB << N*H*4)
    __half*   Z2h     = (__half*)B;    // alias (N*H*2 = 25.6 MB, written after pairbuf is dead)
    (void)ws_size; (void)n_in;

    // --- graph build (slack buckets: no histogram pass) ---
    hipMemsetAsync(gcur, 0, (size_t)MAXNB * 4, stream);
    scatter_pairs_k<<<(E + CHUNK - 1) / CHUNK, 256, 0, stream>>>(srcp, dstp, gcur, pairbuf, E, NB);
    build_csr_k<<<NB, 512, 0, stream>>>(pairbuf, gcur, x, offs, eend, dinv, sbuf, csr, N);

    // --- layer 1 (scalar feature) ---
    agg1_k<<<(N + 255) / 256, 256, 0, stream>>>(sbuf, offs, eend, csr, dinv, td, N);

    // --- layer 2: scalar-gather fused aggregation, then GEMM (fp16 Z2 out) ---
    l2_agg_k<<<(N + 3) / 4, 256, 0, stream>>>(td, offs, eend, csr, W1, b1, A, N);
    gemm_post_k<<<(N + 127) / 128, 256, 0, stream>>>(A, W2, b2, dinv, Z2h, N);  // B = Z2h (fp16)

    // --- layer 3: fp16 row-gather aggregation, GEMM, pool ---
    agg3h_k<<<(N + 3) / 4, 256, 0, stream>>>((const uint2*)Z2h, offs, eend, csr, dinv, A, N); // A = U3
    gemm_k<<<(N + 127) / 128, 256, 0, stream>>>(A, W3, b3, B, N);              // B = h3 (fp32)
    pool_k<<<G, 128, 0, stream>>>(B, batch, P, N, G);

    // --- fused MLP head ---
    head_k<<<(G + 127) / 128, 256, 0, stream>>>(P, Wl1, bl1, Wl2, bl2, Wl3, bl3,
                                                (float*)d_out, G);
}

// Round 4
// 444.086 us; speedup vs baseline: 1.6759x; 1.0292x over previous
//
#include <hip/hip_runtime.h>
#include <hip/hip_fp16.h>

#define H 128
#define SHIFT 9             // nodes per coarse bucket = 512
#define BN 512
#define MAXNB 256           // max coarse buckets (N <= 131072)
#define CHUNK 4096          // edges per scatter block
#define CAP 16384           // slack capacity per bucket (exp 8192, sigma ~90)
#define CSTRIDE (H * 16 + 4)   // 2052 floats: per-cc transposed W block, conflict-free

// ============ graph build: slack-bucket counting sort (no global histogram pass) ============
// Packing: src < 2^17, local node < 512 -> record = (local<<17)|src fits u32.
// Bucket b owns pairbuf/csr region [b*CAP, (b+1)*CAP); gcur[b] (memset 0) allocates within.

__global__ __launch_bounds__(256) void scatter_pairs_k(const int* __restrict__ src,
                                                       const int* __restrict__ dst,
                                                       int* __restrict__ gcur,
                                                       unsigned* __restrict__ pairbuf,
                                                       int E, int NBv) {
    __shared__ unsigned stage[CHUNK];
    __shared__ unsigned char stb[CHUNK];
    __shared__ int hist[MAXNB], basel[MAXNB], cur[MAXNB], gbase[MAXNB];
    __shared__ int total;
    int tid = threadIdx.x;
    int base = blockIdx.x * CHUNK;

    int mysrc[16], mydst[16];
    #pragma unroll
    for (int i = 0; i < 16; ++i) {
        int e = base + i * 256 + tid;
        if (e < E) { mysrc[i] = src[e]; mydst[i] = dst[e]; } else mydst[i] = -1;
    }
    hist[tid] = 0;
    __syncthreads();
    #pragma unroll
    for (int i = 0; i < 16; ++i)
        if (mydst[i] >= 0) atomicAdd(&hist[mydst[i] >> SHIFT], 1);
    __syncthreads();
    if (tid == 0) {
        int run = 0;
        for (int b = 0; b < NBv; ++b) { basel[b] = run; run += hist[b]; }
        total = run;
    }
    __syncthreads();
    if (tid < NBv) {
        cur[tid] = basel[tid];
        if (hist[tid] > 0) gbase[tid] = tid * CAP + atomicAdd(&gcur[tid], hist[tid]);
    }
    __syncthreads();
    #pragma unroll
    for (int i = 0; i < 16; ++i)
        if (mydst[i] >= 0) {
            int b = mydst[i] >> SHIFT;
            int slot = atomicAdd(&cur[b], 1);
            stage[slot] = ((unsigned)(mydst[i] & (BN - 1)) << 17) | (unsigned)mysrc[i];
            stb[slot] = (unsigned char)b;
        }
    __syncthreads();
    for (int s = tid; s < total; s += 256) {
        int b = stb[s];
        pairbuf[gbase[b] + (s - basel[b])] = stage[s];   // contiguous runs -> full-line writes
    }
}

// one block per bucket: LDS hist + scan -> offs/eend/dinv/s, then in-bucket scatter (L2-local)
__global__ __launch_bounds__(512) void build_csr_k(const unsigned* __restrict__ pairbuf,
                                                   const int* __restrict__ gcur,
                                                   const float* __restrict__ x,
                                                   int* __restrict__ offs, int* __restrict__ eend,
                                                   float* __restrict__ dinv, float* __restrict__ s,
                                                   int* __restrict__ csr, int N) {
    __shared__ int hist[BN];
    __shared__ int cur[BN];
    __shared__ int ps[BN];
    int b = blockIdx.x, tid = threadIdx.x;
    int node0 = b << SHIFT;
    int e0 = b * CAP, e1 = e0 + gcur[b];
    hist[tid] = 0;
    __syncthreads();
    for (int p = e0 + tid; p < e1; p += 512)
        atomicAdd(&hist[pairbuf[p] >> 17], 1);
    __syncthreads();
    int v0 = hist[tid];
    ps[tid] = v0;
    __syncthreads();
    for (int off = 1; off < BN; off <<= 1) {
        int t = (tid >= off) ? ps[tid - off] : 0;
        __syncthreads();
        ps[tid] += t;
        __syncthreads();
    }
    int g0 = e0 + ps[tid] - v0;
    int n0 = node0 + tid;
    if (n0 < N) {
        float d = rsqrtf((float)(v0 + 1));
        offs[n0] = g0;
        eend[n0] = g0 + v0;
        dinv[n0] = d;
        s[n0] = x[n0] * d;      // fused s_k
    }
    cur[tid] = g0;
    __syncthreads();
    for (int p = e0 + tid; p < e1; p += 512) {
        unsigned v = pairbuf[p];
        int pos = atomicAdd(&cur[v >> 17], 1);
        csr[pos] = (int)(v & 0x1FFFFu);
    }
}

// ---------------- layer 1: t_i = dinv_i*(s_i + sum s_src); emits (t, dinv) pairs ----------------

__global__ void agg1_k(const float* __restrict__ s, const int* __restrict__ offs,
                       const int* __restrict__ eend, const int* __restrict__ csr,
                       const float* __restrict__ dinv, float2* __restrict__ td, int n) {
    int i = blockIdx.x * blockDim.x + threadIdx.x;
    if (i >= n) return;
    float sum = s[i];
    int e0 = offs[i], e1 = eend[i];
    float a0 = 0.f, a1 = 0.f, a2 = 0.f, a3 = 0.f;
    int p = e0;
    for (; p + 4 <= e1; p += 4) {
        a0 += s[csr[p]]; a1 += s[csr[p + 1]]; a2 += s[csr[p + 2]]; a3 += s[csr[p + 3]];
    }
    for (; p < e1; ++p) sum += s[csr[p]];
    sum += (a0 + a1) + (a2 + a3);
    float d = dinv[i];
    td[i] = make_float2(sum * d, d);
}

// ------- per-edge operand materialization: etd[p] = td[csr[p]] (csr-aligned) -------
// Breaks l2_agg's dependent gather chain: coalesced csr read, random 8B gathers from the
// 800 KB L2-resident td table (4 independent in flight/thread), coalesced etd write.

__global__ __launch_bounds__(256) void gather_td_k(const int* __restrict__ csr,
                                                   const float2* __restrict__ td,
                                                   const int* __restrict__ gcur,
                                                   float2* __restrict__ etd) {
    int b = blockIdx.x >> 2;
    int k = blockIdx.x & 3;
    int base = b * CAP + k * (CAP / 4);
    int e1 = b * CAP + gcur[b];
    int hi = base + (CAP / 4); if (hi > e1) hi = e1;
    for (int p0 = base; p0 < hi; p0 += 1024) {
        int p = p0 + threadIdx.x;
        bool m0 = (p < hi), m1 = (p + 256 < hi), m2 = (p + 512 < hi), m3 = (p + 768 < hi);
        int i0 = m0 ? csr[p] : 0;
        int i1 = m1 ? csr[p + 256] : 0;
        int i2 = m2 ? csr[p + 512] : 0;
        int i3 = m3 ? csr[p + 768] : 0;
        float2 v0 = td[i0];
        float2 v1 = td[i1];
        float2 v2 = td[i2];
        float2 v3 = td[i3];
        if (m0) etd[p] = v0;
        if (m1) etd[p + 256] = v1;
        if (m2) etd[p + 512] = v2;
        if (m3) etd[p + 768] = v3;
    }
}

// ------- layer-2 fused aggregation over SCALARS (aggregate-then-GEMM algebra) -------
// U2_i = dinv_i * sum_{j in N(i)+self} dinv_j * relu(t_j*w1 + b1)
// Streams the csr-aligned etd operand array: no indirection, no random address math;
// wave issue slots go to the rank-1 fma/max/fma work.

__global__ __launch_bounds__(256) void l2_agg_k(const float2* __restrict__ td,
                                                const float2* __restrict__ etd,
                                                const int* __restrict__ offs,
                                                const int* __restrict__ eend,
                                                const float* __restrict__ w1,
                                                const float* __restrict__ b1,
                                                float* __restrict__ U, int n) {
    int node = blockIdx.x * 4 + (threadIdx.x >> 6);
    int lane = threadIdx.x & 63;
    if (node >= n) return;
    float wa = w1[lane],      wb = w1[lane + 64];
    float ba = b1[lane],      bb = b1[lane + 64];
    float2 self = td[node];
    float sa = fmaxf(fmaf(self.x, wa, ba), 0.f) * self.y;
    float sb = fmaxf(fmaf(self.x, wb, bb), 0.f) * self.y;
    const float2* ep = etd + offs[node];
    int cnt = eend[node] - offs[node];
    int p = 0;
    for (; p + 8 <= cnt; p += 8) {
        float2 v[8];
        #pragma unroll
        for (int u = 0; u < 8; ++u) v[u] = ep[p + u];
        #pragma unroll
        for (int u = 0; u < 8; ++u) {
            sa = fmaf(fmaxf(fmaf(v[u].x, wa, ba), 0.f), v[u].y, sa);
            sb = fmaf(fmaxf(fmaf(v[u].x, wb, bb), 0.f), v[u].y, sb);
        }
    }
    for (; p < cnt; ++p) {
        float2 v = ep[p];
        sa = fmaf(fmaxf(fmaf(v.x, wa, ba), 0.f), v.y, sa);
        sb = fmaf(fmaxf(fmaf(v.x, wb, bb), 0.f), v.y, sb);
    }
    float d = self.y;
    U[(size_t)node * H + lane]      = sa * d;
    U[(size_t)node * H + lane + 64] = sb * d;
}

// ---- conflict-free W staging: WT[cc][k][j], stride CSTRIDE per cc ----

__device__ __forceinline__ void stage_WT(const float* __restrict__ W, float* __restrict__ WT) {
    for (int idx = threadIdx.x; idx < H * H / 4; idx += 256) {
        float4 v = ((const float4*)W)[idx];
        int k  = idx >> 5;
        int c4 = idx & 31;
        int cc = c4 >> 2;
        int j  = (c4 & 3) * 4;
        *(float4*)(WT + cc * CSTRIDE + k * 16 + j) = v;
    }
}

// ------- GEMM with post-activation row scale: Z2h = fp16( pscale[row] * relu(in@W + bias) ) -------
// in: row-major fp32 [n][H].  out: row-major fp16 [n][H] (256 B rows -> half the gather
// line-requests and half the L2-fill bytes for agg3h).

__global__ __launch_bounds__(256) void gemm_post_k(const float* __restrict__ in, const float* __restrict__ W,
                                                   const float* __restrict__ bias, const float* __restrict__ pscale,
                                                   __half* __restrict__ out, int n) {
    __shared__ float WT[8 * CSTRIDE];
    stage_WT(W, WT);
    __syncthreads();
    const int cc = threadIdx.x & 7;
    const int rg = threadIdx.x >> 3;
    const int c0 = cc * 16;
    const int row0 = blockIdx.x * 128 + rg * 4;
    const float* wt = WT + cc * CSTRIDE;

    const float* p[4];
    #pragma unroll
    for (int r = 0; r < 4; ++r) {
        int rr = row0 + r; if (rr > n - 1) rr = n - 1;
        p[r] = in + (size_t)rr * H;
    }

    float acc[4][16];
    #pragma unroll
    for (int r = 0; r < 4; ++r)
        #pragma unroll
        for (int j = 0; j < 16; ++j) acc[r][j] = 0.f;

    for (int k4 = 0; k4 < H / 4; ++k4) {
        float4 a[4];
        #pragma unroll
        for (int r = 0; r < 4; ++r) a[r] = *(const float4*)(p[r] + k4 * 4);
        #pragma unroll
        for (int kk = 0; kk < 4; ++kk) {
            const float* wb = wt + (k4 * 4 + kk) * 16;
            float w[16];
            *(float4*)(w + 0)  = *(const float4*)(wb + 0);
            *(float4*)(w + 4)  = *(const float4*)(wb + 4);
            *(float4*)(w + 8)  = *(const float4*)(wb + 8);
            *(float4*)(w + 12) = *(const float4*)(wb + 12);
            float av[4];
            #pragma unroll
            for (int r = 0; r < 4; ++r) av[r] = ((const float*)&a[r])[kk];
            #pragma unroll
            for (int r = 0; r < 4; ++r)
                #pragma unroll
                for (int j = 0; j < 16; ++j)
                    acc[r][j] = fmaf(av[r], w[j], acc[r][j]);
        }
    }

    #pragma unroll
    for (int r = 0; r < 4; ++r) {
        int row = row0 + r;
        if (row < n) {
            float sc = pscale[row];
            __half2 hb[8];
            #pragma unroll
            for (int j4 = 0; j4 < 4; ++j4) {
                float ox = fmaxf(acc[r][j4 * 4 + 0] + bias[c0 + j4 * 4 + 0], 0.f) * sc;
                float oy = fmaxf(acc[r][j4 * 4 + 1] + bias[c0 + j4 * 4 + 1], 0.f) * sc;
                float oz = fmaxf(acc[r][j4 * 4 + 2] + bias[c0 + j4 * 4 + 2], 0.f) * sc;
                float ow = fmaxf(acc[r][j4 * 4 + 3] + bias[c0 + j4 * 4 + 3], 0.f) * sc;
                hb[j4 * 2 + 0] = __floats2half2_rn(ox, oy);
                hb[j4 * 2 + 1] = __floats2half2_rn(oz, ow);
            }
            __half* orow = out + (size_t)row * H + c0;
            *(uint4*)(orow + 0) = *(uint4*)&hb[0];
            *(uint4*)(orow + 8) = *(uint4*)&hb[4];
        }
    }
}

// ------- whole-wave gather of one node's neighbor-row sum (fp16 rows, fp32 accumulate) -------
// Row = 128 halves = 256 B; lane l of 32 reads 8 B (halves 4l..4l+3) -> 2 line-requests/row,
// 2 rows per wave instruction. 8 independent loads in flight per slot group.

__device__ __forceinline__ void acc_h(float4& a, uint2 r) {
    __half2 h0 = *(__half2*)&r.x;
    __half2 h1 = *(__half2*)&r.y;
    float2 f0 = __half22float2(h0);
    float2 f1 = __half22float2(h1);
    a.x += f0.x; a.y += f0.y; a.z += f1.x; a.w += f1.y;
}

__device__ __forceinline__ float4 gather_row_sum_h(const uint2* __restrict__ hrow,
                                                   const int* __restrict__ csr,
                                                   int node, int e0, int e1, int half, int l) {
    float4 acc[8];
    #pragma unroll
    for (int u = 0; u < 8; ++u) acc[u] = make_float4(0.f, 0.f, 0.f, 0.f);
    if (half == 0) {                                  // self loop
        uint2 rs = hrow[(size_t)node * 32 + l];
        acc_h(acc[0], rs);
    }
    int q = e0;
    for (; q + 15 < e1; q += 16) {
        int idx[8];
        #pragma unroll
        for (int u = 0; u < 8; ++u) idx[u] = csr[q + 2 * u + half];
        uint2 raw[8];
        #pragma unroll
        for (int u = 0; u < 8; ++u) raw[u] = hrow[(size_t)idx[u] * 32 + l];
        #pragma unroll
        for (int u = 0; u < 8; ++u) acc_h(acc[u], raw[u]);
    }
    for (; q + 7 < e1; q += 8) {
        int idx[4];
        #pragma unroll
        for (int u = 0; u < 4; ++u) idx[u] = csr[q + 2 * u + half];
        uint2 raw[4];
        #pragma unroll
        for (int u = 0; u < 4; ++u) raw[u] = hrow[(size_t)idx[u] * 32 + l];
        #pragma unroll
        for (int u = 0; u < 4; ++u) acc_h(acc[u], raw[u]);
    }
    for (; q < e1; q += 2) {
        int off = q + half;
        if (off < e1) {
            uint2 raw = hrow[(size_t)csr[off] * 32 + l];
            acc_h(acc[0], raw);
        }
    }
    float4 sum;
    sum.x = ((acc[0].x + acc[1].x) + (acc[2].x + acc[3].x)) + ((acc[4].x + acc[5].x) + (acc[6].x + acc[7].x));
    sum.y = ((acc[0].y + acc[1].y) + (acc[2].y + acc[3].y)) + ((acc[4].y + acc[5].y) + (acc[6].y + acc[7].y));
    sum.z = ((acc[0].z + acc[1].z) + (acc[2].z + acc[3].z)) + ((acc[4].z + acc[5].z) + (acc[6].z + acc[7].z));
    sum.w = ((acc[0].w + acc[1].w) + (acc[2].w + acc[3].w)) + ((acc[4].w + acc[5].w) + (acc[6].w + acc[7].w));
    sum.x += __shfl_xor(sum.x, 32);
    sum.y += __shfl_xor(sum.y, 32);
    sum.z += __shfl_xor(sum.z, 32);
    sum.w += __shfl_xor(sum.w, 32);
    return sum;
}

// ------- layer-3 aggregation of fp16 Z2 rows: U3_i = dinv_i * (Z2_i + sum Z2_src) [fp32 out] -------

__global__ __launch_bounds__(256) void agg3h_k(const uint2* __restrict__ Zh, const int* __restrict__ offs,
                                               const int* __restrict__ eend, const int* __restrict__ csr,
                                               const float* __restrict__ dinv,
                                               float* __restrict__ U, int n) {
    int node = blockIdx.x * 4 + (threadIdx.x >> 6);
    int lane = threadIdx.x & 63;
    int half = lane >> 5;
    int l = lane & 31;
    if (node >= n) return;
    float4 sum = gather_row_sum_h(Zh, csr, node, offs[node], eend[node], half, l);
    if (half == 0) {
        float d = dinv[node];
        float4 o;
        o.x = sum.x * d; o.y = sum.y * d; o.z = sum.z * d; o.w = sum.w * d;
        ((float4*)U)[(size_t)node * 32 + l] = o;
    }
}

// ------- layer-3 GEMM: h3 = relu(U3@W3 + b3) [fp32 row-major in/out] -------

__global__ __launch_bounds__(256) void gemm_k(const float* __restrict__ in, const float* __restrict__ W,
                                              const float* __restrict__ bias,
                                              float* __restrict__ out, int n) {
    __shared__ float WT[8 * CSTRIDE];
    stage_WT(W, WT);
    __syncthreads();
    const int cc = threadIdx.x & 7;
    const int rg = threadIdx.x >> 3;
    const int c0 = cc * 16;
    const int row0 = blockIdx.x * 128 + rg * 4;
    const float* wt = WT + cc * CSTRIDE;

    const float* p[4];
    #pragma unroll
    for (int r = 0; r < 4; ++r) {
        int rr = row0 + r; if (rr > n - 1) rr = n - 1;
        p[r] = in + (size_t)rr * H;
    }

    float acc[4][16];
    #pragma unroll
    for (int r = 0; r < 4; ++r)
        #pragma unroll
        for (int j = 0; j < 16; ++j) acc[r][j] = 0.f;

    for (int k4 = 0; k4 < H / 4; ++k4) {
        float4 a[4];
        #pragma unroll
        for (int r = 0; r < 4; ++r) a[r] = *(const float4*)(p[r] + k4 * 4);
        #pragma unroll
        for (int kk = 0; kk < 4; ++kk) {
            const float* wb = wt + (k4 * 4 + kk) * 16;
            float w[16];
            *(float4*)(w + 0)  = *(const float4*)(wb + 0);
            *(float4*)(w + 4)  = *(const float4*)(wb + 4);
            *(float4*)(w + 8)  = *(const float4*)(wb + 8);
            *(float4*)(w + 12) = *(const float4*)(wb + 12);
            float av[4];
            #pragma unroll
            for (int r = 0; r < 4; ++r) av[r] = ((const float*)&a[r])[kk];
            #pragma unroll
            for (int r = 0; r < 4; ++r)
                #pragma unroll
                for (int j = 0; j < 16; ++j)
                    acc[r][j] = fmaf(av[r], w[j], acc[r][j]);
        }
    }

    #pragma unroll
    for (int r = 0; r < 4; ++r) {
        int row = row0 + r;
        if (row < n) {
            float* orow = out + (size_t)row * H + c0;
            #pragma unroll
            for (int j4 = 0; j4 < 4; ++j4) {
                float4 o;
                o.x = fmaxf(acc[r][j4 * 4 + 0] + bias[c0 + j4 * 4 + 0], 0.f);
                o.y = fmaxf(acc[r][j4 * 4 + 1] + bias[c0 + j4 * 4 + 1], 0.f);
                o.z = fmaxf(acc[r][j4 * 4 + 2] + bias[c0 + j4 * 4 + 2], 0.f);
                o.w = fmaxf(acc[r][j4 * 4 + 3] + bias[c0 + j4 * 4 + 3], 0.f);
                *(float4*)(orow + j4 * 4) = o;
            }
        }
    }
}

// ---------------- pooling (binary search over sorted batch ids; overwrite, no atomics) --------

__global__ __launch_bounds__(128) void pool_k(const float* __restrict__ h, const int* __restrict__ batch,
                                              float* __restrict__ P, int n, int G) {
    int g = blockIdx.x, f = threadIdx.x;
    int lo = 0, hi = n;
    while (lo < hi) { int m = (lo + hi) >> 1; if (batch[m] < g) lo = m + 1; else hi = m; }
    int s0 = lo;
    hi = n;
    while (lo < hi) { int m = (lo + hi) >> 1; if (batch[m] < g + 1) lo = m + 1; else hi = m; }
    int s1 = lo;
    float a0 = 0.f, a1 = 0.f, a2 = 0.f, a3 = 0.f;
    int i = s0;
    for (; i + 4 <= s1; i += 4) {
        a0 += h[(size_t)i * H + f];
        a1 += h[(size_t)(i + 1) * H + f];
        a2 += h[(size_t)(i + 2) * H + f];
        a3 += h[(size_t)(i + 3) * H + f];
    }
    for (; i < s1; ++i) a0 += h[(size_t)i * H + f];
    float sum = (a0 + a1) + (a2 + a3);
    float c = (float)(s1 - s0); if (c < 1.f) c = 1.f;
    P[(size_t)g * H + f] = sum / c;
}

// ------- fused MLP head: relu(@Wl1+bl1) + relu(@Wl2+bl2) + dot Wl3 + bl3 -------

__global__ __launch_bounds__(256) void head_k(const float* __restrict__ P,
                                              const float* __restrict__ Wl1, const float* __restrict__ bl1,
                                              const float* __restrict__ Wl2, const float* __restrict__ bl2,
                                              const float* __restrict__ Wl3, const float* __restrict__ bl3,
                                              float* __restrict__ out, int G) {
    __shared__ float Wb[H * H];
    __shared__ float Tl[H * 133];
    __shared__ float w3l[H];
    int tid = threadIdx.x;
    int g0 = blockIdx.x * 128;

    if (tid < 128) w3l[tid] = Wl3[tid];
    for (int i = tid; i < H * H / 4; i += 256) ((float4*)Wb)[i] = ((const float4*)Wl1)[i];
    __syncthreads();

    const int cc = tid & 7, rg = tid >> 3, c0 = cc * 16;
    float acc[4][16];

    #pragma unroll
    for (int r = 0; r < 4; ++r)
        #pragma unroll
        for (int j = 0; j < 16; ++j) acc[r][j] = 0.f;
    const float4* P4 = (const float4*)P;
    for (int k4 = 0; k4 < H / 4; ++k4) {
        float4 a[4];
        #pragma unroll
        for (int r = 0; r < 4; ++r) a[r] = P4[(size_t)(g0 + rg * 4 + r) * 32 + k4];
        const float* wbase = Wb + (k4 * 4) * H + c0;
        #pragma unroll
        for (int kk = 0; kk < 4; ++kk) {
            float w[16];
            *(float4*)(w + 0)  = *(const float4*)(wbase + kk * H + 0);
            *(float4*)(w + 4)  = *(const float4*)(wbase + kk * H + 4);
            *(float4*)(w + 8)  = *(const float4*)(wbase + kk * H + 8);
            *(float4*)(w + 12) = *(const float4*)(wbase + kk * H + 12);
            float av[4];
            #pragma unroll
            for (int r = 0; r < 4; ++r) av[r] = ((const float*)&a[r])[kk];
            #pragma unroll
            for (int r = 0; r < 4; ++r)
                #pragma unroll
                for (int j = 0; j < 16; ++j)
                    acc[r][j] = fmaf(av[r], w[j], acc[r][j]);
        }
    }
    #pragma unroll
    for (int r = 0; r < 4; ++r) {
        int rl = rg * 4 + r;
        #pragma unroll
        for (int j = 0; j < 16; ++j)
            Tl[rl * 133 + c0 + j] = fmaxf(acc[r][j] + bl1[c0 + j], 0.f);
    }
    __syncthreads();
    for (int i = tid; i < H * H / 4; i += 256) ((float4*)Wb)[i] = ((const float4*)Wl2)[i];
    __syncthreads();

    #pragma unroll
    for (int r = 0; r < 4; ++r)
        #pragma unroll
        for (int j = 0; j < 16; ++j) acc[r][j] = 0.f;
    for (int k4 = 0; k4 < H / 4; ++k4) {
        float4 a[4];
        #pragma unroll
        for (int r = 0; r < 4; ++r) a[r] = *(const float4*)(Tl + (rg * 4 + r) * 133 + k4 * 4);
        const float* wbase = Wb + (k4 * 4) * H + c0;
        #pragma unroll
        for (int kk = 0; kk < 4; ++kk) {
            float w[16];
            *(float4*)(w + 0)  = *(const float4*)(wbase + kk * H + 0);
            *(float4*)(w + 4)  = *(const float4*)(wbase + kk * H + 4);
            *(float4*)(w + 8)  = *(const float4*)(wbase + kk * H + 8);
            *(float4*)(w + 12) = *(const float4*)(wbase + kk * H + 12);
            float av[4];
            #pragma unroll
            for (int r = 0; r < 4; ++r) av[r] = ((const float*)&a[r])[kk];
            #pragma unroll
            for (int r = 0; r < 4; ++r)
                #pragma unroll
                for (int j = 0; j < 16; ++j)
                    acc[r][j] = fmaf(av[r], w[j], acc[r][j]);
        }
    }
    float part[4];
    #pragma unroll
    for (int r = 0; r < 4; ++r) {
        float s = 0.f;
        #pragma unroll
        for (int j = 0; j < 16; ++j)
            s += fmaxf(acc[r][j] + bl2[c0 + j], 0.f) * w3l[c0 + j];
        part[r] = s;
    }
    #pragma unroll
    for (int off = 1; off < 8; off <<= 1)
        #pragma unroll
        for (int r = 0; r < 4; ++r) part[r] += __shfl_xor(part[r], off);
    if (cc == 0) {
        float bb = bl3[0];
        #pragma unroll
        for (int r = 0; r < 4; ++r) out[g0 + rg * 4 + r] = part[r] + bb;
    }
}

// ---------------- launch ----------------

extern "C" void kernel_launch(void* const* d_in, const int* in_sizes, int n_in,
                              void* d_out, int out_size, void* d_ws, size_t ws_size,
                              hipStream_t stream) {
    const float* x     = (const float*)d_in[0];
    const int*   ei    = (const int*)d_in[1];
    const int*   batch = (const int*)d_in[2];
    const float* W1  = (const float*)d_in[3];  const float* b1  = (const float*)d_in[4];
    const float* W2  = (const float*)d_in[5];  const float* b2  = (const float*)d_in[6];
    const float* W3  = (const float*)d_in[7];  const float* b3  = (const float*)d_in[8];
    const float* Wl1 = (const float*)d_in[9];  const float* bl1 = (const float*)d_in[10];
    const float* Wl2 = (const float*)d_in[11]; const float* bl2 = (const float*)d_in[12];
    const float* Wl3 = (const float*)d_in[13]; const float* bl3 = (const float*)d_in[14];

    const int N = in_sizes[0];
    const int E = in_sizes[1] / 2;
    const int G = out_size;
    const int* srcp = ei;
    const int* dstp = ei + E;
    const int NB = (N + BN - 1) / BN;    // 196 for N=100000

    char* w = (char*)d_ws;
    size_t off = 0;
    auto alloc = [&](size_t bytes) -> void* {
        void* p = w + off;
        off += (bytes + 255) & ~(size_t)255;
        return p;
    };
    int*    gcur   = (int*)alloc((size_t)MAXNB * 4);
    int*    offs   = (int*)alloc((size_t)N * 4);
    int*    eend   = (int*)alloc((size_t)N * 4);
    int*    csr    = (int*)alloc((size_t)NB * CAP * 4);   // bucket-padded
    float*  dinv   = (float*)alloc((size_t)N * 4);
    float*  sbuf   = (float*)alloc((size_t)N * 4);
    float2* td     = (float2*)alloc((size_t)N * 8);
    float*  A      = (float*)alloc((size_t)N * H * 4);   // U2 (fp32), then U3 (fp32)
    float*  B      = (float*)alloc((size_t)N * H * 4);   // pairbuf/etd, then Z2h (fp16), then h3
    float*  P      = (float*)alloc((size_t)G * H * 4);   // pooled means
    unsigned* pairbuf = (unsigned*)B;   // alias (NB*CAP*4 = 12.9 MB << N*H*4)
    float2*   etd     = (float2*)B;    // alias (NB*CAP*8 = 25.7 MB; live gather_td -> l2_agg)
    __half*   Z2h     = (__half*)B;    // alias (N*H*2 = 25.6 MB, written after etd is dead)
    (void)ws_size; (void)n_in;

    // --- graph build (slack buckets: no histogram pass) ---
    hipMemsetAsync(gcur, 0, (size_t)MAXNB * 4, stream);
    scatter_pairs_k<<<(E + CHUNK - 1) / CHUNK, 256, 0, stream>>>(srcp, dstp, gcur, pairbuf, E, NB);
    build_csr_k<<<NB, 512, 0, stream>>>(pairbuf, gcur, x, offs, eend, dinv, sbuf, csr, N);

    // --- layer 1 (scalar feature) ---
    agg1_k<<<(N + 255) / 256, 256, 0, stream>>>(sbuf, offs, eend, csr, dinv, td, N);

    // --- layer 2: materialize per-edge (t,d), stream-aggregate, then GEMM (fp16 Z2 out) ---
    gather_td_k<<<NB * 4, 256, 0, stream>>>(csr, td, gcur, etd);
    l2_agg_k<<<(N + 3) / 4, 256, 0, stream>>>(td, etd, offs, eend, W1, b1, A, N);
    gemm_post_k<<<(N + 127) / 128, 256, 0, stream>>>(A, W2, b2, dinv, Z2h, N);  // B = Z2h (fp16)

    // --- layer 3: fp16 row-gather aggregation, GEMM, pool ---
    agg3h_k<<<(N + 3) / 4, 256, 0, stream>>>((const uint2*)Z2h, offs, eend, csr, dinv, A, N); // A = U3
    gemm_k<<<(N + 127) / 128, 256, 0, stream>>>(A, W3, b3, B, N);              // B = h3 (fp32)
    pool_k<<<G, 128, 0, stream>>>(B, batch, P, N, G);

    // --- fused MLP head ---
    head_k<<<(G + 127) / 128, 256, 0, stream>>>(P, Wl1, bl1, Wl2, bl2, Wl3, bl3,
                                                (float*)d_out, G);
}

// Round 5
// 393.528 us; speedup vs baseline: 1.8912x; 1.1285x over previous
//
#include <hip/hip_runtime.h>
#include <hip/hip_fp16.h>

#define H 128
#define SHIFT 9             // nodes per coarse bucket = 512
#define BN 512
#define MAXNB 256           // max coarse buckets (N <= 131072)
#define CHUNK 4096          // edges per scatter block
#define CAP 16384           // slack capacity per bucket (exp 8192, sigma ~90)

typedef _Float16 half8 __attribute__((ext_vector_type(8)));
typedef _Float16 half4 __attribute__((ext_vector_type(4)));
typedef _Float16 half2t __attribute__((ext_vector_type(2)));
typedef float f32x4 __attribute__((ext_vector_type(4)));

// ============ graph build: slack-bucket counting sort (no global histogram pass) ============
// Packing: src < 2^17, local node < 512 -> record = (local<<17)|src fits u32.
// Bucket b owns pairbuf/csr region [b*CAP, (b+1)*CAP); gcur[b] (memset 0) allocates within.

__global__ __launch_bounds__(256) void scatter_pairs_k(const int* __restrict__ src,
                                                       const int* __restrict__ dst,
                                                       int* __restrict__ gcur,
                                                       unsigned* __restrict__ pairbuf,
                                                       int E, int NBv) {
    __shared__ unsigned stage[CHUNK];
    __shared__ unsigned char stb[CHUNK];
    __shared__ int hist[MAXNB], basel[MAXNB], cur[MAXNB], gbase[MAXNB];
    __shared__ int total;
    int tid = threadIdx.x;
    int base = blockIdx.x * CHUNK;

    int mysrc[16], mydst[16];
    #pragma unroll
    for (int i = 0; i < 16; ++i) {
        int e = base + i * 256 + tid;
        if (e < E) { mysrc[i] = src[e]; mydst[i] = dst[e]; } else mydst[i] = -1;
    }
    hist[tid] = 0;
    __syncthreads();
    #pragma unroll
    for (int i = 0; i < 16; ++i)
        if (mydst[i] >= 0) atomicAdd(&hist[mydst[i] >> SHIFT], 1);
    __syncthreads();
    if (tid == 0) {
        int run = 0;
        for (int b = 0; b < NBv; ++b) { basel[b] = run; run += hist[b]; }
        total = run;
    }
    __syncthreads();
    if (tid < NBv) {
        cur[tid] = basel[tid];
        if (hist[tid] > 0) gbase[tid] = tid * CAP + atomicAdd(&gcur[tid], hist[tid]);
    }
    __syncthreads();
    #pragma unroll
    for (int i = 0; i < 16; ++i)
        if (mydst[i] >= 0) {
            int b = mydst[i] >> SHIFT;
            int slot = atomicAdd(&cur[b], 1);
            stage[slot] = ((unsigned)(mydst[i] & (BN - 1)) << 17) | (unsigned)mysrc[i];
            stb[slot] = (unsigned char)b;
        }
    __syncthreads();
    for (int s = tid; s < total; s += 256) {
        int b = stb[s];
        pairbuf[gbase[b] + (s - basel[b])] = stage[s];   // contiguous runs -> full-line writes
    }
}

// one block per bucket: LDS hist + scan -> offs/eend/dinv/s, then in-bucket scatter (L2-local)
__global__ __launch_bounds__(512) void build_csr_k(const unsigned* __restrict__ pairbuf,
                                                   const int* __restrict__ gcur,
                                                   const float* __restrict__ x,
                                                   int* __restrict__ offs, int* __restrict__ eend,
                                                   float* __restrict__ dinv, float* __restrict__ s,
                                                   int* __restrict__ csr, int N) {
    __shared__ int hist[BN];
    __shared__ int cur[BN];
    __shared__ int ps[BN];
    int b = blockIdx.x, tid = threadIdx.x;
    int node0 = b << SHIFT;
    int e0 = b * CAP, e1 = e0 + gcur[b];
    hist[tid] = 0;
    __syncthreads();
    for (int p = e0 + tid; p < e1; p += 512)
        atomicAdd(&hist[pairbuf[p] >> 17], 1);
    __syncthreads();
    int v0 = hist[tid];
    ps[tid] = v0;
    __syncthreads();
    for (int off = 1; off < BN; off <<= 1) {
        int t = (tid >= off) ? ps[tid - off] : 0;
        __syncthreads();
        ps[tid] += t;
        __syncthreads();
    }
    int g0 = e0 + ps[tid] - v0;
    int n0 = node0 + tid;
    if (n0 < N) {
        float d = rsqrtf((float)(v0 + 1));
        offs[n0] = g0;
        eend[n0] = g0 + v0;
        dinv[n0] = d;
        s[n0] = x[n0] * d;      // fused s_k
    }
    cur[tid] = g0;
    __syncthreads();
    for (int p = e0 + tid; p < e1; p += 512) {
        unsigned v = pairbuf[p];
        int pos = atomicAdd(&cur[v >> 17], 1);
        csr[pos] = (int)(v & 0x1FFFFu);
    }
}

// ---------------- layer 1: t_i = dinv_i*(s_i + sum s_src); emits (t, dinv) pairs ----------------

__global__ void agg1_k(const float* __restrict__ s, const int* __restrict__ offs,
                       const int* __restrict__ eend, const int* __restrict__ csr,
                       const float* __restrict__ dinv, float2* __restrict__ td, int n) {
    int i = blockIdx.x * blockDim.x + threadIdx.x;
    if (i >= n) return;
    float sum = s[i];
    int e0 = offs[i], e1 = eend[i];
    float a0 = 0.f, a1 = 0.f, a2 = 0.f, a3 = 0.f;
    int p = e0;
    for (; p + 4 <= e1; p += 4) {
        a0 += s[csr[p]]; a1 += s[csr[p + 1]]; a2 += s[csr[p + 2]]; a3 += s[csr[p + 3]];
    }
    for (; p < e1; ++p) sum += s[csr[p]];
    sum += (a0 + a1) + (a2 + a3);
    float d = dinv[i];
    td[i] = make_float2(sum * d, d);
}

// ------- per-edge operand materialization: etd[p] = td[csr[p]] (csr-aligned) -------

__global__ __launch_bounds__(256) void gather_td_k(const int* __restrict__ csr,
                                                   const float2* __restrict__ td,
                                                   const int* __restrict__ gcur,
                                                   float2* __restrict__ etd) {
    int b = blockIdx.x >> 2;
    int k = blockIdx.x & 3;
    int base = b * CAP + k * (CAP / 4);
    int e1 = b * CAP + gcur[b];
    int hi = base + (CAP / 4); if (hi > e1) hi = e1;
    for (int p0 = base; p0 < hi; p0 += 1024) {
        int p = p0 + threadIdx.x;
        bool m0 = (p < hi), m1 = (p + 256 < hi), m2 = (p + 512 < hi), m3 = (p + 768 < hi);
        int i0 = m0 ? csr[p] : 0;
        int i1 = m1 ? csr[p + 256] : 0;
        int i2 = m2 ? csr[p + 512] : 0;
        int i3 = m3 ? csr[p + 768] : 0;
        float2 v0 = td[i0];
        float2 v1 = td[i1];
        float2 v2 = td[i2];
        float2 v3 = td[i3];
        if (m0) etd[p] = v0;
        if (m1) etd[p + 256] = v1;
        if (m2) etd[p + 512] = v2;
        if (m3) etd[p + 768] = v3;
    }
}

// ------- layer-2 fused aggregation over SCALARS; fp16 U2 out -------
// U2_i = dinv_i * sum_{j in N(i)+self} dinv_j * relu(t_j*w1 + b1)

__global__ __launch_bounds__(256) void l2_agg_k(const float2* __restrict__ td,
                                                const float2* __restrict__ etd,
                                                const int* __restrict__ offs,
                                                const int* __restrict__ eend,
                                                const float* __restrict__ w1,
                                                const float* __restrict__ b1,
                                                _Float16* __restrict__ Uh, int n) {
    int node = blockIdx.x * 4 + (threadIdx.x >> 6);
    int lane = threadIdx.x & 63;
    if (node >= n) return;
    float wa = w1[lane],      wb = w1[lane + 64];
    float ba = b1[lane],      bb = b1[lane + 64];
    float2 self = td[node];
    float sa = fmaxf(fmaf(self.x, wa, ba), 0.f) * self.y;
    float sb = fmaxf(fmaf(self.x, wb, bb), 0.f) * self.y;
    const float2* ep = etd + offs[node];
    int cnt = eend[node] - offs[node];
    int p = 0;
    for (; p + 8 <= cnt; p += 8) {
        float2 v[8];
        #pragma unroll
        for (int u = 0; u < 8; ++u) v[u] = ep[p + u];
        #pragma unroll
        for (int u = 0; u < 8; ++u) {
            sa = fmaf(fmaxf(fmaf(v[u].x, wa, ba), 0.f), v[u].y, sa);
            sb = fmaf(fmaxf(fmaf(v[u].x, wb, bb), 0.f), v[u].y, sb);
        }
    }
    for (; p < cnt; ++p) {
        float2 v = ep[p];
        sa = fmaf(fmaxf(fmaf(v.x, wa, ba), 0.f), v.y, sa);
        sb = fmaf(fmaxf(fmaf(v.x, wb, bb), 0.f), v.y, sb);
    }
    float d = self.y;
    Uh[(size_t)node * H + lane]      = (_Float16)(sa * d);
    Uh[(size_t)node * H + lane + 64] = (_Float16)(sb * d);
}

// ------- MFMA GEMM (f16 in, f16 out, fp32 accum): out = [pscale] * relu(in @ W + bias) -------
// v_mfma_f32_16x16x32_f16 layouts (m89-verified C/D; AMD lab-notes A/B):
//   A: row = lane&15, k = 8*(lane>>4)+j   (16 B contiguous from row-major fp16 in)
//   B: col = lane&15, k = 8*(lane>>4)+j   (16 B contiguous from LDS W^T [col][k], stride 136)
//   D: col = lane&15, row = 4*(lane>>4)+reg
// Block: 4 waves x 16 rows = 64 rows, full N=128. LDS out re-stage for coalesced stores.

__global__ __launch_bounds__(256) void gemm_h_k(const _Float16* __restrict__ in,
                                                const float* __restrict__ W,
                                                const float* __restrict__ bias,
                                                const float* __restrict__ pscale,
                                                _Float16* __restrict__ out, int n) {
    __shared__ _Float16 WT[128 * 136];   // [col][k], +8 pad: ds_read_b128 2-way banks (free)
    __shared__ _Float16 OT[64 * 136];    // out tile re-stage, same padded stride
    __shared__ float bsh[H];

    // stage W^T fp16 (global W is [k][col] fp32 row-major)
    for (int idx = threadIdx.x; idx < 128 * 32; idx += 256) {
        int k  = idx >> 5;
        int c4 = (idx & 31) << 2;
        float4 v = *(const float4*)(W + k * H + c4);
        WT[(c4 + 0) * 136 + k] = (_Float16)v.x;
        WT[(c4 + 1) * 136 + k] = (_Float16)v.y;
        WT[(c4 + 2) * 136 + k] = (_Float16)v.z;
        WT[(c4 + 3) * 136 + k] = (_Float16)v.w;
    }
    if (threadIdx.x < H) bsh[threadIdx.x] = bias[threadIdx.x];
    __syncthreads();

    const int wave = threadIdx.x >> 6;
    const int l    = threadIdx.x & 63;
    const int lr   = l & 15;     // A-row / B-col / D-col within tile
    const int lk   = l >> 4;     // k sub-block (0..3)
    const int row0 = blockIdx.x * 64 + wave * 16;

    f32x4 acc[8];
    #pragma unroll
    for (int c = 0; c < 8; ++c) acc[c] = (f32x4){0.f, 0.f, 0.f, 0.f};

    int arow = row0 + lr; if (arow > n - 1) arow = n - 1;
    const _Float16* ap = in + (size_t)arow * H + lk * 8;

    #pragma unroll
    for (int ks = 0; ks < 4; ++ks) {
        half8 a = *(const half8*)(ap + ks * 32);
        #pragma unroll
        for (int c = 0; c < 8; ++c) {
            half8 b = *(const half8*)(WT + (c * 16 + lr) * 136 + ks * 32 + lk * 8);
            acc[c] = __builtin_amdgcn_mfma_f32_16x16x32_f16(a, b, acc[c], 0, 0, 0);
        }
    }

    // epilogue: bias + relu (+ pscale), fp16 into OT (2-way LDS banks from 136 stride)
    #pragma unroll
    for (int r = 0; r < 4; ++r) {
        int lrow = wave * 16 + lk * 4 + r;       // row within block tile
        int grow = blockIdx.x * 64 + lrow;
        float sc = 1.f;
        if (pscale) { int gr = grow > n - 1 ? n - 1 : grow; sc = pscale[gr]; }
        #pragma unroll
        for (int c = 0; c < 8; ++c) {
            float v = fmaxf(acc[c][r] + bsh[c * 16 + lr], 0.f) * sc;
            OT[lrow * 136 + c * 16 + lr] = (_Float16)v;
        }
    }
    __syncthreads();

    // coalesced fp16 row stores: 64 rows x 256 B = 16 uint4 per row
    for (int idx = threadIdx.x; idx < 64 * 16; idx += 256) {
        int row = idx >> 4;
        int gr = blockIdx.x * 64 + row;
        if (gr < n)
            ((uint4*)(out + (size_t)gr * H))[idx & 15] = ((const uint4*)(OT + row * 136))[idx & 15];
    }
}

// ------- whole-wave gather of one node's neighbor-row sum (fp16 rows, fp32 accumulate) -------

__device__ __forceinline__ void acc_h(float4& a, uint2 r) {
    __half2 h0 = *(__half2*)&r.x;
    __half2 h1 = *(__half2*)&r.y;
    float2 f0 = __half22float2(h0);
    float2 f1 = __half22float2(h1);
    a.x += f0.x; a.y += f0.y; a.z += f1.x; a.w += f1.y;
}

__device__ __forceinline__ float4 gather_row_sum_h(const uint2* __restrict__ hrow,
                                                   const int* __restrict__ csr,
                                                   int node, int e0, int e1, int half, int l) {
    float4 acc[8];
    #pragma unroll
    for (int u = 0; u < 8; ++u) acc[u] = make_float4(0.f, 0.f, 0.f, 0.f);
    if (half == 0) {                                  // self loop
        uint2 rs = hrow[(size_t)node * 32 + l];
        acc_h(acc[0], rs);
    }
    int q = e0;
    for (; q + 15 < e1; q += 16) {
        int idx[8];
        #pragma unroll
        for (int u = 0; u < 8; ++u) idx[u] = csr[q + 2 * u + half];
        uint2 raw[8];
        #pragma unroll
        for (int u = 0; u < 8; ++u) raw[u] = hrow[(size_t)idx[u] * 32 + l];
        #pragma unroll
        for (int u = 0; u < 8; ++u) acc_h(acc[u], raw[u]);
    }
    for (; q + 7 < e1; q += 8) {
        int idx[4];
        #pragma unroll
        for (int u = 0; u < 4; ++u) idx[u] = csr[q + 2 * u + half];
        uint2 raw[4];
        #pragma unroll
        for (int u = 0; u < 4; ++u) raw[u] = hrow[(size_t)idx[u] * 32 + l];
        #pragma unroll
        for (int u = 0; u < 4; ++u) acc_h(acc[u], raw[u]);
    }
    for (; q < e1; q += 2) {
        int off = q + half;
        if (off < e1) {
            uint2 raw = hrow[(size_t)csr[off] * 32 + l];
            acc_h(acc[0], raw);
        }
    }
    float4 sum;
    sum.x = ((acc[0].x + acc[1].x) + (acc[2].x + acc[3].x)) + ((acc[4].x + acc[5].x) + (acc[6].x + acc[7].x));
    sum.y = ((acc[0].y + acc[1].y) + (acc[2].y + acc[3].y)) + ((acc[4].y + acc[5].y) + (acc[6].y + acc[7].y));
    sum.z = ((acc[0].z + acc[1].z) + (acc[2].z + acc[3].z)) + ((acc[4].z + acc[5].z) + (acc[6].z + acc[7].z));
    sum.w = ((acc[0].w + acc[1].w) + (acc[2].w + acc[3].w)) + ((acc[4].w + acc[5].w) + (acc[6].w + acc[7].w));
    sum.x += __shfl_xor(sum.x, 32);
    sum.y += __shfl_xor(sum.y, 32);
    sum.z += __shfl_xor(sum.z, 32);
    sum.w += __shfl_xor(sum.w, 32);
    return sum;
}

// ------- layer-3 aggregation of fp16 Z2 rows: U3_i = dinv_i * (Z2_i + sum Z2_src) [fp16 out] -------

__global__ __launch_bounds__(256) void agg3h_k(const uint2* __restrict__ Zh, const int* __restrict__ offs,
                                               const int* __restrict__ eend, const int* __restrict__ csr,
                                               const float* __restrict__ dinv,
                                               _Float16* __restrict__ Uh, int n) {
    int node = blockIdx.x * 4 + (threadIdx.x >> 6);
    int lane = threadIdx.x & 63;
    int half = lane >> 5;
    int l = lane & 31;
    if (node >= n) return;
    float4 sum = gather_row_sum_h(Zh, csr, node, offs[node], eend[node], half, l);
    if (half == 0) {
        float d = dinv[node];
        half4 o;
        o[0] = (_Float16)(sum.x * d);
        o[1] = (_Float16)(sum.y * d);
        o[2] = (_Float16)(sum.z * d);
        o[3] = (_Float16)(sum.w * d);
        *(half4*)(Uh + (size_t)node * H + l * 4) = o;
    }
}

// ---------------- pooling (fp16 rows, half2-vectorized; binary search; no atomics) --------

__global__ __launch_bounds__(64) void pool_h_k(const _Float16* __restrict__ h, const int* __restrict__ batch,
                                               float* __restrict__ P, int n, int G) {
    int g = blockIdx.x, f = threadIdx.x;     // f handles features 2f, 2f+1
    int lo = 0, hi = n;
    while (lo < hi) { int m = (lo + hi) >> 1; if (batch[m] < g) lo = m + 1; else hi = m; }
    int s0 = lo;
    hi = n;
    while (lo < hi) { int m = (lo + hi) >> 1; if (batch[m] < g + 1) lo = m + 1; else hi = m; }
    int s1 = lo;
    const half2t* hp = (const half2t*)h;
    float a0x = 0.f, a0y = 0.f, a1x = 0.f, a1y = 0.f;
    float a2x = 0.f, a2y = 0.f, a3x = 0.f, a3y = 0.f;
    int i = s0;
    for (; i + 4 <= s1; i += 4) {
        half2t v0 = hp[(size_t)i * 64 + f];
        half2t v1 = hp[(size_t)(i + 1) * 64 + f];
        half2t v2 = hp[(size_t)(i + 2) * 64 + f];
        half2t v3 = hp[(size_t)(i + 3) * 64 + f];
        a0x += (float)v0[0]; a0y += (float)v0[1];
        a1x += (float)v1[0]; a1y += (float)v1[1];
        a2x += (float)v2[0]; a2y += (float)v2[1];
        a3x += (float)v3[0]; a3y += (float)v3[1];
    }
    for (; i < s1; ++i) {
        half2t v = hp[(size_t)i * 64 + f];
        a0x += (float)v[0]; a0y += (float)v[1];
    }
    float sx = (a0x + a1x) + (a2x + a3x);
    float sy = (a0y + a1y) + (a2y + a3y);
    float c = (float)(s1 - s0); if (c < 1.f) c = 1.f;
    P[(size_t)g * H + 2 * f]     = sx / c;
    P[(size_t)g * H + 2 * f + 1] = sy / c;
}

// ------- fused MLP head: relu(@Wl1+bl1) + relu(@Wl2+bl2) + dot Wl3 + bl3 -------

__global__ __launch_bounds__(256) void head_k(const float* __restrict__ P,
                                              const float* __restrict__ Wl1, const float* __restrict__ bl1,
                                              const float* __restrict__ Wl2, const float* __restrict__ bl2,
                                              const float* __restrict__ Wl3, const float* __restrict__ bl3,
                                              float* __restrict__ out, int G) {
    __shared__ float Wb[H * H];
    __shared__ float Tl[H * 133];
    __shared__ float w3l[H];
    int tid = threadIdx.x;
    int g0 = blockIdx.x * 128;

    if (tid < 128) w3l[tid] = Wl3[tid];
    for (int i = tid; i < H * H / 4; i += 256) ((float4*)Wb)[i] = ((const float4*)Wl1)[i];
    __syncthreads();

    const int cc = tid & 7, rg = tid >> 3, c0 = cc * 16;
    float acc[4][16];

    #pragma unroll
    for (int r = 0; r < 4; ++r)
        #pragma unroll
        for (int j = 0; j < 16; ++j) acc[r][j] = 0.f;
    const float4* P4 = (const float4*)P;
    for (int k4 = 0; k4 < H / 4; ++k4) {
        float4 a[4];
        #pragma unroll
        for (int r = 0; r < 4; ++r) a[r] = P4[(size_t)(g0 + rg * 4 + r) * 32 + k4];
        const float* wbase = Wb + (k4 * 4) * H + c0;
        #pragma unroll
        for (int kk = 0; kk < 4; ++kk) {
            float w[16];
            *(float4*)(w + 0)  = *(const float4*)(wbase + kk * H + 0);
            *(float4*)(w + 4)  = *(const float4*)(wbase + kk * H + 4);
            *(float4*)(w + 8)  = *(const float4*)(wbase + kk * H + 8);
            *(float4*)(w + 12) = *(const float4*)(wbase + kk * H + 12);
            float av[4];
            #pragma unroll
            for (int r = 0; r < 4; ++r) av[r] = ((const float*)&a[r])[kk];
            #pragma unroll
            for (int r = 0; r < 4; ++r)
                #pragma unroll
                for (int j = 0; j < 16; ++j)
                    acc[r][j] = fmaf(av[r], w[j], acc[r][j]);
        }
    }
    #pragma unroll
    for (int r = 0; r < 4; ++r) {
        int rl = rg * 4 + r;
        #pragma unroll
        for (int j = 0; j < 16; ++j)
            Tl[rl * 133 + c0 + j] = fmaxf(acc[r][j] + bl1[c0 + j], 0.f);
    }
    __syncthreads();
    for (int i = tid; i < H * H / 4; i += 256) ((float4*)Wb)[i] = ((const float4*)Wl2)[i];
    __syncthreads();

    #pragma unroll
    for (int r = 0; r < 4; ++r)
        #pragma unroll
        for (int j = 0; j < 16; ++j) acc[r][j] = 0.f;
    for (int k4 = 0; k4 < H / 4; ++k4) {
        float4 a[4];
        #pragma unroll
        for (int r = 0; r < 4; ++r) a[r] = *(const float4*)(Tl + (rg * 4 + r) * 133 + k4 * 4);
        const float* wbase = Wb + (k4 * 4) * H + c0;
        #pragma unroll
        for (int kk = 0; kk < 4; ++kk) {
            float w[16];
            *(float4*)(w + 0)  = *(const float4*)(wbase + kk * H + 0);
            *(float4*)(w + 4)  = *(const float4*)(wbase + kk * H + 4);
            *(float4*)(w + 8)  = *(const float4*)(wbase + kk * H + 8);
            *(float4*)(w + 12) = *(const float4*)(wbase + kk * H + 12);
            float av[4];
            #pragma unroll
            for (int r = 0; r < 4; ++r) av[r] = ((const float*)&a[r])[kk];
            #pragma unroll
            for (int r = 0; r < 4; ++r)
                #pragma unroll
                for (int j = 0; j < 16; ++j)
                    acc[r][j] = fmaf(av[r], w[j], acc[r][j]);
        }
    }
    float part[4];
    #pragma unroll
    for (int r = 0; r < 4; ++r) {
        float s = 0.f;
        #pragma unroll
        for (int j = 0; j < 16; ++j)
            s += fmaxf(acc[r][j] + bl2[c0 + j], 0.f) * w3l[c0 + j];
        part[r] = s;
    }
    #pragma unroll
    for (int off = 1; off < 8; off <<= 1)
        #pragma unroll
        for (int r = 0; r < 4; ++r) part[r] += __shfl_xor(part[r], off);
    if (cc == 0) {
        float bb = bl3[0];
        #pragma unroll
        for (int r = 0; r < 4; ++r) out[g0 + rg * 4 + r] = part[r] + bb;
    }
}

// ---------------- launch ----------------

extern "C" void kernel_launch(void* const* d_in, const int* in_sizes, int n_in,
                              void* d_out, int out_size, void* d_ws, size_t ws_size,
                              hipStream_t stream) {
    const float* x     = (const float*)d_in[0];
    const int*   ei    = (const int*)d_in[1];
    const int*   batch = (const int*)d_in[2];
    const float* W1  = (const float*)d_in[3];  const float* b1  = (const float*)d_in[4];
    const float* W2  = (const float*)d_in[5];  const float* b2  = (const float*)d_in[6];
    const float* W3  = (const float*)d_in[7];  const float* b3  = (const float*)d_in[8];
    const float* Wl1 = (const float*)d_in[9];  const float* bl1 = (const float*)d_in[10];
    const float* Wl2 = (const float*)d_in[11]; const float* bl2 = (const float*)d_in[12];
    const float* Wl3 = (const float*)d_in[13]; const float* bl3 = (const float*)d_in[14];

    const int N = in_sizes[0];
    const int E = in_sizes[1] / 2;
    const int G = out_size;
    const int* srcp = ei;
    const int* dstp = ei + E;
    const int NB = (N + BN - 1) / BN;    // 196 for N=100000

    char* w = (char*)d_ws;
    size_t off = 0;
    auto alloc = [&](size_t bytes) -> void* {
        void* p = w + off;
        off += (bytes + 255) & ~(size_t)255;
        return p;
    };
    int*    gcur   = (int*)alloc((size_t)MAXNB * 4);
    int*    offs   = (int*)alloc((size_t)N * 4);
    int*    eend   = (int*)alloc((size_t)N * 4);
    int*    csr    = (int*)alloc((size_t)NB * CAP * 4);   // bucket-padded
    float*  dinv   = (float*)alloc((size_t)N * 4);
    float*  sbuf   = (float*)alloc((size_t)N * 4);
    float2* td     = (float2*)alloc((size_t)N * 8);
    float*  A      = (float*)alloc((size_t)N * H * 4);   // U2h (fp16), then U3h (fp16)
    float*  B      = (float*)alloc((size_t)N * H * 4);   // pairbuf/etd, then Z2h, then h3h
    float*  P      = (float*)alloc((size_t)G * H * 4);   // pooled means (fp32)
    unsigned* pairbuf = (unsigned*)B;   // alias (NB*CAP*4 = 12.9 MB << N*H*4)
    float2*   etd     = (float2*)B;    // alias (NB*CAP*8 = 25.7 MB; live gather_td -> l2_agg)
    _Float16* Z2h     = (_Float16*)B;  // alias (N*H*2 = 25.6 MB, written after etd is dead)
    _Float16* h3h     = (_Float16*)B;  // alias (written after Z2h is dead)
    _Float16* U2h     = (_Float16*)A;
    _Float16* U3h     = (_Float16*)A;
    (void)ws_size; (void)n_in;

    // --- graph build (slack buckets: no histogram pass) ---
    hipMemsetAsync(gcur, 0, (size_t)MAXNB * 4, stream);
    scatter_pairs_k<<<(E + CHUNK - 1) / CHUNK, 256, 0, stream>>>(srcp, dstp, gcur, pairbuf, E, NB);
    build_csr_k<<<NB, 512, 0, stream>>>(pairbuf, gcur, x, offs, eend, dinv, sbuf, csr, N);

    // --- layer 1 (scalar feature) ---
    agg1_k<<<(N + 255) / 256, 256, 0, stream>>>(sbuf, offs, eend, csr, dinv, td, N);

    // --- layer 2: per-edge operands, stream-aggregate (fp16 U2), MFMA GEMM (fp16 Z2) ---
    gather_td_k<<<NB * 4, 256, 0, stream>>>(csr, td, gcur, etd);
    l2_agg_k<<<(N + 3) / 4, 256, 0, stream>>>(td, etd, offs, eend, W1, b1, U2h, N);
    gemm_h_k<<<(N + 63) / 64, 256, 0, stream>>>(U2h, W2, b2, dinv, Z2h, N);   // B = Z2h

    // --- layer 3: fp16 row-gather aggregation (fp16 U3), MFMA GEMM (fp16 h3), pool ---
    agg3h_k<<<(N + 3) / 4, 256, 0, stream>>>((const uint2*)Z2h, offs, eend, csr, dinv, U3h, N);
    gemm_h_k<<<(N + 63) / 64, 256, 0, stream>>>(U3h, W3, b3, nullptr, h3h, N); // B = h3h
    pool_h_k<<<G, 64, 0, stream>>>(h3h, batch, P, N, G);

    // --- fused MLP head ---
    head_k<<<(G + 127) / 128, 256, 0, stream>>>(P, Wl1, bl1, Wl2, bl2, Wl3, bl3,
                                                (float*)d_out, G);
}

// Round 6
// 380.298 us; speedup vs baseline: 1.9570x; 1.0348x over previous
//
#include <hip/hip_runtime.h>
#include <hip/hip_fp16.h>

#define H 128
#define SHIFT 9             // nodes per coarse bucket = 512
#define BN 512
#define MAXNB 256           // max coarse buckets (N <= 131072)
#define CHUNK 4096          // edges per scatter block
#define CAP 16384           // slack capacity per bucket (exp 8192, sigma ~90)

typedef _Float16 half8 __attribute__((ext_vector_type(8)));
typedef _Float16 half4 __attribute__((ext_vector_type(4)));
typedef _Float16 half2t __attribute__((ext_vector_type(2)));
typedef float f32x4 __attribute__((ext_vector_type(4)));

// ============ graph build: slack-bucket counting sort (no global histogram pass) ============
// Packing: src < 2^17, local node < 512 -> record = (local<<17)|src fits u32.
// Bucket b owns pairbuf/csr region [b*CAP, (b+1)*CAP); gcur[b] (memset 0) allocates within.

__global__ __launch_bounds__(256) void scatter_pairs_k(const int* __restrict__ src,
                                                       const int* __restrict__ dst,
                                                       int* __restrict__ gcur,
                                                       unsigned* __restrict__ pairbuf,
                                                       int E, int NBv) {
    __shared__ unsigned stage[CHUNK];
    __shared__ unsigned char stb[CHUNK];
    __shared__ int hist[MAXNB], basel[MAXNB], cur[MAXNB], gbase[MAXNB];
    __shared__ int total;
    int tid = threadIdx.x;
    int base = blockIdx.x * CHUNK;

    int mysrc[16], mydst[16];
    #pragma unroll
    for (int i = 0; i < 16; ++i) {
        int e = base + i * 256 + tid;
        if (e < E) { mysrc[i] = src[e]; mydst[i] = dst[e]; } else mydst[i] = -1;
    }
    hist[tid] = 0;
    __syncthreads();
    #pragma unroll
    for (int i = 0; i < 16; ++i)
        if (mydst[i] >= 0) atomicAdd(&hist[mydst[i] >> SHIFT], 1);
    __syncthreads();
    if (tid == 0) {
        int run = 0;
        for (int b = 0; b < NBv; ++b) { basel[b] = run; run += hist[b]; }
        total = run;
    }
    __syncthreads();
    if (tid < NBv) {
        cur[tid] = basel[tid];
        if (hist[tid] > 0) gbase[tid] = tid * CAP + atomicAdd(&gcur[tid], hist[tid]);
    }
    __syncthreads();
    #pragma unroll
    for (int i = 0; i < 16; ++i)
        if (mydst[i] >= 0) {
            int b = mydst[i] >> SHIFT;
            int slot = atomicAdd(&cur[b], 1);
            stage[slot] = ((unsigned)(mydst[i] & (BN - 1)) << 17) | (unsigned)mysrc[i];
            stb[slot] = (unsigned char)b;
        }
    __syncthreads();
    for (int s = tid; s < total; s += 256) {
        int b = stb[s];
        pairbuf[gbase[b] + (s - basel[b])] = stage[s];   // contiguous runs -> full-line writes
    }
}

// one block per bucket: LDS hist + scan -> offs/eend/dinv/s, then in-bucket scatter (L2-local)
__global__ __launch_bounds__(512) void build_csr_k(const unsigned* __restrict__ pairbuf,
                                                   const int* __restrict__ gcur,
                                                   const float* __restrict__ x,
                                                   int* __restrict__ offs, int* __restrict__ eend,
                                                   float* __restrict__ dinv, float* __restrict__ s,
                                                   int* __restrict__ csr, int N) {
    __shared__ int hist[BN];
    __shared__ int cur[BN];
    __shared__ int ps[BN];
    int b = blockIdx.x, tid = threadIdx.x;
    int node0 = b << SHIFT;
    int e0 = b * CAP, e1 = e0 + gcur[b];
    hist[tid] = 0;
    __syncthreads();
    for (int p = e0 + tid; p < e1; p += 512)
        atomicAdd(&hist[pairbuf[p] >> 17], 1);
    __syncthreads();
    int v0 = hist[tid];
    ps[tid] = v0;
    __syncthreads();
    for (int off = 1; off < BN; off <<= 1) {
        int t = (tid >= off) ? ps[tid - off] : 0;
        __syncthreads();
        ps[tid] += t;
        __syncthreads();
    }
    int g0 = e0 + ps[tid] - v0;
    int n0 = node0 + tid;
    if (n0 < N) {
        float d = rsqrtf((float)(v0 + 1));
        offs[n0] = g0;
        eend[n0] = g0 + v0;
        dinv[n0] = d;
        s[n0] = x[n0] * d;      // fused s_k
    }
    cur[tid] = g0;
    __syncthreads();
    for (int p = e0 + tid; p < e1; p += 512) {
        unsigned v = pairbuf[p];
        int pos = atomicAdd(&cur[v >> 17], 1);
        csr[pos] = (int)(v & 0x1FFFFu);
    }
}

// ---------------- layer 1 (wave-split): t_i = dinv_i*(s_i + sum s_src) ----------------
// 16 lanes per node (4 nodes/wave): lane j sums edges j, j+16, ... -> 16-32 independent
// gathers in flight per node (vs 4 in the old per-thread serial loop), then a 4-step
// __shfl_xor tree reduce within the 16-lane group. s table (400 KB) is L2-resident.

__global__ __launch_bounds__(256) void agg1_k(const float* __restrict__ s, const int* __restrict__ offs,
                                              const int* __restrict__ eend, const int* __restrict__ csr,
                                              const float* __restrict__ dinv, float2* __restrict__ td, int n) {
    int l = threadIdx.x & 63;
    int wave = threadIdx.x >> 6;
    int sub = l >> 4;               // node within wave (0..3)
    int j   = l & 15;               // lane within node
    int node = blockIdx.x * 16 + wave * 4 + sub;
    int nd = node < n ? node : n - 1;
    int e0 = offs[nd], e1 = eend[nd];
    float sum = 0.f;
    int p = e0 + j;
    for (; p + 16 < e1; p += 32) {  // 2 independent gathers per lane per round
        int iA = csr[p];
        int iB = csr[p + 16];
        float vA = s[iA];
        float vB = s[iB];
        sum += vA + vB;
    }
    if (p < e1) sum += s[csr[p]];
    #pragma unroll
    for (int m = 1; m < 16; m <<= 1) sum += __shfl_xor(sum, m);
    if (j == 0 && node < n) {
        float d = dinv[nd];
        td[node] = make_float2((sum + s[nd]) * d, d);
    }
}

// ------- per-edge operand materialization: etd[p] = td[csr[p]] (csr-aligned) -------

__global__ __launch_bounds__(256) void gather_td_k(const int* __restrict__ csr,
                                                   const float2* __restrict__ td,
                                                   const int* __restrict__ gcur,
                                                   float2* __restrict__ etd) {
    int b = blockIdx.x >> 2;
    int k = blockIdx.x & 3;
    int base = b * CAP + k * (CAP / 4);
    int e1 = b * CAP + gcur[b];
    int hi = base + (CAP / 4); if (hi > e1) hi = e1;
    for (int p0 = base; p0 < hi; p0 += 1024) {
        int p = p0 + threadIdx.x;
        bool m0 = (p < hi), m1 = (p + 256 < hi), m2 = (p + 512 < hi), m3 = (p + 768 < hi);
        int i0 = m0 ? csr[p] : 0;
        int i1 = m1 ? csr[p + 256] : 0;
        int i2 = m2 ? csr[p + 512] : 0;
        int i3 = m3 ? csr[p + 768] : 0;
        float2 v0 = td[i0];
        float2 v1 = td[i1];
        float2 v2 = td[i2];
        float2 v3 = td[i3];
        if (m0) etd[p] = v0;
        if (m1) etd[p + 256] = v1;
        if (m2) etd[p + 512] = v2;
        if (m3) etd[p + 768] = v3;
    }
}

// ------- layer-2 fused aggregation over SCALARS; fp16 U2 out -------
// U2_i = dinv_i * sum_{j in N(i)+self} dinv_j * relu(t_j*w1 + b1)

__global__ __launch_bounds__(256) void l2_agg_k(const float2* __restrict__ td,
                                                const float2* __restrict__ etd,
                                                const int* __restrict__ offs,
                                                const int* __restrict__ eend,
                                                const float* __restrict__ w1,
                                                const float* __restrict__ b1,
                                                _Float16* __restrict__ Uh, int n) {
    int node = blockIdx.x * 4 + (threadIdx.x >> 6);
    int lane = threadIdx.x & 63;
    if (node >= n) return;
    float wa = w1[lane],      wb = w1[lane + 64];
    float ba = b1[lane],      bb = b1[lane + 64];
    float2 self = td[node];
    float sa = fmaxf(fmaf(self.x, wa, ba), 0.f) * self.y;
    float sb = fmaxf(fmaf(self.x, wb, bb), 0.f) * self.y;
    const float2* ep = etd + offs[node];
    int cnt = eend[node] - offs[node];
    int p = 0;
    for (; p + 8 <= cnt; p += 8) {
        float2 v[8];
        #pragma unroll
        for (int u = 0; u < 8; ++u) v[u] = ep[p + u];
        #pragma unroll
        for (int u = 0; u < 8; ++u) {
            sa = fmaf(fmaxf(fmaf(v[u].x, wa, ba), 0.f), v[u].y, sa);
            sb = fmaf(fmaxf(fmaf(v[u].x, wb, bb), 0.f), v[u].y, sb);
        }
    }
    for (; p < cnt; ++p) {
        float2 v = ep[p];
        sa = fmaf(fmaxf(fmaf(v.x, wa, ba), 0.f), v.y, sa);
        sb = fmaf(fmaxf(fmaf(v.x, wb, bb), 0.f), v.y, sb);
    }
    float d = self.y;
    Uh[(size_t)node * H + lane]      = (_Float16)(sa * d);
    Uh[(size_t)node * H + lane + 64] = (_Float16)(sb * d);
}

// ------- MFMA GEMM (f16 in, f16 out, fp32 accum): out = [pscale] * relu(in @ W + bias) -------
// v_mfma_f32_16x16x32_f16 layouts (m89-verified C/D; AMD lab-notes A/B):
//   A: row = lane&15, k = 8*(lane>>4)+j   (16 B contiguous from row-major fp16 in)
//   B: col = lane&15, k = 8*(lane>>4)+j   (16 B contiguous from LDS W^T [col][k], stride 136)
//   D: col = lane&15, row = 4*(lane>>4)+reg
// Block: 4 waves x 16 rows = 64 rows, full N=128. LDS out re-stage for coalesced stores.

__global__ __launch_bounds__(256) void gemm_h_k(const _Float16* __restrict__ in,
                                                const float* __restrict__ W,
                                                const float* __restrict__ bias,
                                                const float* __restrict__ pscale,
                                                _Float16* __restrict__ out, int n) {
    __shared__ _Float16 WT[128 * 136];   // [col][k], +8 pad: ds_read_b128 2-way banks (free)
    __shared__ _Float16 OT[64 * 136];    // out tile re-stage, same padded stride
    __shared__ float bsh[H];

    // stage W^T fp16 (global W is [k][col] fp32 row-major)
    for (int idx = threadIdx.x; idx < 128 * 32; idx += 256) {
        int k  = idx >> 5;
        int c4 = (idx & 31) << 2;
        float4 v = *(const float4*)(W + k * H + c4);
        WT[(c4 + 0) * 136 + k] = (_Float16)v.x;
        WT[(c4 + 1) * 136 + k] = (_Float16)v.y;
        WT[(c4 + 2) * 136 + k] = (_Float16)v.z;
        WT[(c4 + 3) * 136 + k] = (_Float16)v.w;
    }
    if (threadIdx.x < H) bsh[threadIdx.x] = bias[threadIdx.x];
    __syncthreads();

    const int wave = threadIdx.x >> 6;
    const int l    = threadIdx.x & 63;
    const int lr   = l & 15;     // A-row / B-col / D-col within tile
    const int lk   = l >> 4;     // k sub-block (0..3)
    const int row0 = blockIdx.x * 64 + wave * 16;

    f32x4 acc[8];
    #pragma unroll
    for (int c = 0; c < 8; ++c) acc[c] = (f32x4){0.f, 0.f, 0.f, 0.f};

    int arow = row0 + lr; if (arow > n - 1) arow = n - 1;
    const _Float16* ap = in + (size_t)arow * H + lk * 8;

    #pragma unroll
    for (int ks = 0; ks < 4; ++ks) {
        half8 a = *(const half8*)(ap + ks * 32);
        #pragma unroll
        for (int c = 0; c < 8; ++c) {
            half8 b = *(const half8*)(WT + (c * 16 + lr) * 136 + ks * 32 + lk * 8);
            acc[c] = __builtin_amdgcn_mfma_f32_16x16x32_f16(a, b, acc[c], 0, 0, 0);
        }
    }

    // epilogue: bias + relu (+ pscale), fp16 into OT (2-way LDS banks from 136 stride)
    #pragma unroll
    for (int r = 0; r < 4; ++r) {
        int lrow = wave * 16 + lk * 4 + r;       // row within block tile
        int grow = blockIdx.x * 64 + lrow;
        float sc = 1.f;
        if (pscale) { int gr = grow > n - 1 ? n - 1 : grow; sc = pscale[gr]; }
        #pragma unroll
        for (int c = 0; c < 8; ++c) {
            float v = fmaxf(acc[c][r] + bsh[c * 16 + lr], 0.f) * sc;
            OT[lrow * 136 + c * 16 + lr] = (_Float16)v;
        }
    }
    __syncthreads();

    // coalesced fp16 row stores: 64 rows x 256 B = 16 uint4 per row
    for (int idx = threadIdx.x; idx < 64 * 16; idx += 256) {
        int row = idx >> 4;
        int gr = blockIdx.x * 64 + row;
        if (gr < n)
            ((uint4*)(out + (size_t)gr * H))[idx & 15] = ((const uint4*)(OT + row * 136))[idx & 15];
    }
}

// ------- whole-wave gather of one node's neighbor-row sum (fp16 rows, fp32 accumulate) -------

__device__ __forceinline__ void acc_h(float4& a, uint2 r) {
    __half2 h0 = *(__half2*)&r.x;
    __half2 h1 = *(__half2*)&r.y;
    float2 f0 = __half22float2(h0);
    float2 f1 = __half22float2(h1);
    a.x += f0.x; a.y += f0.y; a.z += f1.x; a.w += f1.y;
}

__device__ __forceinline__ float4 gather_row_sum_h(const uint2* __restrict__ hrow,
                                                   const int* __restrict__ csr,
                                                   int node, int e0, int e1, int half, int l) {
    float4 acc[8];
    #pragma unroll
    for (int u = 0; u < 8; ++u) acc[u] = make_float4(0.f, 0.f, 0.f, 0.f);
    if (half == 0) {                                  // self loop
        uint2 rs = hrow[(size_t)node * 32 + l];
        acc_h(acc[0], rs);
    }
    int q = e0;
    for (; q + 15 < e1; q += 16) {
        int idx[8];
        #pragma unroll
        for (int u = 0; u < 8; ++u) idx[u] = csr[q + 2 * u + half];
        uint2 raw[8];
        #pragma unroll
        for (int u = 0; u < 8; ++u) raw[u] = hrow[(size_t)idx[u] * 32 + l];
        #pragma unroll
        for (int u = 0; u < 8; ++u) acc_h(acc[u], raw[u]);
    }
    for (; q + 7 < e1; q += 8) {
        int idx[4];
        #pragma unroll
        for (int u = 0; u < 4; ++u) idx[u] = csr[q + 2 * u + half];
        uint2 raw[4];
        #pragma unroll
        for (int u = 0; u < 4; ++u) raw[u] = hrow[(size_t)idx[u] * 32 + l];
        #pragma unroll
        for (int u = 0; u < 4; ++u) acc_h(acc[u], raw[u]);
    }
    for (; q < e1; q += 2) {
        int off = q + half;
        if (off < e1) {
            uint2 raw = hrow[(size_t)csr[off] * 32 + l];
            acc_h(acc[0], raw);
        }
    }
    float4 sum;
    sum.x = ((acc[0].x + acc[1].x) + (acc[2].x + acc[3].x)) + ((acc[4].x + acc[5].x) + (acc[6].x + acc[7].x));
    sum.y = ((acc[0].y + acc[1].y) + (acc[2].y + acc[3].y)) + ((acc[4].y + acc[5].y) + (acc[6].y + acc[7].y));
    sum.z = ((acc[0].z + acc[1].z) + (acc[2].z + acc[3].z)) + ((acc[4].z + acc[5].z) + (acc[6].z + acc[7].z));
    sum.w = ((acc[0].w + acc[1].w) + (acc[2].w + acc[3].w)) + ((acc[4].w + acc[5].w) + (acc[6].w + acc[7].w));
    sum.x += __shfl_xor(sum.x, 32);
    sum.y += __shfl_xor(sum.y, 32);
    sum.z += __shfl_xor(sum.z, 32);
    sum.w += __shfl_xor(sum.w, 32);
    return sum;
}

// ------- layer-3 aggregation of fp16 Z2 rows: U3_i = dinv_i * (Z2_i + sum Z2_src) [fp16 out] -------

__global__ __launch_bounds__(256) void agg3h_k(const uint2* __restrict__ Zh, const int* __restrict__ offs,
                                               const int* __restrict__ eend, const int* __restrict__ csr,
                                               const float* __restrict__ dinv,
                                               _Float16* __restrict__ Uh, int n) {
    int node = blockIdx.x * 4 + (threadIdx.x >> 6);
    int lane = threadIdx.x & 63;
    int half = lane >> 5;
    int l = lane & 31;
    if (node >= n) return;
    float4 sum = gather_row_sum_h(Zh, csr, node, offs[node], eend[node], half, l);
    if (half == 0) {
        float d = dinv[node];
        half4 o;
        o[0] = (_Float16)(sum.x * d);
        o[1] = (_Float16)(sum.y * d);
        o[2] = (_Float16)(sum.z * d);
        o[3] = (_Float16)(sum.w * d);
        *(half4*)(Uh + (size_t)node * H + l * 4) = o;
    }
}

// ---------------- pooling (fp16 rows, half2-vectorized; binary search; no atomics) --------

__global__ __launch_bounds__(64) void pool_h_k(const _Float16* __restrict__ h, const int* __restrict__ batch,
                                               float* __restrict__ P, int n, int G) {
    int g = blockIdx.x, f = threadIdx.x;     // f handles features 2f, 2f+1
    int lo = 0, hi = n;
    while (lo < hi) { int m = (lo + hi) >> 1; if (batch[m] < g) lo = m + 1; else hi = m; }
    int s0 = lo;
    hi = n;
    while (lo < hi) { int m = (lo + hi) >> 1; if (batch[m] < g + 1) lo = m + 1; else hi = m; }
    int s1 = lo;
    const half2t* hp = (const half2t*)h;
    float a0x = 0.f, a0y = 0.f, a1x = 0.f, a1y = 0.f;
    float a2x = 0.f, a2y = 0.f, a3x = 0.f, a3y = 0.f;
    int i = s0;
    for (; i + 4 <= s1; i += 4) {
        half2t v0 = hp[(size_t)i * 64 + f];
        half2t v1 = hp[(size_t)(i + 1) * 64 + f];
        half2t v2 = hp[(size_t)(i + 2) * 64 + f];
        half2t v3 = hp[(size_t)(i + 3) * 64 + f];
        a0x += (float)v0[0]; a0y += (float)v0[1];
        a1x += (float)v1[0]; a1y += (float)v1[1];
        a2x += (float)v2[0]; a2y += (float)v2[1];
        a3x += (float)v3[0]; a3y += (float)v3[1];
    }
    for (; i < s1; ++i) {
        half2t v = hp[(size_t)i * 64 + f];
        a0x += (float)v[0]; a0y += (float)v[1];
    }
    float sx = (a0x + a1x) + (a2x + a3x);
    float sy = (a0y + a1y) + (a2y + a3y);
    float c = (float)(s1 - s0); if (c < 1.f) c = 1.f;
    P[(size_t)g * H + 2 * f]     = sx / c;
    P[(size_t)g * H + 2 * f + 1] = sy / c;
}

// ------- fused MLP head: relu(@Wl1+bl1) + relu(@Wl2+bl2) + dot Wl3 + bl3 -------
// 64 blocks x 32 graphs (was 16 x 128): 4x parallelism, LDS 82 KB. Each thread owns one
// graph row (rg) and 16 output cols (cc); 8-lane shfl reduce for the final dot.

__global__ __launch_bounds__(256) void head_k(const float* __restrict__ P,
                                              const float* __restrict__ Wl1, const float* __restrict__ bl1,
                                              const float* __restrict__ Wl2, const float* __restrict__ bl2,
                                              const float* __restrict__ Wl3, const float* __restrict__ bl3,
                                              float* __restrict__ out, int G) {
    __shared__ float Wb[H * H];
    __shared__ float Tl[32 * 133];
    __shared__ float w3l[H];
    int tid = threadIdx.x;
    int g0 = blockIdx.x * 32;

    if (tid < 128) w3l[tid] = Wl3[tid];
    for (int i = tid; i < H * H / 4; i += 256) ((float4*)Wb)[i] = ((const float4*)Wl1)[i];
    __syncthreads();

    const int cc = tid & 7, rg = tid >> 3, c0 = cc * 16;
    int grow = g0 + rg; if (grow > G - 1) grow = G - 1;
    float acc[16];

    #pragma unroll
    for (int j = 0; j < 16; ++j) acc[j] = 0.f;
    const float4* P4 = (const float4*)P;
    for (int k4 = 0; k4 < H / 4; ++k4) {
        float4 a = P4[(size_t)grow * 32 + k4];
        const float* wbase = Wb + (k4 * 4) * H + c0;
        #pragma unroll
        for (int kk = 0; kk < 4; ++kk) {
            float w[16];
            *(float4*)(w + 0)  = *(const float4*)(wbase + kk * H + 0);
            *(float4*)(w + 4)  = *(const float4*)(wbase + kk * H + 4);
            *(float4*)(w + 8)  = *(const float4*)(wbase + kk * H + 8);
            *(float4*)(w + 12) = *(const float4*)(wbase + kk * H + 12);
            float av = ((const float*)&a)[kk];
            #pragma unroll
            for (int j = 0; j < 16; ++j)
                acc[j] = fmaf(av, w[j], acc[j]);
        }
    }
    #pragma unroll
    for (int j = 0; j < 16; ++j)
        Tl[rg * 133 + c0 + j] = fmaxf(acc[j] + bl1[c0 + j], 0.f);
    __syncthreads();
    for (int i = tid; i < H * H / 4; i += 256) ((float4*)Wb)[i] = ((const float4*)Wl2)[i];
    __syncthreads();

    #pragma unroll
    for (int j = 0; j < 16; ++j) acc[j] = 0.f;
    for (int k4 = 0; k4 < H / 4; ++k4) {
        float4 a = *(const float4*)(Tl + rg * 133 + k4 * 4);
        const float* wbase = Wb + (k4 * 4) * H + c0;
        #pragma unroll
        for (int kk = 0; kk < 4; ++kk) {
            float w[16];
            *(float4*)(w + 0)  = *(const float4*)(wbase + kk * H + 0);
            *(float4*)(w + 4)  = *(const float4*)(wbase + kk * H + 4);
            *(float4*)(w + 8)  = *(const float4*)(wbase + kk * H + 8);
            *(float4*)(w + 12) = *(const float4*)(wbase + kk * H + 12);
            float av = ((const float*)&a)[kk];
            #pragma unroll
            for (int j = 0; j < 16; ++j)
                acc[j] = fmaf(av, w[j], acc[j]);
        }
    }
    float part = 0.f;
    #pragma unroll
    for (int j = 0; j < 16; ++j)
        part += fmaxf(acc[j] + bl2[c0 + j], 0.f) * w3l[c0 + j];
    #pragma unroll
    for (int off = 1; off < 8; off <<= 1)
        part += __shfl_xor(part, off);
    if (cc == 0 && g0 + rg < G)
        out[g0 + rg] = part + bl3[0];
}

// ---------------- launch ----------------

extern "C" void kernel_launch(void* const* d_in, const int* in_sizes, int n_in,
                              void* d_out, int out_size, void* d_ws, size_t ws_size,
                              hipStream_t stream) {
    const float* x     = (const float*)d_in[0];
    const int*   ei    = (const int*)d_in[1];
    const int*   batch = (const int*)d_in[2];
    const float* W1  = (const float*)d_in[3];  const float* b1  = (const float*)d_in[4];
    const float* W2  = (const float*)d_in[5];  const float* b2  = (const float*)d_in[6];
    const float* W3  = (const float*)d_in[7];  const float* b3  = (const float*)d_in[8];
    const float* Wl1 = (const float*)d_in[9];  const float* bl1 = (const float*)d_in[10];
    const float* Wl2 = (const float*)d_in[11]; const float* bl2 = (const float*)d_in[12];
    const float* Wl3 = (const float*)d_in[13]; const float* bl3 = (const float*)d_in[14];

    const int N = in_sizes[0];
    const int E = in_sizes[1] / 2;
    const int G = out_size;
    const int* srcp = ei;
    const int* dstp = ei + E;
    const int NB = (N + BN - 1) / BN;    // 196 for N=100000

    char* w = (char*)d_ws;
    size_t off = 0;
    auto alloc = [&](size_t bytes) -> void* {
        void* p = w + off;
        off += (bytes + 255) & ~(size_t)255;
        return p;
    };
    int*    gcur   = (int*)alloc((size_t)MAXNB * 4);
    int*    offs   = (int*)alloc((size_t)N * 4);
    int*    eend   = (int*)alloc((size_t)N * 4);
    int*    csr    = (int*)alloc((size_t)NB * CAP * 4);   // bucket-padded
    float*  dinv   = (float*)alloc((size_t)N * 4);
    float*  sbuf   = (float*)alloc((size_t)N * 4);
    float2* td     = (float2*)alloc((size_t)N * 8);
    float*  A      = (float*)alloc((size_t)N * H * 4);   // U2h (fp16), then U3h (fp16)
    float*  B      = (float*)alloc((size_t)N * H * 4);   // pairbuf/etd, then Z2h, then h3h
    float*  P      = (float*)alloc((size_t)G * H * 4);   // pooled means (fp32)
    unsigned* pairbuf = (unsigned*)B;   // alias (NB*CAP*4 = 12.9 MB << N*H*4)
    float2*   etd     = (float2*)B;    // alias (NB*CAP*8 = 25.7 MB; live gather_td -> l2_agg)
    _Float16* Z2h     = (_Float16*)B;  // alias (N*H*2 = 25.6 MB, written after etd is dead)
    _Float16* h3h     = (_Float16*)B;  // alias (written after Z2h is dead)
    _Float16* U2h     = (_Float16*)A;
    _Float16* U3h     = (_Float16*)A;
    (void)ws_size; (void)n_in;

    // --- graph build (slack buckets: no histogram pass) ---
    hipMemsetAsync(gcur, 0, (size_t)MAXNB * 4, stream);
    scatter_pairs_k<<<(E + CHUNK - 1) / CHUNK, 256, 0, stream>>>(srcp, dstp, gcur, pairbuf, E, NB);
    build_csr_k<<<NB, 512, 0, stream>>>(pairbuf, gcur, x, offs, eend, dinv, sbuf, csr, N);

    // --- layer 1 (scalar feature, wave-split gather) ---
    agg1_k<<<(N + 15) / 16, 256, 0, stream>>>(sbuf, offs, eend, csr, dinv, td, N);

    // --- layer 2: per-edge operands, stream-aggregate (fp16 U2), MFMA GEMM (fp16 Z2) ---
    gather_td_k<<<NB * 4, 256, 0, stream>>>(csr, td, gcur, etd);
    l2_agg_k<<<(N + 3) / 4, 256, 0, stream>>>(td, etd, offs, eend, W1, b1, U2h, N);
    gemm_h_k<<<(N + 63) / 64, 256, 0, stream>>>(U2h, W2, b2, dinv, Z2h, N);   // B = Z2h

    // --- layer 3: fp16 row-gather aggregation (fp16 U3), MFMA GEMM (fp16 h3), pool ---
    agg3h_k<<<(N + 3) / 4, 256, 0, stream>>>((const uint2*)Z2h, offs, eend, csr, dinv, U3h, N);
    gemm_h_k<<<(N + 63) / 64, 256, 0, stream>>>(U3h, W3, b3, nullptr, h3h, N); // B = h3h
    pool_h_k<<<G, 64, 0, stream>>>(h3h, batch, P, N, G);

    // --- fused MLP head (64 blocks x 32 graphs) ---
    head_k<<<(G + 31) / 32, 256, 0, stream>>>(P, Wl1, bl1, Wl2, bl2, Wl3, bl3,
                                              (float*)d_out, G);
}

// Round 8
// 377.376 us; speedup vs baseline: 1.9722x; 1.0077x over previous
//
#include <hip/hip_runtime.h>
#include <hip/hip_fp16.h>

#define H 128
#define SHIFT 9             // nodes per coarse bucket = 512
#define BN 512
#define MAXNB 256           // max coarse buckets (N <= 131072)
#define CHUNK 4096          // edges per scatter block
#define CAP 16384           // slack capacity per bucket (exp 8192, sigma ~90)

typedef _Float16 half8 __attribute__((ext_vector_type(8)));
typedef _Float16 half4 __attribute__((ext_vector_type(4)));
typedef _Float16 half2t __attribute__((ext_vector_type(2)));
typedef float f32x4 __attribute__((ext_vector_type(4)));

// ============ graph build: slack-bucket counting sort (no global histogram pass) ============
// Packing: src < 2^17, local node < 512 -> record = (local<<17)|src fits u32.
// Bucket b owns pairbuf/csr region [b*CAP, (b+1)*CAP); gcur[b] (memset 0) allocates within.

__global__ __launch_bounds__(256) void scatter_pairs_k(const int* __restrict__ src,
                                                       const int* __restrict__ dst,
                                                       int* __restrict__ gcur,
                                                       unsigned* __restrict__ pairbuf,
                                                       int E, int NBv) {
    __shared__ unsigned stage[CHUNK];
    __shared__ unsigned char stb[CHUNK];
    __shared__ int hist[MAXNB], basel[MAXNB], cur[MAXNB], gbase[MAXNB];
    __shared__ int total;
    int tid = threadIdx.x;
    int base = blockIdx.x * CHUNK;

    int mysrc[16], mydst[16];
    #pragma unroll
    for (int i = 0; i < 16; ++i) {
        int e = base + i * 256 + tid;
        if (e < E) { mysrc[i] = src[e]; mydst[i] = dst[e]; } else mydst[i] = -1;
    }
    hist[tid] = 0;
    __syncthreads();
    #pragma unroll
    for (int i = 0; i < 16; ++i)
        if (mydst[i] >= 0) atomicAdd(&hist[mydst[i] >> SHIFT], 1);
    __syncthreads();
    if (tid == 0) {
        int run = 0;
        for (int b = 0; b < NBv; ++b) { basel[b] = run; run += hist[b]; }
        total = run;
    }
    __syncthreads();
    if (tid < NBv) {
        cur[tid] = basel[tid];
        if (hist[tid] > 0) gbase[tid] = tid * CAP + atomicAdd(&gcur[tid], hist[tid]);
    }
    __syncthreads();
    #pragma unroll
    for (int i = 0; i < 16; ++i)
        if (mydst[i] >= 0) {
            int b = mydst[i] >> SHIFT;
            int slot = atomicAdd(&cur[b], 1);
            stage[slot] = ((unsigned)(mydst[i] & (BN - 1)) << 17) | (unsigned)mysrc[i];
            stb[slot] = (unsigned char)b;
        }
    __syncthreads();
    for (int s = tid; s < total; s += 256) {
        int b = stb[s];
        pairbuf[gbase[b] + (s - basel[b])] = stage[s];   // contiguous runs -> full-line writes
    }
}

// one block per bucket: LDS hist + scan -> offs/eend/dinv/s, then in-bucket scatter (L2-local)
__global__ __launch_bounds__(512) void build_csr_k(const unsigned* __restrict__ pairbuf,
                                                   const int* __restrict__ gcur,
                                                   const float* __restrict__ x,
                                                   int* __restrict__ offs, int* __restrict__ eend,
                                                   float* __restrict__ dinv, float* __restrict__ s,
                                                   int* __restrict__ csr, int N) {
    __shared__ int hist[BN];
    __shared__ int cur[BN];
    __shared__ int ps[BN];
    int b = blockIdx.x, tid = threadIdx.x;
    int node0 = b << SHIFT;
    int e0 = b * CAP, e1 = e0 + gcur[b];
    hist[tid] = 0;
    __syncthreads();
    for (int p = e0 + tid; p < e1; p += 512)
        atomicAdd(&hist[pairbuf[p] >> 17], 1);
    __syncthreads();
    int v0 = hist[tid];
    ps[tid] = v0;
    __syncthreads();
    for (int off = 1; off < BN; off <<= 1) {
        int t = (tid >= off) ? ps[tid - off] : 0;
        __syncthreads();
        ps[tid] += t;
        __syncthreads();
    }
    int g0 = e0 + ps[tid] - v0;
    int n0 = node0 + tid;
    if (n0 < N) {
        float d = rsqrtf((float)(v0 + 1));
        offs[n0] = g0;
        eend[n0] = g0 + v0;
        dinv[n0] = d;
        s[n0] = x[n0] * d;      // fused s_k
    }
    cur[tid] = g0;
    __syncthreads();
    for (int p = e0 + tid; p < e1; p += 512) {
        unsigned v = pairbuf[p];
        int pos = atomicAdd(&cur[v >> 17], 1);
        csr[pos] = (int)(v & 0x1FFFFu);
    }
}

// ---------------- layer 1 (wave-split): t_i = dinv_i*(s_i + sum s_src) ----------------
// 16 lanes per node (4 nodes/wave): lane j sums edges j, j+16, ... -> 16-32 independent
// gathers in flight per node, then a 4-step __shfl_xor tree reduce. s table L2-resident.

__global__ __launch_bounds__(256) void agg1_k(const float* __restrict__ s, const int* __restrict__ offs,
                                              const int* __restrict__ eend, const int* __restrict__ csr,
                                              const float* __restrict__ dinv, float2* __restrict__ td, int n) {
    int l = threadIdx.x & 63;
    int wave = threadIdx.x >> 6;
    int sub = l >> 4;               // node within wave (0..3)
    int j   = l & 15;               // lane within node
    int node = blockIdx.x * 16 + wave * 4 + sub;
    int nd = node < n ? node : n - 1;
    int e0 = offs[nd], e1 = eend[nd];
    float sum = 0.f;
    int p = e0 + j;
    for (; p + 16 < e1; p += 32) {  // 2 independent gathers per lane per round
        int iA = csr[p];
        int iB = csr[p + 16];
        float vA = s[iA];
        float vB = s[iB];
        sum += vA + vB;
    }
    if (p < e1) sum += s[csr[p]];
    #pragma unroll
    for (int m = 1; m < 16; m <<= 1) sum += __shfl_xor(sum, m);
    if (j == 0 && node < n) {
        float d = dinv[nd];
        td[node] = make_float2((sum + s[nd]) * d, d);
    }
}

// ------- per-edge operand materialization: etd[p] = td[csr[p]] (csr-aligned) -------

__global__ __launch_bounds__(256) void gather_td_k(const int* __restrict__ csr,
                                                   const float2* __restrict__ td,
                                                   const int* __restrict__ gcur,
                                                   float2* __restrict__ etd) {
    int b = blockIdx.x >> 2;
    int k = blockIdx.x & 3;
    int base = b * CAP + k * (CAP / 4);
    int e1 = b * CAP + gcur[b];
    int hi = base + (CAP / 4); if (hi > e1) hi = e1;
    for (int p0 = base; p0 < hi; p0 += 1024) {
        int p = p0 + threadIdx.x;
        bool m0 = (p < hi), m1 = (p + 256 < hi), m2 = (p + 512 < hi), m3 = (p + 768 < hi);
        int i0 = m0 ? csr[p] : 0;
        int i1 = m1 ? csr[p + 256] : 0;
        int i2 = m2 ? csr[p + 512] : 0;
        int i3 = m3 ? csr[p + 768] : 0;
        float2 v0 = td[i0];
        float2 v1 = td[i1];
        float2 v2 = td[i2];
        float2 v3 = td[i3];
        if (m0) etd[p] = v0;
        if (m1) etd[p + 256] = v1;
        if (m2) etd[p + 512] = v2;
        if (m3) etd[p + 768] = v3;
    }
}

// ------- layer-2 fused aggregation over SCALARS; fp16 U2 out -------
// U2_i = dinv_i * sum_{j in N(i)+self} dinv_j * relu(t_j*w1 + b1)

__global__ __launch_bounds__(256) void l2_agg_k(const float2* __restrict__ td,
                                                const float2* __restrict__ etd,
                                                const int* __restrict__ offs,
                                                const int* __restrict__ eend,
                                                const float* __restrict__ w1,
                                                const float* __restrict__ b1,
                                                _Float16* __restrict__ Uh, int n) {
    int node = blockIdx.x * 4 + (threadIdx.x >> 6);
    int lane = threadIdx.x & 63;
    if (node >= n) return;
    float wa = w1[lane],      wb = w1[lane + 64];
    float ba = b1[lane],      bb = b1[lane + 64];
    float2 self = td[node];
    float sa = fmaxf(fmaf(self.x, wa, ba), 0.f) * self.y;
    float sb = fmaxf(fmaf(self.x, wb, bb), 0.f) * self.y;
    const float2* ep = etd + offs[node];
    int cnt = eend[node] - offs[node];
    int p = 0;
    for (; p + 8 <= cnt; p += 8) {
        float2 v[8];
        #pragma unroll
        for (int u = 0; u < 8; ++u) v[u] = ep[p + u];
        #pragma unroll
        for (int u = 0; u < 8; ++u) {
            sa = fmaf(fmaxf(fmaf(v[u].x, wa, ba), 0.f), v[u].y, sa);
            sb = fmaf(fmaxf(fmaf(v[u].x, wb, bb), 0.f), v[u].y, sb);
        }
    }
    for (; p < cnt; ++p) {
        float2 v = ep[p];
        sa = fmaf(fmaxf(fmaf(v.x, wa, ba), 0.f), v.y, sa);
        sb = fmaf(fmaxf(fmaf(v.x, wb, bb), 0.f), v.y, sb);
    }
    float d = self.y;
    Uh[(size_t)node * H + lane]      = (_Float16)(sa * d);
    Uh[(size_t)node * H + lane + 64] = (_Float16)(sb * d);
}

// ------- MFMA GEMM (f16 in, fp32 accum): relu(in @ W + bias) [* pscale] -------
// POOL=false: fp16 row stores (Z2 path).  POOL=true: NO global store — per-graph column
// sums (batch is sorted -> <=3 graph segments per 64-row tile) atomicAdd'ed into P.
// v_mfma_f32_16x16x32_f16 layouts (m89-verified C/D; AMD lab-notes A/B):
//   A: row = lane&15, k = 8*(lane>>4)+j   (16 B contiguous from row-major fp16 in)
//   B: col = lane&15, k = 8*(lane>>4)+j   (16 B contiguous from LDS W^T [col][k], stride 136)
//   D: col = lane&15, row = 4*(lane>>4)+reg

template <bool POOL>
__global__ __launch_bounds__(256) void gemm_h_k(const _Float16* __restrict__ in,
                                                const float* __restrict__ W,
                                                const float* __restrict__ bias,
                                                const float* __restrict__ pscale,
                                                _Float16* __restrict__ out,
                                                const int* __restrict__ batch,
                                                float* __restrict__ P, int n) {
    __shared__ _Float16 WT[128 * 136];   // [col][k], +8 pad: ds_read_b128 2-way banks (free)
    __shared__ _Float16 OT[64 * 136];    // out tile re-stage, same padded stride
    __shared__ float bsh[H];
    __shared__ int bid[64];

    // stage W^T fp16 (global W is [k][col] fp32 row-major)
    for (int idx = threadIdx.x; idx < 128 * 32; idx += 256) {
        int k  = idx >> 5;
        int c4 = (idx & 31) << 2;
        float4 v = *(const float4*)(W + k * H + c4);
        WT[(c4 + 0) * 136 + k] = (_Float16)v.x;
        WT[(c4 + 1) * 136 + k] = (_Float16)v.y;
        WT[(c4 + 2) * 136 + k] = (_Float16)v.z;
        WT[(c4 + 3) * 136 + k] = (_Float16)v.w;
    }
    if (threadIdx.x < H) bsh[threadIdx.x] = bias[threadIdx.x];
    if (POOL && threadIdx.x < 64) {
        int gr = blockIdx.x * 64 + threadIdx.x;
        bid[threadIdx.x] = (gr < n) ? batch[gr] : -1;
    }
    __syncthreads();

    const int wave = threadIdx.x >> 6;
    const int l    = threadIdx.x & 63;
    const int lr   = l & 15;     // A-row / B-col / D-col within tile
    const int lk   = l >> 4;     // k sub-block (0..3)
    const int row0 = blockIdx.x * 64 + wave * 16;

    f32x4 acc[8];
    #pragma unroll
    for (int c = 0; c < 8; ++c) acc[c] = (f32x4){0.f, 0.f, 0.f, 0.f};

    int arow = row0 + lr; if (arow > n - 1) arow = n - 1;
    const _Float16* ap = in + (size_t)arow * H + lk * 8;

    #pragma unroll
    for (int ks = 0; ks < 4; ++ks) {
        half8 a = *(const half8*)(ap + ks * 32);
        #pragma unroll
        for (int c = 0; c < 8; ++c) {
            half8 b = *(const half8*)(WT + (c * 16 + lr) * 136 + ks * 32 + lk * 8);
            acc[c] = __builtin_amdgcn_mfma_f32_16x16x32_f16(a, b, acc[c], 0, 0, 0);
        }
    }

    // epilogue: bias + relu (+ pscale), fp16 into OT (2-way LDS banks from 136 stride)
    #pragma unroll
    for (int r = 0; r < 4; ++r) {
        int lrow = wave * 16 + lk * 4 + r;       // row within block tile
        int grow = blockIdx.x * 64 + lrow;
        float sc = 1.f;
        if (pscale) { int gr = grow > n - 1 ? n - 1 : grow; sc = pscale[gr]; }
        #pragma unroll
        for (int c = 0; c < 8; ++c) {
            float v = fmaxf(acc[c][r] + bsh[c * 16 + lr], 0.f) * sc;
            OT[lrow * 136 + c * 16 + lr] = (_Float16)v;
        }
    }
    __syncthreads();

    if constexpr (POOL) {
        // fused mean-pool partial: thread (f, half) walks 32 rows of column f, accumulating
        // per-graph run sums (batch sorted); ~1-2 atomicAdds per thread into L2-resident P.
        int f  = threadIdx.x & 127;
        int r0 = (threadIdx.x >> 7) * 32;
        float acc2 = 0.f;
        int cur = bid[r0];
        for (int r = r0; r < r0 + 32; ++r) {
            int b = bid[r];
            if (b != cur) {
                if (cur >= 0) atomicAdd(&P[(size_t)cur * H + f], acc2);
                acc2 = 0.f; cur = b;
            }
            if (b >= 0) acc2 += (float)OT[r * 136 + f];
        }
        if (cur >= 0) atomicAdd(&P[(size_t)cur * H + f], acc2);
    } else {
        // coalesced fp16 row stores: 64 rows x 256 B = 16 uint4 per row
        for (int idx = threadIdx.x; idx < 64 * 16; idx += 256) {
            int row = idx >> 4;
            int gr = blockIdx.x * 64 + row;
            if (gr < n)
                ((uint4*)(out + (size_t)gr * H))[idx & 15] = ((const uint4*)(OT + row * 136))[idx & 15];
        }
    }
}

// ------- whole-wave gather of one node's neighbor-row sum (fp16 rows, fp32 accumulate) -------

__device__ __forceinline__ void acc_h(float4& a, uint2 r) {
    __half2 h0 = *(__half2*)&r.x;
    __half2 h1 = *(__half2*)&r.y;
    float2 f0 = __half22float2(h0);
    float2 f1 = __half22float2(h1);
    a.x += f0.x; a.y += f0.y; a.z += f1.x; a.w += f1.y;
}

__device__ __forceinline__ float4 gather_row_sum_h(const uint2* __restrict__ hrow,
                                                   const int* __restrict__ csr,
                                                   int node, int e0, int e1, int half, int l) {
    float4 acc[8];
    #pragma unroll
    for (int u = 0; u < 8; ++u) acc[u] = make_float4(0.f, 0.f, 0.f, 0.f);
    if (half == 0) {                                  // self loop
        uint2 rs = hrow[(size_t)node * 32 + l];
        acc_h(acc[0], rs);
    }
    int q = e0;
    for (; q + 15 < e1; q += 16) {
        int idx[8];
        #pragma unroll
        for (int u = 0; u < 8; ++u) idx[u] = csr[q + 2 * u + half];
        uint2 raw[8];
        #pragma unroll
        for (int u = 0; u < 8; ++u) raw[u] = hrow[(size_t)idx[u] * 32 + l];
        #pragma unroll
        for (int u = 0; u < 8; ++u) acc_h(acc[u], raw[u]);
    }
    for (; q + 7 < e1; q += 8) {
        int idx[4];
        #pragma unroll
        for (int u = 0; u < 4; ++u) idx[u] = csr[q + 2 * u + half];
        uint2 raw[4];
        #pragma unroll
        for (int u = 0; u < 4; ++u) raw[u] = hrow[(size_t)idx[u] * 32 + l];
        #pragma unroll
        for (int u = 0; u < 4; ++u) acc_h(acc[u], raw[u]);
    }
    for (; q < e1; q += 2) {
        int off = q + half;
        if (off < e1) {
            uint2 raw = hrow[(size_t)csr[off] * 32 + l];
            acc_h(acc[0], raw);
        }
    }
    float4 sum;
    sum.x = ((acc[0].x + acc[1].x) + (acc[2].x + acc[3].x)) + ((acc[4].x + acc[5].x) + (acc[6].x + acc[7].x));
    sum.y = ((acc[0].y + acc[1].y) + (acc[2].y + acc[3].y)) + ((acc[4].y + acc[5].y) + (acc[6].y + acc[7].y));
    sum.z = ((acc[0].z + acc[1].z) + (acc[2].z + acc[3].z)) + ((acc[4].z + acc[5].z) + (acc[6].z + acc[7].z));
    sum.w = ((acc[0].w + acc[1].w) + (acc[2].w + acc[3].w)) + ((acc[4].w + acc[5].w) + (acc[6].w + acc[7].w));
    sum.x += __shfl_xor(sum.x, 32);
    sum.y += __shfl_xor(sum.y, 32);
    sum.z += __shfl_xor(sum.z, 32);
    sum.w += __shfl_xor(sum.w, 32);
    return sum;
}

// ------- layer-3 aggregation of fp16 Z2 rows: U3_i = dinv_i * (Z2_i + sum Z2_src) [fp16 out] -------

__global__ __launch_bounds__(256) void agg3h_k(const uint2* __restrict__ Zh, const int* __restrict__ offs,
                                               const int* __restrict__ eend, const int* __restrict__ csr,
                                               const float* __restrict__ dinv,
                                               _Float16* __restrict__ Uh, int n) {
    int node = blockIdx.x * 4 + (threadIdx.x >> 6);
    int lane = threadIdx.x & 63;
    int half = lane >> 5;
    int l = lane & 31;
    if (node >= n) return;
    float4 sum = gather_row_sum_h(Zh, csr, node, offs[node], eend[node], half, l);
    if (half == 0) {
        float d = dinv[node];
        half4 o;
        o[0] = (_Float16)(sum.x * d);
        o[1] = (_Float16)(sum.y * d);
        o[2] = (_Float16)(sum.z * d);
        o[3] = (_Float16)(sum.w * d);
        *(half4*)(Uh + (size_t)node * H + l * 4) = o;
    }
}

// ------- fused MLP head: mean = P/cnt, relu(@Wl1+bl1) + relu(@Wl2+bl2) + dot Wl3 + bl3 -------
// P holds per-graph SUMS (from the fused-pool gemm); counts via binary search on sorted batch.
// 64 blocks x 32 graphs: each thread owns one graph row (rg) and 16 output cols (cc).

__global__ __launch_bounds__(256) void head_k(const float* __restrict__ P,
                                              const int* __restrict__ batch,
                                              const float* __restrict__ Wl1, const float* __restrict__ bl1,
                                              const float* __restrict__ Wl2, const float* __restrict__ bl2,
                                              const float* __restrict__ Wl3, const float* __restrict__ bl3,
                                              float* __restrict__ out, int G, int n) {
    __shared__ float Wb[H * H];
    __shared__ float Tl[32 * 133];
    __shared__ float w3l[H];
    __shared__ int lb[33];
    int tid = threadIdx.x;
    int g0 = blockIdx.x * 32;

    if (tid < 128) w3l[tid] = Wl3[tid];
    if (tid >= 128 && tid < 161) {            // lower bounds for graphs g0..g0+32
        int g = g0 + (tid - 128); if (g > G) g = G;
        int lo = 0, hi = n;
        while (lo < hi) { int m = (lo + hi) >> 1; if (batch[m] < g) lo = m + 1; else hi = m; }
        lb[tid - 128] = lo;
    }
    for (int i = tid; i < H * H / 4; i += 256) ((float4*)Wb)[i] = ((const float4*)Wl1)[i];
    __syncthreads();

    const int cc = tid & 7, rg = tid >> 3, c0 = cc * 16;
    int grow = g0 + rg; if (grow > G - 1) grow = G - 1;
    int cntg = lb[rg + 1] - lb[rg];
    float rinv = 1.f / (cntg < 1 ? 1.f : (float)cntg);
    float acc[16];

    #pragma unroll
    for (int j = 0; j < 16; ++j) acc[j] = 0.f;
    const float4* P4 = (const float4*)P;
    for (int k4 = 0; k4 < H / 4; ++k4) {
        float4 a = P4[(size_t)grow * 32 + k4];
        a.x *= rinv; a.y *= rinv; a.z *= rinv; a.w *= rinv;
        const float* wbase = Wb + (k4 * 4) * H + c0;
        #pragma unroll
        for (int kk = 0; kk < 4; ++kk) {
            float w[16];
            *(float4*)(w + 0)  = *(const float4*)(wbase + kk * H + 0);
            *(float4*)(w + 4)  = *(const float4*)(wbase + kk * H + 4);
            *(float4*)(w + 8)  = *(const float4*)(wbase + kk * H + 8);
            *(float4*)(w + 12) = *(const float4*)(wbase + kk * H + 12);
            float av = ((const float*)&a)[kk];
            #pragma unroll
            for (int j = 0; j < 16; ++j)
                acc[j] = fmaf(av, w[j], acc[j]);
        }
    }
    #pragma unroll
    for (int j = 0; j < 16; ++j)
        Tl[rg * 133 + c0 + j] = fmaxf(acc[j] + bl1[c0 + j], 0.f);
    __syncthreads();
    for (int i = tid; i < H * H / 4; i += 256) ((float4*)Wb)[i] = ((const float4*)Wl2)[i];
    __syncthreads();

    #pragma unroll
    for (int j = 0; j < 16; ++j) acc[j] = 0.f;
    for (int k4 = 0; k4 < H / 4; ++k4) {
        float4 a = *(const float4*)(Tl + rg * 133 + k4 * 4);
        const float* wbase = Wb + (k4 * 4) * H + c0;
        #pragma unroll
        for (int kk = 0; kk < 4; ++kk) {
            float w[16];
            *(float4*)(w + 0)  = *(const float4*)(wbase + kk * H + 0);
            *(float4*)(w + 4)  = *(const float4*)(wbase + kk * H + 4);
            *(float4*)(w + 8)  = *(const float4*)(wbase + kk * H + 8);
            *(float4*)(w + 12) = *(const float4*)(wbase + kk * H + 12);
            float av = ((const float*)&a)[kk];
            #pragma unroll
            for (int j = 0; j < 16; ++j)
                acc[j] = fmaf(av, w[j], acc[j]);
        }
    }
    float part = 0.f;
    #pragma unroll
    for (int j = 0; j < 16; ++j)
        part += fmaxf(acc[j] + bl2[c0 + j], 0.f) * w3l[c0 + j];
    #pragma unroll
    for (int off = 1; off < 8; off <<= 1)
        part += __shfl_xor(part, off);
    if (cc == 0 && g0 + rg < G)
        out[g0 + rg] = part + bl3[0];
}

// ---------------- launch ----------------

extern "C" void kernel_launch(void* const* d_in, const int* in_sizes, int n_in,
                              void* d_out, int out_size, void* d_ws, size_t ws_size,
                              hipStream_t stream) {
    const float* x     = (const float*)d_in[0];
    const int*   ei    = (const int*)d_in[1];
    const int*   batch = (const int*)d_in[2];
    const float* W1  = (const float*)d_in[3];  const float* b1  = (const float*)d_in[4];
    const float* W2  = (const float*)d_in[5];  const float* b2  = (const float*)d_in[6];
    const float* W3  = (const float*)d_in[7];  const float* b3  = (const float*)d_in[8];
    const float* Wl1 = (const float*)d_in[9];  const float* bl1 = (const float*)d_in[10];
    const float* Wl2 = (const float*)d_in[11]; const float* bl2 = (const float*)d_in[12];
    const float* Wl3 = (const float*)d_in[13]; const float* bl3 = (const float*)d_in[14];

    const int N = in_sizes[0];
    const int E = in_sizes[1] / 2;
    const int G = out_size;
    const int* srcp = ei;
    const int* dstp = ei + E;
    const int NB = (N + BN - 1) / BN;    // 196 for N=100000

    char* w = (char*)d_ws;
    size_t off = 0;
    auto alloc = [&](size_t bytes) -> void* {
        void* p = w + off;
        off += (bytes + 255) & ~(size_t)255;
        return p;
    };
    // gcur and P adjacent at the front: ONE memset zeroes both.
    int*    gcur   = (int*)alloc((size_t)MAXNB * 4);
    float*  P      = (float*)alloc((size_t)G * H * 4);   // pooled SUMS (atomic, fp32)
    size_t  zbytes = off;                                 // memset span
    int*    offs   = (int*)alloc((size_t)N * 4);
    int*    eend   = (int*)alloc((size_t)N * 4);
    int*    csr    = (int*)alloc((size_t)NB * CAP * 4);   // bucket-padded
    float*  dinv   = (float*)alloc((size_t)N * 4);
    float*  sbuf   = (float*)alloc((size_t)N * 4);
    float2* td     = (float2*)alloc((size_t)N * 8);
    float*  A      = (float*)alloc((size_t)N * H * 4);   // U2h (fp16), then U3h (fp16)
    float*  B      = (float*)alloc((size_t)N * H * 4);   // pairbuf/etd, then Z2h (fp16)
    unsigned* pairbuf = (unsigned*)B;   // alias (NB*CAP*4 = 12.9 MB << N*H*4)
    float2*   etd     = (float2*)B;    // alias (NB*CAP*8 = 25.7 MB; live gather_td -> l2_agg)
    _Float16* Z2h     = (_Float16*)B;  // alias (N*H*2 = 25.6 MB, written after etd is dead)
    _Float16* U2h     = (_Float16*)A;
    _Float16* U3h     = (_Float16*)A;
    (void)ws_size; (void)n_in;

    // --- zero gcur + P in one shot; graph build (slack buckets) ---
    hipMemsetAsync(gcur, 0, zbytes, stream);
    scatter_pairs_k<<<(E + CHUNK - 1) / CHUNK, 256, 0, stream>>>(srcp, dstp, gcur, pairbuf, E, NB);
    build_csr_k<<<NB, 512, 0, stream>>>(pairbuf, gcur, x, offs, eend, dinv, sbuf, csr, N);

    // --- layer 1 (scalar feature, wave-split gather) ---
    agg1_k<<<(N + 15) / 16, 256, 0, stream>>>(sbuf, offs, eend, csr, dinv, td, N);

    // --- layer 2: per-edge operands, stream-aggregate (fp16 U2), MFMA GEMM (fp16 Z2) ---
    gather_td_k<<<NB * 4, 256, 0, stream>>>(csr, td, gcur, etd);
    l2_agg_k<<<(N + 3) / 4, 256, 0, stream>>>(td, etd, offs, eend, W1, b1, U2h, N);
    gemm_h_k<false><<<(N + 63) / 64, 256, 0, stream>>>(U2h, W2, b2, dinv, Z2h, nullptr, nullptr, N);

    // --- layer 3: fp16 row-gather aggregation (fp16 U3), MFMA GEMM + fused pool ---
    agg3h_k<<<(N + 3) / 4, 256, 0, stream>>>((const uint2*)Z2h, offs, eend, csr, dinv, U3h, N);
    gemm_h_k<true><<<(N + 63) / 64, 256, 0, stream>>>(U3h, W3, b3, nullptr, nullptr, batch, P, N);

    // --- fused MLP head (64 blocks x 32 graphs; divides P sums by counts) ---
    head_k<<<(G + 31) / 32, 256, 0, stream>>>(P, batch, Wl1, bl1, Wl2, bl2, Wl3, bl3,
                                              (float*)d_out, G, N);
}